// Round 6
// baseline (835.488 us; speedup 1.0000x reference)
//
#include <hip/hip_runtime.h>
#include <hip/hip_bf16.h>

typedef unsigned short u16;
typedef __attribute__((ext_vector_type(4))) u16 u16x4;
typedef __attribute__((ext_vector_type(8))) __bf16 bf16x8;
typedef __attribute__((ext_vector_type(4))) float f32x4;

__device__ __forceinline__ u16 f2bf(float x) {
    unsigned u = __float_as_uint(x);
    unsigned r = u + 0x7FFF + ((u >> 16) & 1);
    return (u16)(r >> 16);
}
__device__ __forceinline__ float bf2f(u16 h) {
    return __uint_as_float(((unsigned)h) << 16);
}

__device__ __forceinline__ void gl_lds16(const void* g, void* l) {
    __builtin_amdgcn_global_load_lds(
        (const __attribute__((address_space(1))) void*)g,
        (__attribute__((address_space(3))) void*)l, 16, 0, 0);
}

// =============== split-bf16 MFMA GEMM ===============
// C[M,Nc] = A[M,K] @ B^T[Nc,K] + bias, A,B as (hi,lo) bf16 pairs.
// acc = Ahi*Bhi + Ahi*Blo + Alo*Bhi   (lo*lo dropped, ~2^-16 relative)
__global__ __launch_bounds__(256) void gemm_mfma_kernel(
    const u16* __restrict__ Ahi, const u16* __restrict__ Alo, int lda,
    const u16* __restrict__ Bhi, const u16* __restrict__ Blo, int ldb,
    const float* __restrict__ bias, float* __restrict__ C,
    int M, int Nc, int K)
{
    __shared__ __align__(16) u16 lds[4 * 4096];
    u16* sAhi = lds;
    u16* sAlo = lds + 4096;
    u16* sBhi = lds + 8192;
    u16* sBlo = lds + 12288;

    int tid = threadIdx.x;
    int wave = tid >> 6, lane = tid & 63;
    int row0 = blockIdx.x * 128, col0 = blockIdx.y * 128;

    long gA[2], gB[2];
    int sOff[2];
#pragma unroll
    for (int r = 0; r < 2; ++r) {
        int trow = r * 64 + wave * 16 + (lane >> 2);
        int chunk = (lane & 3) ^ ((trow >> 2) & 3);
        int arow = min(row0 + trow, M - 1);
        gA[r] = (long)arow * lda + chunk * 8;
        gB[r] = (long)(col0 + trow) * ldb + chunk * 8;
        sOff[r] = (r * 64 + wave * 16) * 32;
    }

    int m16 = lane & 15, quad = lane >> 4;
    int offA[4], offB[4];
#pragma unroll
    for (int i = 0; i < 4; ++i) {
        int ra = (wave & 1) * 64 + i * 16 + m16;
        offA[i] = ra * 32 + ((quad ^ ((ra >> 2) & 3)) * 8);
        int rb = (wave >> 1) * 64 + i * 16 + m16;
        offB[i] = rb * 32 + ((quad ^ ((rb >> 2) & 3)) * 8);
    }

    f32x4 acc[4][4];
#pragma unroll
    for (int i = 0; i < 4; ++i)
#pragma unroll
        for (int j = 0; j < 4; ++j) {
            f32x4 z = {0.f, 0.f, 0.f, 0.f};
            acc[i][j] = z;
        }

    int nkb = K >> 5;
    for (int kb = 0; kb < nkb; ++kb) {
#pragma unroll
        for (int r = 0; r < 2; ++r) {
            gl_lds16(Ahi + gA[r], sAhi + sOff[r]);
            gl_lds16(Alo + gA[r], sAlo + sOff[r]);
            gl_lds16(Bhi + gB[r], sBhi + sOff[r]);
            gl_lds16(Blo + gB[r], sBlo + sOff[r]);
        }
        __syncthreads();
        bf16x8 ah[4], al[4], bh[4], bl[4];
#pragma unroll
        for (int i = 0; i < 4; ++i) {
            ah[i] = *(const bf16x8*)(sAhi + offA[i]);
            al[i] = *(const bf16x8*)(sAlo + offA[i]);
            bh[i] = *(const bf16x8*)(sBhi + offB[i]);
            bl[i] = *(const bf16x8*)(sBlo + offB[i]);
        }
#pragma unroll
        for (int i = 0; i < 4; ++i)
#pragma unroll
            for (int j = 0; j < 4; ++j) {
                acc[i][j] = __builtin_amdgcn_mfma_f32_16x16x32_bf16(ah[i], bh[j], acc[i][j], 0, 0, 0);
                acc[i][j] = __builtin_amdgcn_mfma_f32_16x16x32_bf16(ah[i], bl[j], acc[i][j], 0, 0, 0);
                acc[i][j] = __builtin_amdgcn_mfma_f32_16x16x32_bf16(al[i], bh[j], acc[i][j], 0, 0, 0);
            }
        __syncthreads();
#pragma unroll
        for (int r = 0; r < 2; ++r) { gA[r] += 32; gB[r] += 32; }
    }

    int wm = (wave & 1) * 64, wn = (wave >> 1) * 64;
#pragma unroll
    for (int j = 0; j < 4; ++j) {
        int col = col0 + wn + j * 16 + m16;
        float bj = bias[col];
#pragma unroll
        for (int i = 0; i < 4; ++i) {
#pragma unroll
            for (int rr = 0; rr < 4; ++rr) {
                int row = row0 + wm + i * 16 + quad * 4 + rr;
                if (row < M) C[(size_t)row * Nc + col] = acc[i][j][rr] + bj;
            }
        }
    }
}

// =============== conversion kernels ===============
__global__ void split4_kernel(const float* __restrict__ src, u16* __restrict__ hi,
                              u16* __restrict__ lo, int n4)
{
    int i = blockIdx.x * blockDim.x + threadIdx.x;
    if (i >= n4) return;
    float4 x = ((const float4*)src)[i];
    u16x4 h, l;
    h.x = f2bf(x.x); l.x = f2bf(x.x - bf2f(h.x));
    h.y = f2bf(x.y); l.y = f2bf(x.y - bf2f(h.y));
    h.z = f2bf(x.z); l.z = f2bf(x.z - bf2f(h.z));
    h.w = f2bf(x.w); l.w = f2bf(x.w - bf2f(h.w));
    *(u16x4*)(hi + (size_t)i * 4) = h;
    *(u16x4*)(lo + (size_t)i * 4) = l;
}

// S[M,64] -> (hi,lo) into cols 256..319 of the [M,320]-strided edge A-buffer
__global__ void s_split_kernel(const float* __restrict__ S, u16* __restrict__ Aehi,
                               u16* __restrict__ Aelo, int M)
{
    int i = blockIdx.x * blockDim.x + threadIdx.x;
    if (i >= M * 64) return;
    int e = i >> 6, c = i & 63;
    float x = S[i];
    u16 h = f2bf(x);
    u16 l = f2bf(x - bf2f(h));
    Aehi[(size_t)e * 320 + 256 + c] = h;
    Aelo[(size_t)e * 320 + 256 + c] = l;
}

// W[K,Nc] fp32 -> W^T (hi,lo) bf16 [Nc,K].  Nc = 2^ncShift.
__global__ void wsplitT_kernel(const float* __restrict__ W, u16* __restrict__ Whi,
                               u16* __restrict__ Wlo, int K, int ncShift)
{
    int Nc = 1 << ncShift;
    int idx = blockIdx.x * blockDim.x + threadIdx.x;
    if (idx >= K * Nc) return;
    int k = idx >> ncShift, n = idx & (Nc - 1);
    float x = W[idx];
    u16 h = f2bf(x);
    u16 l = f2bf(x - bf2f(h));
    Whi[(size_t)n * K + k] = h;
    Wlo[(size_t)n * K + k] = l;
}

// =============== CSR build ===============
__global__ void count_kernel(const int* __restrict__ V, const int* __restrict__ E,
                             int* ecnt, int* ncnt, int nnz)
{
    int k = blockIdx.x * blockDim.x + threadIdx.x;
    if (k >= nnz) return;
    atomicAdd(&ecnt[E[k]], 1);
    atomicAdd(&ncnt[V[k]], 1);
}

__global__ __launch_bounds__(256) void scan_part1(const int* __restrict__ cnt,
                                                  int* __restrict__ off,
                                                  int* __restrict__ psum, int n)
{
    __shared__ int tsum[256];
    int base = blockIdx.x * 1024;
    int t = threadIdx.x;
    int idx0 = base + t * 4;
    int4 c = make_int4(0, 0, 0, 0);
    if (idx0 + 3 < n) c = *(const int4*)(cnt + idx0);
    else {
        if (idx0 + 0 < n) c.x = cnt[idx0 + 0];
        if (idx0 + 1 < n) c.y = cnt[idx0 + 1];
        if (idx0 + 2 < n) c.z = cnt[idx0 + 2];
        if (idx0 + 3 < n) c.w = cnt[idx0 + 3];
    }
    int s = c.x + c.y + c.z + c.w;
    tsum[t] = s;
    __syncthreads();
    for (int o = 1; o < 256; o <<= 1) {
        int v = (t >= o) ? tsum[t - o] : 0;
        __syncthreads();
        tsum[t] += v;
        __syncthreads();
    }
    int run = tsum[t] - s;
    run += c.x; if (idx0 + 0 < n) off[idx0 + 1] = run;
    run += c.y; if (idx0 + 1 < n) off[idx0 + 2] = run;
    run += c.z; if (idx0 + 2 < n) off[idx0 + 3] = run;
    run += c.w; if (idx0 + 3 < n) off[idx0 + 4] = run;
    if (t == 255) psum[blockIdx.x] = tsum[255];
}

__global__ __launch_bounds__(256) void scan_part2(const int* __restrict__ cnt,
                                                  int* __restrict__ off,
                                                  const int* __restrict__ psum,
                                                  int* __restrict__ cur, int n)
{
    __shared__ int bpref;
    int t = threadIdx.x;
    int b = blockIdx.x;
    if (t < 64) {
        int s = (t < b) ? psum[t] : 0;
#pragma unroll
        for (int o = 32; o; o >>= 1) s += __shfl_xor(s, o);
        if (t == 0) {
            bpref = s;
            if (b == 0) off[0] = 0;
        }
    }
    __syncthreads();
    int base = b * 1024 + t * 4;
#pragma unroll
    for (int q = 0; q < 4; ++q) {
        int i = base + q;
        if (i < n) {
            int inc = off[i + 1] + bpref;
            off[i + 1] = inc;
            cur[i] = inc - cnt[i];
        }
    }
}

__global__ void fill_kernel(const int* __restrict__ V, const int* __restrict__ E,
                            int* ecur, int* ncur, int* edge_v, int* node_e, int nnz)
{
    int k = blockIdx.x * blockDim.x + threadIdx.x;
    if (k >= nnz) return;
    int v = V[k], e = E[k];
    int j = atomicAdd(&ecur[e], 1);
    edge_v[j] = v;
    int i = atomicAdd(&ncur[v], 1);
    node_e[i] = e;
}

// =============== graph kernels ===============
__global__ void score_kernel(const float* __restrict__ Xf, const float* __restrict__ a,
                             float* __restrict__ score, int N)
{
    int row = blockIdx.x * (blockDim.x >> 6) + (threadIdx.x >> 6);
    int lane = threadIdx.x & 63;
    if (row >= N) return;
    float4 x = *(const float4*)(Xf + (size_t)row * 256 + lane * 4);
    float4 av = *(const float4*)(a + lane * 4);
    float p = x.x * av.x + x.y * av.y + x.z * av.z + x.w * av.w;
#pragma unroll
    for (int off = 32; off; off >>= 1) p += __shfl_down(p, off);
    if (lane == 0) score[row] = p;
}

__device__ __forceinline__ float lrelu(float s) { return s >= 0.f ? s : 0.2f * s; }
__device__ __forceinline__ void acc4(float4& a, const float4& x, float w) {
    a.x += x.x * w; a.y += x.y * w; a.z += x.z * w; a.w += x.w * w;
}
__device__ __forceinline__ void add4(float4& a, const float4& x) {
    a.x += x.x; a.y += x.y; a.z += x.z; a.w += x.w;
}

// fused segment softmax + weighted gather; 32 lanes per edge (2 edges/wave),
// each lane covers 8 cols; writes elu result as (hi,lo) bf16 into the
// [M,320]-strided edge A-buffer
__global__ void v2e_fused_kernel(const float* __restrict__ Xf,
                                 const float* __restrict__ score,
                                 const int* __restrict__ eoff,
                                 const int* __restrict__ edge_v,
                                 u16* __restrict__ Aehi, u16* __restrict__ Aelo, int M)
{
    int e = blockIdx.x * 8 + (threadIdx.x >> 5);
    if (e >= M) return;
    int sl = threadIdx.x & 31;
    int j0 = eoff[e], j1 = eoff[e + 1];
    float m = -INFINITY;
    for (int j = j0 + sl; j < j1; j += 32) m = fmaxf(m, lrelu(score[edge_v[j]]));
#pragma unroll
    for (int o = 16; o; o >>= 1) m = fmaxf(m, __shfl_xor(m, o));
    float sum = 0.f;
    for (int j = j0 + sl; j < j1; j += 32) sum += expf(lrelu(score[edge_v[j]]) - m);
#pragma unroll
    for (int o = 16; o; o >>= 1) sum += __shfl_xor(sum, o);
    float inv = (j1 > j0) ? 1.0f / sum : 0.f;

    float4 accA = make_float4(0.f, 0.f, 0.f, 0.f);
    float4 accB = make_float4(0.f, 0.f, 0.f, 0.f);
    int col = sl * 8;
    int j = j0;
    for (; j + 3 < j1; j += 4) {
        int v0 = edge_v[j + 0], v1 = edge_v[j + 1], v2 = edge_v[j + 2], v3 = edge_v[j + 3];
        float s0 = score[v0], s1 = score[v1], s2 = score[v2], s3 = score[v3];
        const float* p0 = Xf + (size_t)v0 * 256 + col;
        const float* p1 = Xf + (size_t)v1 * 256 + col;
        const float* p2 = Xf + (size_t)v2 * 256 + col;
        const float* p3 = Xf + (size_t)v3 * 256 + col;
        float4 a0 = *(const float4*)p0, b0 = *(const float4*)(p0 + 4);
        float4 a1 = *(const float4*)p1, b1 = *(const float4*)(p1 + 4);
        float4 a2 = *(const float4*)p2, b2 = *(const float4*)(p2 + 4);
        float4 a3 = *(const float4*)p3, b3 = *(const float4*)(p3 + 4);
        float w0 = expf(lrelu(s0) - m) * inv;
        float w1 = expf(lrelu(s1) - m) * inv;
        float w2 = expf(lrelu(s2) - m) * inv;
        float w3 = expf(lrelu(s3) - m) * inv;
        acc4(accA, a0, w0); acc4(accB, b0, w0);
        acc4(accA, a1, w1); acc4(accB, b1, w1);
        acc4(accA, a2, w2); acc4(accB, b2, w2);
        acc4(accA, a3, w3); acc4(accB, b3, w3);
    }
    for (; j < j1; ++j) {
        int v = edge_v[j];
        float ww = expf(lrelu(score[v]) - m) * inv;
        const float* p = Xf + (size_t)v * 256 + col;
        float4 a = *(const float4*)p, b = *(const float4*)(p + 4);
        acc4(accA, a, ww); acc4(accB, b, ww);
    }
    float o8[8] = {accA.x, accA.y, accA.z, accA.w, accB.x, accB.y, accB.z, accB.w};
    u16x4 hA, lA, hB, lB;
#pragma unroll
    for (int q = 0; q < 8; ++q) {
        float vq = o8[q];
        vq = vq > 0.f ? vq : expm1f(vq);
        u16 h = f2bf(vq);
        u16 l = f2bf(vq - bf2f(h));
        if (q < 4) { hA[q] = h; lA[q] = l; } else { hB[q - 4] = h; lB[q - 4] = l; }
    }
    size_t base = (size_t)e * 320 + col;
    *(u16x4*)(Aehi + base) = hA;
    *(u16x4*)(Aehi + base + 4) = hB;
    *(u16x4*)(Aelo + base) = lA;
    *(u16x4*)(Aelo + base + 4) = lB;
}

// h[v,:] = elu(mean_i Y[node_e[i],:]) + Xinit[v,:] -> (hi,lo) bf16
// 32 lanes per node (2 nodes/wave), 8 cols/lane, 4-wide index unroll
__global__ void e2v_finish_kernel(const float* __restrict__ Y,
                                  const int* __restrict__ noff,
                                  const int* __restrict__ node_e,
                                  const float* __restrict__ Xinit,
                                  u16* __restrict__ Hhi, u16* __restrict__ Hlo, int N)
{
    int v = blockIdx.x * 8 + (threadIdx.x >> 5);
    if (v >= N) return;
    int sl = threadIdx.x & 31;
    int col = sl * 8;
    int i0 = noff[v], i1 = noff[v + 1];
    float4 accA = make_float4(0.f, 0.f, 0.f, 0.f);
    float4 accB = make_float4(0.f, 0.f, 0.f, 0.f);
    int i = i0;
    for (; i + 3 < i1; i += 4) {
        int e0 = node_e[i + 0], e1 = node_e[i + 1], e2 = node_e[i + 2], e3 = node_e[i + 3];
        const float* p0 = Y + (size_t)e0 * 256 + col;
        const float* p1 = Y + (size_t)e1 * 256 + col;
        const float* p2 = Y + (size_t)e2 * 256 + col;
        const float* p3 = Y + (size_t)e3 * 256 + col;
        float4 a0 = *(const float4*)p0, b0 = *(const float4*)(p0 + 4);
        float4 a1 = *(const float4*)p1, b1 = *(const float4*)(p1 + 4);
        float4 a2 = *(const float4*)p2, b2 = *(const float4*)(p2 + 4);
        float4 a3 = *(const float4*)p3, b3 = *(const float4*)(p3 + 4);
        add4(accA, a0); add4(accB, b0);
        add4(accA, a1); add4(accB, b1);
        add4(accA, a2); add4(accB, b2);
        add4(accA, a3); add4(accB, b3);
    }
    for (; i < i1; ++i) {
        int e = node_e[i];
        const float* p = Y + (size_t)e * 256 + col;
        float4 a = *(const float4*)p, b = *(const float4*)(p + 4);
        add4(accA, a); add4(accB, b);
    }
    float inv = (i1 > i0) ? 1.0f / (float)(i1 - i0) : 0.f;
    size_t base = (size_t)v * 256 + col;
    float4 xiA = *(const float4*)(Xinit + base);
    float4 xiB = *(const float4*)(Xinit + base + 4);
    float s8[8] = {accA.x, accA.y, accA.z, accA.w, accB.x, accB.y, accB.z, accB.w};
    float x8[8] = {xiA.x, xiA.y, xiA.z, xiA.w, xiB.x, xiB.y, xiB.z, xiB.w};
    u16x4 hA, lA, hB, lB;
#pragma unroll
    for (int q = 0; q < 8; ++q) {
        float mm = s8[q] * inv;
        float oq = (mm > 0.f ? mm : expm1f(mm)) + x8[q];
        u16 h = f2bf(oq);
        u16 l = f2bf(oq - bf2f(h));
        if (q < 4) { hA[q] = h; lA[q] = l; } else { hB[q - 4] = h; lB[q - 4] = l; }
    }
    *(u16x4*)(Hhi + base) = hA;
    *(u16x4*)(Hhi + base + 4) = hB;
    *(u16x4*)(Hlo + base) = lA;
    *(u16x4*)(Hlo + base + 4) = lB;
}

// =============== hyperconv ===============
__global__ void deinv_kernel(const int* __restrict__ eoff, const int* __restrict__ edge_v,
                             const int* __restrict__ noff, float* __restrict__ Deinv, int M)
{
    int e = blockIdx.x * blockDim.x + threadIdx.x;
    if (e >= M) return;
    int j0 = eoff[e], j1 = eoff[e + 1];
    float s = 0.f;
    for (int j = j0; j < j1; ++j) {
        int v = edge_v[j];
        s += (float)(noff[v + 1] - noff[v]);
    }
    float De = s / ((float)(j1 - j0) + 1.0f);
    Deinv[e] = De > 0.f ? rsqrtf(De) : 1.0f;
}

// Yh[e,:] = Deinv[e] * mean_j Xc[edge_v[j],:]  — 32 lanes/edge, float4/lane
__global__ void yh_kernel(const float* __restrict__ Xc,
                          const int* __restrict__ eoff, const int* __restrict__ edge_v,
                          const float* __restrict__ Deinv, float* __restrict__ Yh, int M)
{
    int e = blockIdx.x * 8 + (threadIdx.x >> 5);
    if (e >= M) return;
    int sl = threadIdx.x & 31;
    int col = sl * 4;
    int j0 = eoff[e], j1 = eoff[e + 1];
    float4 acc = make_float4(0.f, 0.f, 0.f, 0.f);
    int j = j0;
    for (; j + 3 < j1; j += 4) {
        int v0 = edge_v[j + 0], v1 = edge_v[j + 1], v2 = edge_v[j + 2], v3 = edge_v[j + 3];
        float4 x0 = *(const float4*)(Xc + (size_t)v0 * 128 + col);
        float4 x1 = *(const float4*)(Xc + (size_t)v1 * 128 + col);
        float4 x2 = *(const float4*)(Xc + (size_t)v2 * 128 + col);
        float4 x3 = *(const float4*)(Xc + (size_t)v3 * 128 + col);
        add4(acc, x0); add4(acc, x1); add4(acc, x2); add4(acc, x3);
    }
    for (; j < j1; ++j) {
        int v = edge_v[j];
        float4 x = *(const float4*)(Xc + (size_t)v * 128 + col);
        add4(acc, x);
    }
    float sc = ((j1 > j0) ? 1.0f / (float)(j1 - j0) : 0.f) * Deinv[e];
    float4 o;
    o.x = acc.x * sc; o.y = acc.y * sc; o.z = acc.z * sc; o.w = acc.w * sc;
    *(float4*)(Yh + (size_t)e * 128 + col) = o;
}

// out[v,:] = Dv^-0.5 * sum_i Yh[node_e[i],:]  — 32 lanes/node, float4/lane
__global__ void xo_final_kernel(const float* __restrict__ Yh,
                                const int* __restrict__ noff, const int* __restrict__ node_e,
                                float* __restrict__ out, int N)
{
    int v = blockIdx.x * 8 + (threadIdx.x >> 5);
    if (v >= N) return;
    int sl = threadIdx.x & 31;
    int col = sl * 4;
    int i0 = noff[v], i1 = noff[v + 1];
    float4 acc = make_float4(0.f, 0.f, 0.f, 0.f);
    int i = i0;
    for (; i + 3 < i1; i += 4) {
        int e0 = node_e[i + 0], e1 = node_e[i + 1], e2 = node_e[i + 2], e3 = node_e[i + 3];
        float4 y0 = *(const float4*)(Yh + (size_t)e0 * 128 + col);
        float4 y1 = *(const float4*)(Yh + (size_t)e1 * 128 + col);
        float4 y2 = *(const float4*)(Yh + (size_t)e2 * 128 + col);
        float4 y3 = *(const float4*)(Yh + (size_t)e3 * 128 + col);
        add4(acc, y0); add4(acc, y1); add4(acc, y2); add4(acc, y3);
    }
    for (; i < i1; ++i) {
        int e = node_e[i];
        float4 y = *(const float4*)(Yh + (size_t)e * 128 + col);
        add4(acc, y);
    }
    float sc = (i1 > i0) ? rsqrtf((float)(i1 - i0)) : 0.f;
    float4 o;
    o.x = acc.x * sc; o.y = acc.y * sc; o.z = acc.z * sc; o.w = acc.w * sc;
    *(float4*)(out + (size_t)v * 128 + col) = o;
}

// =============== host-side ===============
static void gemm(const u16* Ahi, const u16* Alo, int lda,
                 const u16* Bhi, const u16* Blo, int ldb,
                 const float* bias, float* C, int M, int Nc, int K,
                 hipStream_t stream)
{
    dim3 g((M + 127) / 128, Nc / 128);
    gemm_mfma_kernel<<<g, 256, 0, stream>>>(Ahi, Alo, lda, Bhi, Blo, ldb, bias, C, M, Nc, K);
}

static void run_layer(u16* Ahi, u16* Alo, int K,
                      const u16* WxThi, const u16* WxTlo, const float* bx,
                      const u16* WvThi, const u16* WvTlo, const float* bv,
                      const float* a,
                      const u16* WtThi, const u16* WtTlo, const float* bt,
                      u16* Aehi, u16* Aelo,
                      float* Xinit, float* Xfeat, float* Ybuf, float* score,
                      const int* eoff, const int* edge_v,
                      const int* noff, const int* node_e,
                      int N, int M, hipStream_t stream)
{
    gemm(Ahi, Alo, K, WxThi, WxTlo, K, bx, Xinit, N, 256, K, stream);
    gemm(Ahi, Alo, K, WvThi, WvTlo, K, bv, Xfeat, N, 256, K, stream);
    score_kernel<<<(N + 3) / 4, 256, 0, stream>>>(Xfeat, a, score, N);
    v2e_fused_kernel<<<(M + 7) / 8, 256, 0, stream>>>(Xfeat, score, eoff, edge_v, Aehi, Aelo, M);
    gemm(Aehi, Aelo, 320, WtThi, WtTlo, 320, bt, Ybuf, M, 256, 320, stream);
    e2v_finish_kernel<<<(N + 7) / 8, 256, 0, stream>>>(Ybuf, noff, node_e, Xinit, Ahi, Alo, N);
}

extern "C" void kernel_launch(void* const* d_in, const int* in_sizes, int n_in,
                              void* d_out, int out_size, void* d_ws, size_t ws_size,
                              hipStream_t stream)
{
    const float* X   = (const float*)d_in[0];
    const int*   V   = (const int*)d_in[1];
    const int*   E   = (const int*)d_in[2];
    const float* S   = (const float*)d_in[3];
    const float* Wx0 = (const float*)d_in[4];  const float* bx0 = (const float*)d_in[5];
    const float* Wv0 = (const float*)d_in[6];  const float* bv0 = (const float*)d_in[7];
    const float* a0  = (const float*)d_in[8];
    const float* Wt0 = (const float*)d_in[9];  const float* bt0 = (const float*)d_in[10];
    const float* Wx1 = (const float*)d_in[11]; const float* bx1 = (const float*)d_in[12];
    const float* Wv1 = (const float*)d_in[13]; const float* bv1 = (const float*)d_in[14];
    const float* a1  = (const float*)d_in[15];
    const float* Wt1 = (const float*)d_in[16]; const float* bt1 = (const float*)d_in[17];
    const float* Wf  = (const float*)d_in[18]; const float* bf  = (const float*)d_in[19];

    int N   = in_sizes[0] / 128;
    int NNZ = in_sizes[1];
    int M   = in_sizes[3] / 64;

    float* ws = (float*)d_ws;
    size_t off = 0;
    float* Xinit = ws + off; off += (size_t)N * 256;   // also Yh [M,128] in hyperconv
    float* Xfeat = ws + off; off += (size_t)N * 256;   // also Ybuf [M,256]; also Xc [N,128]
    float* Ybuf  = Xfeat;
    u16* Ahi  = (u16*)(ws + off); off += (size_t)N * 128;  // N*256 u16
    u16* Alo  = (u16*)(ws + off); off += (size_t)N * 128;
    u16* Aehi = (u16*)(ws + off); off += (size_t)M * 160;  // M*320 u16
    u16* Aelo = (u16*)(ws + off); off += (size_t)M * 160;
    u16* WxT0h = (u16*)(ws + off); off += (size_t)(256 * 128) / 2;
    u16* WxT0l = (u16*)(ws + off); off += (size_t)(256 * 128) / 2;
    u16* WvT0h = (u16*)(ws + off); off += (size_t)(256 * 128) / 2;
    u16* WvT0l = (u16*)(ws + off); off += (size_t)(256 * 128) / 2;
    u16* WtT0h = (u16*)(ws + off); off += (size_t)(256 * 320) / 2;
    u16* WtT0l = (u16*)(ws + off); off += (size_t)(256 * 320) / 2;
    u16* WxT1h = (u16*)(ws + off); off += (size_t)(256 * 256) / 2;
    u16* WxT1l = (u16*)(ws + off); off += (size_t)(256 * 256) / 2;
    u16* WvT1h = (u16*)(ws + off); off += (size_t)(256 * 256) / 2;
    u16* WvT1l = (u16*)(ws + off); off += (size_t)(256 * 256) / 2;
    u16* WtT1h = (u16*)(ws + off); off += (size_t)(256 * 320) / 2;
    u16* WtT1l = (u16*)(ws + off); off += (size_t)(256 * 320) / 2;
    u16* WfTh  = (u16*)(ws + off); off += (size_t)(128 * 256) / 2;
    u16* WfTl  = (u16*)(ws + off); off += (size_t)(128 * 256) / 2;
    float* score = ws + off; off += (size_t)N;
    float* Deinv = ws + off; off += (size_t)M;
    int* eoff   = (int*)(ws + off); off += (size_t)(M + 1);
    int* ecnt   = (int*)(ws + off); off += (size_t)M;
    int* ecur   = (int*)(ws + off); off += (size_t)M;
    int* psumE  = (int*)(ws + off); off += 64;
    int* edge_v = (int*)(ws + off); off += (size_t)NNZ;
    int* noff   = (int*)(ws + off); off += (size_t)(N + 1);
    int* ncnt   = (int*)(ws + off); off += (size_t)N;
    int* ncur   = (int*)(ws + off); off += (size_t)N;
    int* psumN  = (int*)(ws + off); off += 64;
    int* node_e = (int*)(ws + off); off += (size_t)NNZ;

    // ---- CSR build (parallel scan) ----
    hipMemsetAsync(ecnt, 0, (size_t)M * 4, stream);
    hipMemsetAsync(ncnt, 0, (size_t)N * 4, stream);
    count_kernel<<<(NNZ + 255) / 256, 256, 0, stream>>>(V, E, ecnt, ncnt, NNZ);
    int nbE = (M + 1023) / 1024, nbN = (N + 1023) / 1024;
    scan_part1<<<nbE, 256, 0, stream>>>(ecnt, eoff, psumE, M);
    scan_part1<<<nbN, 256, 0, stream>>>(ncnt, noff, psumN, N);
    scan_part2<<<nbE, 256, 0, stream>>>(ecnt, eoff, psumE, ecur, M);
    scan_part2<<<nbN, 256, 0, stream>>>(ncnt, noff, psumN, ncur, N);
    fill_kernel<<<(NNZ + 255) / 256, 256, 0, stream>>>(V, E, ecur, ncur, edge_v, node_e, NNZ);

    // ---- input splits ----
    split4_kernel<<<((N * 128 / 4) + 255) / 256, 256, 0, stream>>>(X, Ahi, Alo, N * 128 / 4);
    s_split_kernel<<<((M * 64) + 255) / 256, 256, 0, stream>>>(S, Aehi, Aelo, M);

    // ---- weight transpose+split ----
    wsplitT_kernel<<<(128 * 256 + 255) / 256, 256, 0, stream>>>(Wx0, WxT0h, WxT0l, 128, 8);
    wsplitT_kernel<<<(128 * 256 + 255) / 256, 256, 0, stream>>>(Wv0, WvT0h, WvT0l, 128, 8);
    wsplitT_kernel<<<(320 * 256 + 255) / 256, 256, 0, stream>>>(Wt0, WtT0h, WtT0l, 320, 8);
    wsplitT_kernel<<<(256 * 256 + 255) / 256, 256, 0, stream>>>(Wx1, WxT1h, WxT1l, 256, 8);
    wsplitT_kernel<<<(256 * 256 + 255) / 256, 256, 0, stream>>>(Wv1, WvT1h, WvT1l, 256, 8);
    wsplitT_kernel<<<(320 * 256 + 255) / 256, 256, 0, stream>>>(Wt1, WtT1h, WtT1l, 320, 8);
    wsplitT_kernel<<<(256 * 128 + 255) / 256, 256, 0, stream>>>(Wf, WfTh, WfTl, 256, 7);

    // ---- layers ----
    run_layer(Ahi, Alo, 128, WxT0h, WxT0l, bx0, WvT0h, WvT0l, bv0, a0,
              WtT0h, WtT0l, bt0, Aehi, Aelo, Xinit, Xfeat, Ybuf, score,
              eoff, edge_v, noff, node_e, N, M, stream);
    run_layer(Ahi, Alo, 256, WxT1h, WxT1l, bx1, WvT1h, WvT1l, bv1, a1,
              WtT1h, WtT1l, bt1, Aehi, Aelo, Xinit, Xfeat, Ybuf, score,
              eoff, edge_v, noff, node_e, N, M, stream);

    // ---- hyperconv ----
    float* Xc = Xfeat;   // [N,128] (Ybuf dead)
    float* Yh = Xinit;   // [M,128] (Xinit dead)
    gemm(Ahi, Alo, 256, WfTh, WfTl, 256, bf, Xc, N, 128, 256, stream);
    deinv_kernel<<<(M + 255) / 256, 256, 0, stream>>>(eoff, edge_v, noff, Deinv, M);
    yh_kernel<<<(M + 7) / 8, 256, 0, stream>>>(Xc, eoff, edge_v, Deinv, Yh, M);
    xo_final_kernel<<<(N + 7) / 8, 256, 0, stream>>>(Yh, noff, node_e, (float*)d_out, N);
}

// Round 7
// 718.670 us; speedup vs baseline: 1.1625x; 1.1625x over previous
//
#include <hip/hip_runtime.h>
#include <hip/hip_bf16.h>

typedef unsigned short u16;
typedef __attribute__((ext_vector_type(4))) u16 u16x4;
typedef __attribute__((ext_vector_type(8))) u16 u16x8;
typedef __attribute__((ext_vector_type(8))) __bf16 bf16x8;
typedef __attribute__((ext_vector_type(4))) float f32x4;

__device__ __forceinline__ u16 f2bf(float x) {
    unsigned u = __float_as_uint(x);
    unsigned r = u + 0x7FFF + ((u >> 16) & 1);
    return (u16)(r >> 16);
}
__device__ __forceinline__ float bf2f(u16 h) {
    return __uint_as_float(((unsigned)h) << 16);
}

__device__ __forceinline__ void gl_lds16(const void* g, void* l) {
    __builtin_amdgcn_global_load_lds(
        (const __attribute__((address_space(1))) void*)g,
        (__attribute__((address_space(3))) void*)l, 16, 0, 0);
}

// =============== split-bf16 MFMA GEMM ===============
// C[M,Nc] = A[M,K] @ B^T[Nc,K] + bias, A,B as (hi,lo) bf16 pairs.
// acc = Ahi*Bhi + Ahi*Blo + Alo*Bhi   (lo*lo dropped, ~2^-16 relative)
// out_bf16: 0 -> fp32 C, 1 -> bf16 (u16) C
__global__ __launch_bounds__(256) void gemm_mfma_kernel(
    const u16* __restrict__ Ahi, const u16* __restrict__ Alo, int lda,
    const u16* __restrict__ Bhi, const u16* __restrict__ Blo, int ldb,
    const float* __restrict__ bias, void* __restrict__ C,
    int M, int Nc, int K, int out_bf16)
{
    __shared__ __align__(16) u16 lds[4 * 4096];
    u16* sAhi = lds;
    u16* sAlo = lds + 4096;
    u16* sBhi = lds + 8192;
    u16* sBlo = lds + 12288;

    int tid = threadIdx.x;
    int wave = tid >> 6, lane = tid & 63;
    int row0 = blockIdx.x * 128, col0 = blockIdx.y * 128;

    long gA[2], gB[2];
    int sOff[2];
#pragma unroll
    for (int r = 0; r < 2; ++r) {
        int trow = r * 64 + wave * 16 + (lane >> 2);
        int chunk = (lane & 3) ^ ((trow >> 2) & 3);
        int arow = min(row0 + trow, M - 1);
        gA[r] = (long)arow * lda + chunk * 8;
        gB[r] = (long)(col0 + trow) * ldb + chunk * 8;
        sOff[r] = (r * 64 + wave * 16) * 32;
    }

    int m16 = lane & 15, quad = lane >> 4;
    int offA[4], offB[4];
#pragma unroll
    for (int i = 0; i < 4; ++i) {
        int ra = (wave & 1) * 64 + i * 16 + m16;
        offA[i] = ra * 32 + ((quad ^ ((ra >> 2) & 3)) * 8);
        int rb = (wave >> 1) * 64 + i * 16 + m16;
        offB[i] = rb * 32 + ((quad ^ ((rb >> 2) & 3)) * 8);
    }

    f32x4 acc[4][4];
#pragma unroll
    for (int i = 0; i < 4; ++i)
#pragma unroll
        for (int j = 0; j < 4; ++j) {
            f32x4 z = {0.f, 0.f, 0.f, 0.f};
            acc[i][j] = z;
        }

    int nkb = K >> 5;
    for (int kb = 0; kb < nkb; ++kb) {
#pragma unroll
        for (int r = 0; r < 2; ++r) {
            gl_lds16(Ahi + gA[r], sAhi + sOff[r]);
            gl_lds16(Alo + gA[r], sAlo + sOff[r]);
            gl_lds16(Bhi + gB[r], sBhi + sOff[r]);
            gl_lds16(Blo + gB[r], sBlo + sOff[r]);
        }
        __syncthreads();
        bf16x8 ah[4], al[4], bh[4], bl[4];
#pragma unroll
        for (int i = 0; i < 4; ++i) {
            ah[i] = *(const bf16x8*)(sAhi + offA[i]);
            al[i] = *(const bf16x8*)(sAlo + offA[i]);
            bh[i] = *(const bf16x8*)(sBhi + offB[i]);
            bl[i] = *(const bf16x8*)(sBlo + offB[i]);
        }
#pragma unroll
        for (int i = 0; i < 4; ++i)
#pragma unroll
            for (int j = 0; j < 4; ++j) {
                acc[i][j] = __builtin_amdgcn_mfma_f32_16x16x32_bf16(ah[i], bh[j], acc[i][j], 0, 0, 0);
                acc[i][j] = __builtin_amdgcn_mfma_f32_16x16x32_bf16(ah[i], bl[j], acc[i][j], 0, 0, 0);
                acc[i][j] = __builtin_amdgcn_mfma_f32_16x16x32_bf16(al[i], bh[j], acc[i][j], 0, 0, 0);
            }
        __syncthreads();
#pragma unroll
        for (int r = 0; r < 2; ++r) { gA[r] += 32; gB[r] += 32; }
    }

    int wm = (wave & 1) * 64, wn = (wave >> 1) * 64;
    if (out_bf16) {
        u16* Cb = (u16*)C;
#pragma unroll
        for (int j = 0; j < 4; ++j) {
            int col = col0 + wn + j * 16 + m16;
            float bj = bias[col];
#pragma unroll
            for (int i = 0; i < 4; ++i) {
#pragma unroll
                for (int rr = 0; rr < 4; ++rr) {
                    int row = row0 + wm + i * 16 + quad * 4 + rr;
                    if (row < M) Cb[(size_t)row * Nc + col] = f2bf(acc[i][j][rr] + bj);
                }
            }
        }
    } else {
        float* Cf = (float*)C;
#pragma unroll
        for (int j = 0; j < 4; ++j) {
            int col = col0 + wn + j * 16 + m16;
            float bj = bias[col];
#pragma unroll
            for (int i = 0; i < 4; ++i) {
#pragma unroll
                for (int rr = 0; rr < 4; ++rr) {
                    int row = row0 + wm + i * 16 + quad * 4 + rr;
                    if (row < M) Cf[(size_t)row * Nc + col] = acc[i][j][rr] + bj;
                }
            }
        }
    }
}

// =============== conversion kernels ===============
__global__ void split4_kernel(const float* __restrict__ src, u16* __restrict__ hi,
                              u16* __restrict__ lo, int n4)
{
    int i = blockIdx.x * blockDim.x + threadIdx.x;
    if (i >= n4) return;
    float4 x = ((const float4*)src)[i];
    u16x4 h, l;
    h.x = f2bf(x.x); l.x = f2bf(x.x - bf2f(h.x));
    h.y = f2bf(x.y); l.y = f2bf(x.y - bf2f(h.y));
    h.z = f2bf(x.z); l.z = f2bf(x.z - bf2f(h.z));
    h.w = f2bf(x.w); l.w = f2bf(x.w - bf2f(h.w));
    *(u16x4*)(hi + (size_t)i * 4) = h;
    *(u16x4*)(lo + (size_t)i * 4) = l;
}

// S[M,64] -> (hi,lo) into cols 256..319 of the [M,320]-strided edge A-buffer
__global__ void s_split_kernel(const float* __restrict__ S, u16* __restrict__ Aehi,
                               u16* __restrict__ Aelo, int M)
{
    int i = blockIdx.x * blockDim.x + threadIdx.x;
    if (i >= M * 64) return;
    int e = i >> 6, c = i & 63;
    float x = S[i];
    u16 h = f2bf(x);
    u16 l = f2bf(x - bf2f(h));
    Aehi[(size_t)e * 320 + 256 + c] = h;
    Aelo[(size_t)e * 320 + 256 + c] = l;
}

// W[K,Nc] fp32 -> W^T (hi,lo) bf16 [Nc,K].  Nc = 2^ncShift.
__global__ void wsplitT_kernel(const float* __restrict__ W, u16* __restrict__ Whi,
                               u16* __restrict__ Wlo, int K, int ncShift)
{
    int Nc = 1 << ncShift;
    int idx = blockIdx.x * blockDim.x + threadIdx.x;
    if (idx >= K * Nc) return;
    int k = idx >> ncShift, n = idx & (Nc - 1);
    float x = W[idx];
    u16 h = f2bf(x);
    u16 l = f2bf(x - bf2f(h));
    Whi[(size_t)n * K + k] = h;
    Wlo[(size_t)n * K + k] = l;
}

// =============== CSR build ===============
__global__ void count_kernel(const int* __restrict__ V, const int* __restrict__ E,
                             int* ecnt, int* ncnt, int nnz)
{
    int k = blockIdx.x * blockDim.x + threadIdx.x;
    if (k >= nnz) return;
    atomicAdd(&ecnt[E[k]], 1);
    atomicAdd(&ncnt[V[k]], 1);
}

__global__ __launch_bounds__(256) void scan_part1(const int* __restrict__ cnt,
                                                  int* __restrict__ off,
                                                  int* __restrict__ psum, int n)
{
    __shared__ int tsum[256];
    int base = blockIdx.x * 1024;
    int t = threadIdx.x;
    int idx0 = base + t * 4;
    int4 c = make_int4(0, 0, 0, 0);
    if (idx0 + 3 < n) c = *(const int4*)(cnt + idx0);
    else {
        if (idx0 + 0 < n) c.x = cnt[idx0 + 0];
        if (idx0 + 1 < n) c.y = cnt[idx0 + 1];
        if (idx0 + 2 < n) c.z = cnt[idx0 + 2];
        if (idx0 + 3 < n) c.w = cnt[idx0 + 3];
    }
    int s = c.x + c.y + c.z + c.w;
    tsum[t] = s;
    __syncthreads();
    for (int o = 1; o < 256; o <<= 1) {
        int v = (t >= o) ? tsum[t - o] : 0;
        __syncthreads();
        tsum[t] += v;
        __syncthreads();
    }
    int run = tsum[t] - s;
    run += c.x; if (idx0 + 0 < n) off[idx0 + 1] = run;
    run += c.y; if (idx0 + 1 < n) off[idx0 + 2] = run;
    run += c.z; if (idx0 + 2 < n) off[idx0 + 3] = run;
    run += c.w; if (idx0 + 3 < n) off[idx0 + 4] = run;
    if (t == 255) psum[blockIdx.x] = tsum[255];
}

__global__ __launch_bounds__(256) void scan_part2(const int* __restrict__ cnt,
                                                  int* __restrict__ off,
                                                  const int* __restrict__ psum,
                                                  int* __restrict__ cur, int n)
{
    __shared__ int bpref;
    int t = threadIdx.x;
    int b = blockIdx.x;
    if (t < 64) {
        int s = (t < b) ? psum[t] : 0;
#pragma unroll
        for (int o = 32; o; o >>= 1) s += __shfl_xor(s, o);
        if (t == 0) {
            bpref = s;
            if (b == 0) off[0] = 0;
        }
    }
    __syncthreads();
    int base = b * 1024 + t * 4;
#pragma unroll
    for (int q = 0; q < 4; ++q) {
        int i = base + q;
        if (i < n) {
            int inc = off[i + 1] + bpref;
            off[i + 1] = inc;
            cur[i] = inc - cnt[i];
        }
    }
}

__global__ void fill_kernel(const int* __restrict__ V, const int* __restrict__ E,
                            int* ecur, int* ncur, int* edge_v, int* node_e, int nnz)
{
    int k = blockIdx.x * blockDim.x + threadIdx.x;
    if (k >= nnz) return;
    int v = V[k], e = E[k];
    int j = atomicAdd(&ecur[e], 1);
    edge_v[j] = v;
    int i = atomicAdd(&ncur[v], 1);
    node_e[i] = e;
}

// =============== graph kernels ===============
// score = Xfeat(bf16) @ a   (wave per row, 4 cols/lane)
__global__ void score_kernel(const u16* __restrict__ Xf, const float* __restrict__ a,
                             float* __restrict__ score, int N)
{
    int row = blockIdx.x * (blockDim.x >> 6) + (threadIdx.x >> 6);
    int lane = threadIdx.x & 63;
    if (row >= N) return;
    u16x4 x = *(const u16x4*)(Xf + (size_t)row * 256 + lane * 4);
    float4 av = *(const float4*)(a + lane * 4);
    float p = bf2f(x.x) * av.x + bf2f(x.y) * av.y + bf2f(x.z) * av.z + bf2f(x.w) * av.w;
#pragma unroll
    for (int off = 32; off; off >>= 1) p += __shfl_down(p, off);
    if (lane == 0) score[row] = p;
}

__device__ __forceinline__ float lrelu(float s) { return s >= 0.f ? s : 0.2f * s; }

// fused segment softmax + weighted gather over bf16 Xfeat; 32 lanes/edge
// (2 edges/wave), 8 cols/lane (one 16B load per row); writes elu result as
// (hi,lo) bf16 into the [M,320]-strided edge A-buffer
__global__ void v2e_fused_kernel(const u16* __restrict__ Xf,
                                 const float* __restrict__ score,
                                 const int* __restrict__ eoff,
                                 const int* __restrict__ edge_v,
                                 u16* __restrict__ Aehi, u16* __restrict__ Aelo, int M)
{
    int e = blockIdx.x * 8 + (threadIdx.x >> 5);
    if (e >= M) return;
    int sl = threadIdx.x & 31;
    int j0 = eoff[e], j1 = eoff[e + 1];
    float m = -INFINITY;
    for (int j = j0 + sl; j < j1; j += 32) m = fmaxf(m, lrelu(score[edge_v[j]]));
#pragma unroll
    for (int o = 16; o; o >>= 1) m = fmaxf(m, __shfl_xor(m, o));
    float sum = 0.f;
    for (int j = j0 + sl; j < j1; j += 32) sum += expf(lrelu(score[edge_v[j]]) - m);
#pragma unroll
    for (int o = 16; o; o >>= 1) sum += __shfl_xor(sum, o);
    float inv = (j1 > j0) ? 1.0f / sum : 0.f;

    float acc[8] = {0.f, 0.f, 0.f, 0.f, 0.f, 0.f, 0.f, 0.f};
    int col = sl * 8;
    int j = j0;
    for (; j + 3 < j1; j += 4) {
        int v0 = edge_v[j + 0], v1 = edge_v[j + 1], v2 = edge_v[j + 2], v3 = edge_v[j + 3];
        float s0 = score[v0], s1 = score[v1], s2 = score[v2], s3 = score[v3];
        u16x8 r0 = *(const u16x8*)(Xf + (size_t)v0 * 256 + col);
        u16x8 r1 = *(const u16x8*)(Xf + (size_t)v1 * 256 + col);
        u16x8 r2 = *(const u16x8*)(Xf + (size_t)v2 * 256 + col);
        u16x8 r3 = *(const u16x8*)(Xf + (size_t)v3 * 256 + col);
        float w0 = expf(lrelu(s0) - m) * inv;
        float w1 = expf(lrelu(s1) - m) * inv;
        float w2 = expf(lrelu(s2) - m) * inv;
        float w3 = expf(lrelu(s3) - m) * inv;
#pragma unroll
        for (int q = 0; q < 8; ++q) {
            acc[q] += bf2f(r0[q]) * w0;
            acc[q] += bf2f(r1[q]) * w1;
            acc[q] += bf2f(r2[q]) * w2;
            acc[q] += bf2f(r3[q]) * w3;
        }
    }
    for (; j < j1; ++j) {
        int v = edge_v[j];
        float ww = expf(lrelu(score[v]) - m) * inv;
        u16x8 r = *(const u16x8*)(Xf + (size_t)v * 256 + col);
#pragma unroll
        for (int q = 0; q < 8; ++q) acc[q] += bf2f(r[q]) * ww;
    }
    u16x8 hv, lv;
#pragma unroll
    for (int q = 0; q < 8; ++q) {
        float vq = acc[q];
        vq = vq > 0.f ? vq : expm1f(vq);
        u16 h = f2bf(vq);
        hv[q] = h;
        lv[q] = f2bf(vq - bf2f(h));
    }
    size_t base = (size_t)e * 320 + col;
    *(u16x8*)(Aehi + base) = hv;
    *(u16x8*)(Aelo + base) = lv;
}

// h[v,:] = elu(mean_i Y[node_e[i],:]) + Xinit[v,:] -> (hi,lo) bf16
// Y is bf16; 32 lanes/node (2 nodes/wave), 8 cols/lane, 4-wide index unroll
__global__ void e2v_finish_kernel(const u16* __restrict__ Y,
                                  const int* __restrict__ noff,
                                  const int* __restrict__ node_e,
                                  const float* __restrict__ Xinit,
                                  u16* __restrict__ Hhi, u16* __restrict__ Hlo, int N)
{
    int v = blockIdx.x * 8 + (threadIdx.x >> 5);
    if (v >= N) return;
    int sl = threadIdx.x & 31;
    int col = sl * 8;
    int i0 = noff[v], i1 = noff[v + 1];
    float acc[8] = {0.f, 0.f, 0.f, 0.f, 0.f, 0.f, 0.f, 0.f};
    int i = i0;
    for (; i + 3 < i1; i += 4) {
        int e0 = node_e[i + 0], e1 = node_e[i + 1], e2 = node_e[i + 2], e3 = node_e[i + 3];
        u16x8 r0 = *(const u16x8*)(Y + (size_t)e0 * 256 + col);
        u16x8 r1 = *(const u16x8*)(Y + (size_t)e1 * 256 + col);
        u16x8 r2 = *(const u16x8*)(Y + (size_t)e2 * 256 + col);
        u16x8 r3 = *(const u16x8*)(Y + (size_t)e3 * 256 + col);
#pragma unroll
        for (int q = 0; q < 8; ++q) {
            acc[q] += bf2f(r0[q]);
            acc[q] += bf2f(r1[q]);
            acc[q] += bf2f(r2[q]);
            acc[q] += bf2f(r3[q]);
        }
    }
    for (; i < i1; ++i) {
        int e = node_e[i];
        u16x8 r = *(const u16x8*)(Y + (size_t)e * 256 + col);
#pragma unroll
        for (int q = 0; q < 8; ++q) acc[q] += bf2f(r[q]);
    }
    float inv = (i1 > i0) ? 1.0f / (float)(i1 - i0) : 0.f;
    size_t base = (size_t)v * 256 + col;
    float4 xiA = *(const float4*)(Xinit + base);
    float4 xiB = *(const float4*)(Xinit + base + 4);
    float x8[8] = {xiA.x, xiA.y, xiA.z, xiA.w, xiB.x, xiB.y, xiB.z, xiB.w};
    u16x8 hv, lv;
#pragma unroll
    for (int q = 0; q < 8; ++q) {
        float mm = acc[q] * inv;
        float oq = (mm > 0.f ? mm : expm1f(mm)) + x8[q];
        u16 h = f2bf(oq);
        hv[q] = h;
        lv[q] = f2bf(oq - bf2f(h));
    }
    *(u16x8*)(Hhi + base) = hv;
    *(u16x8*)(Hlo + base) = lv;
}

// =============== hyperconv ===============
__global__ void deinv_kernel(const int* __restrict__ eoff, const int* __restrict__ edge_v,
                             const int* __restrict__ noff, float* __restrict__ Deinv, int M)
{
    int e = blockIdx.x * blockDim.x + threadIdx.x;
    if (e >= M) return;
    int j0 = eoff[e], j1 = eoff[e + 1];
    float s = 0.f;
    for (int j = j0; j < j1; ++j) {
        int v = edge_v[j];
        s += (float)(noff[v + 1] - noff[v]);
    }
    float De = s / ((float)(j1 - j0) + 1.0f);
    Deinv[e] = De > 0.f ? rsqrtf(De) : 1.0f;
}

__device__ __forceinline__ void add4(float4& a, const float4& x) {
    a.x += x.x; a.y += x.y; a.z += x.z; a.w += x.w;
}

// Yh[e,:] = Deinv[e] * mean_j Xc[edge_v[j],:]  — 32 lanes/edge, float4/lane
__global__ void yh_kernel(const float* __restrict__ Xc,
                          const int* __restrict__ eoff, const int* __restrict__ edge_v,
                          const float* __restrict__ Deinv, float* __restrict__ Yh, int M)
{
    int e = blockIdx.x * 8 + (threadIdx.x >> 5);
    if (e >= M) return;
    int sl = threadIdx.x & 31;
    int col = sl * 4;
    int j0 = eoff[e], j1 = eoff[e + 1];
    float4 acc = make_float4(0.f, 0.f, 0.f, 0.f);
    int j = j0;
    for (; j + 3 < j1; j += 4) {
        int v0 = edge_v[j + 0], v1 = edge_v[j + 1], v2 = edge_v[j + 2], v3 = edge_v[j + 3];
        float4 x0 = *(const float4*)(Xc + (size_t)v0 * 128 + col);
        float4 x1 = *(const float4*)(Xc + (size_t)v1 * 128 + col);
        float4 x2 = *(const float4*)(Xc + (size_t)v2 * 128 + col);
        float4 x3 = *(const float4*)(Xc + (size_t)v3 * 128 + col);
        add4(acc, x0); add4(acc, x1); add4(acc, x2); add4(acc, x3);
    }
    for (; j < j1; ++j) {
        int v = edge_v[j];
        float4 x = *(const float4*)(Xc + (size_t)v * 128 + col);
        add4(acc, x);
    }
    float sc = ((j1 > j0) ? 1.0f / (float)(j1 - j0) : 0.f) * Deinv[e];
    float4 o;
    o.x = acc.x * sc; o.y = acc.y * sc; o.z = acc.z * sc; o.w = acc.w * sc;
    *(float4*)(Yh + (size_t)e * 128 + col) = o;
}

// out[v,:] = Dv^-0.5 * sum_i Yh[node_e[i],:]  — 32 lanes/node, float4/lane
__global__ void xo_final_kernel(const float* __restrict__ Yh,
                                const int* __restrict__ noff, const int* __restrict__ node_e,
                                float* __restrict__ out, int N)
{
    int v = blockIdx.x * 8 + (threadIdx.x >> 5);
    if (v >= N) return;
    int sl = threadIdx.x & 31;
    int col = sl * 4;
    int i0 = noff[v], i1 = noff[v + 1];
    float4 acc = make_float4(0.f, 0.f, 0.f, 0.f);
    int i = i0;
    for (; i + 3 < i1; i += 4) {
        int e0 = node_e[i + 0], e1 = node_e[i + 1], e2 = node_e[i + 2], e3 = node_e[i + 3];
        float4 y0 = *(const float4*)(Yh + (size_t)e0 * 128 + col);
        float4 y1 = *(const float4*)(Yh + (size_t)e1 * 128 + col);
        float4 y2 = *(const float4*)(Yh + (size_t)e2 * 128 + col);
        float4 y3 = *(const float4*)(Yh + (size_t)e3 * 128 + col);
        add4(acc, y0); add4(acc, y1); add4(acc, y2); add4(acc, y3);
    }
    for (; i < i1; ++i) {
        int e = node_e[i];
        float4 y = *(const float4*)(Yh + (size_t)e * 128 + col);
        add4(acc, y);
    }
    float sc = (i1 > i0) ? rsqrtf((float)(i1 - i0)) : 0.f;
    float4 o;
    o.x = acc.x * sc; o.y = acc.y * sc; o.z = acc.z * sc; o.w = acc.w * sc;
    *(float4*)(out + (size_t)v * 128 + col) = o;
}

// =============== host-side ===============
static void gemm(const u16* Ahi, const u16* Alo, int lda,
                 const u16* Bhi, const u16* Blo, int ldb,
                 const float* bias, void* C, int M, int Nc, int K, int out_bf16,
                 hipStream_t stream)
{
    dim3 g((M + 127) / 128, Nc / 128);
    gemm_mfma_kernel<<<g, 256, 0, stream>>>(Ahi, Alo, lda, Bhi, Blo, ldb, bias, C, M, Nc, K, out_bf16);
}

static void run_layer(u16* Ahi, u16* Alo, int K,
                      const u16* WxThi, const u16* WxTlo, const float* bx,
                      const u16* WvThi, const u16* WvTlo, const float* bv,
                      const float* a,
                      const u16* WtThi, const u16* WtTlo, const float* bt,
                      u16* Aehi, u16* Aelo,
                      float* Xinit, u16* Xfeatb, u16* Ybufb, float* score,
                      const int* eoff, const int* edge_v,
                      const int* noff, const int* node_e,
                      int N, int M, hipStream_t stream)
{
    gemm(Ahi, Alo, K, WxThi, WxTlo, K, bx, Xinit, N, 256, K, 0, stream);
    gemm(Ahi, Alo, K, WvThi, WvTlo, K, bv, Xfeatb, N, 256, K, 1, stream);
    score_kernel<<<(N + 3) / 4, 256, 0, stream>>>(Xfeatb, a, score, N);
    v2e_fused_kernel<<<(M + 7) / 8, 256, 0, stream>>>(Xfeatb, score, eoff, edge_v, Aehi, Aelo, M);
    gemm(Aehi, Aelo, 320, WtThi, WtTlo, 320, bt, Ybufb, M, 256, 320, 1, stream);
    e2v_finish_kernel<<<(N + 7) / 8, 256, 0, stream>>>(Ybufb, noff, node_e, Xinit, Ahi, Alo, N);
}

extern "C" void kernel_launch(void* const* d_in, const int* in_sizes, int n_in,
                              void* d_out, int out_size, void* d_ws, size_t ws_size,
                              hipStream_t stream)
{
    const float* X   = (const float*)d_in[0];
    const int*   V   = (const int*)d_in[1];
    const int*   E   = (const int*)d_in[2];
    const float* S   = (const float*)d_in[3];
    const float* Wx0 = (const float*)d_in[4];  const float* bx0 = (const float*)d_in[5];
    const float* Wv0 = (const float*)d_in[6];  const float* bv0 = (const float*)d_in[7];
    const float* a0  = (const float*)d_in[8];
    const float* Wt0 = (const float*)d_in[9];  const float* bt0 = (const float*)d_in[10];
    const float* Wx1 = (const float*)d_in[11]; const float* bx1 = (const float*)d_in[12];
    const float* Wv1 = (const float*)d_in[13]; const float* bv1 = (const float*)d_in[14];
    const float* a1  = (const float*)d_in[15];
    const float* Wt1 = (const float*)d_in[16]; const float* bt1 = (const float*)d_in[17];
    const float* Wf  = (const float*)d_in[18]; const float* bf  = (const float*)d_in[19];

    int N   = in_sizes[0] / 128;
    int NNZ = in_sizes[1];
    int M   = in_sizes[3] / 64;

    float* ws = (float*)d_ws;
    size_t off = 0;
    float* Xinit = ws + off; off += (size_t)N * 256;   // also Yh [M,128] fp32 in hyperconv
    float* Xfeat = ws + off; off += (size_t)N * 256;   // region reused: Xfeatb/Ybufb bf16; Xc [N,128] fp32
    u16*   Xfeatb = (u16*)Xfeat;
    u16*   Ybufb  = (u16*)Xfeat;      // Xfeatb dead when Ybuf GEMM runs
    u16* Ahi  = (u16*)(ws + off); off += (size_t)N * 128;  // N*256 u16
    u16* Alo  = (u16*)(ws + off); off += (size_t)N * 128;
    u16* Aehi = (u16*)(ws + off); off += (size_t)M * 160;  // M*320 u16
    u16* Aelo = (u16*)(ws + off); off += (size_t)M * 160;
    u16* WxT0h = (u16*)(ws + off); off += (size_t)(256 * 128) / 2;
    u16* WxT0l = (u16*)(ws + off); off += (size_t)(256 * 128) / 2;
    u16* WvT0h = (u16*)(ws + off); off += (size_t)(256 * 128) / 2;
    u16* WvT0l = (u16*)(ws + off); off += (size_t)(256 * 128) / 2;
    u16* WtT0h = (u16*)(ws + off); off += (size_t)(256 * 320) / 2;
    u16* WtT0l = (u16*)(ws + off); off += (size_t)(256 * 320) / 2;
    u16* WxT1h = (u16*)(ws + off); off += (size_t)(256 * 256) / 2;
    u16* WxT1l = (u16*)(ws + off); off += (size_t)(256 * 256) / 2;
    u16* WvT1h = (u16*)(ws + off); off += (size_t)(256 * 256) / 2;
    u16* WvT1l = (u16*)(ws + off); off += (size_t)(256 * 256) / 2;
    u16* WtT1h = (u16*)(ws + off); off += (size_t)(256 * 320) / 2;
    u16* WtT1l = (u16*)(ws + off); off += (size_t)(256 * 320) / 2;
    u16* WfTh  = (u16*)(ws + off); off += (size_t)(128 * 256) / 2;
    u16* WfTl  = (u16*)(ws + off); off += (size_t)(128 * 256) / 2;
    float* score = ws + off; off += (size_t)N;
    float* Deinv = ws + off; off += (size_t)M;
    int* eoff   = (int*)(ws + off); off += (size_t)(M + 1);
    int* ecnt   = (int*)(ws + off); off += (size_t)M;
    int* ecur   = (int*)(ws + off); off += (size_t)M;
    int* psumE  = (int*)(ws + off); off += 64;
    int* edge_v = (int*)(ws + off); off += (size_t)NNZ;
    int* noff   = (int*)(ws + off); off += (size_t)(N + 1);
    int* ncnt   = (int*)(ws + off); off += (size_t)N;
    int* ncur   = (int*)(ws + off); off += (size_t)N;
    int* psumN  = (int*)(ws + off); off += 64;
    int* node_e = (int*)(ws + off); off += (size_t)NNZ;

    // ---- CSR build (parallel scan) ----
    hipMemsetAsync(ecnt, 0, (size_t)M * 4, stream);
    hipMemsetAsync(ncnt, 0, (size_t)N * 4, stream);
    count_kernel<<<(NNZ + 255) / 256, 256, 0, stream>>>(V, E, ecnt, ncnt, NNZ);
    int nbE = (M + 1023) / 1024, nbN = (N + 1023) / 1024;
    scan_part1<<<nbE, 256, 0, stream>>>(ecnt, eoff, psumE, M);
    scan_part1<<<nbN, 256, 0, stream>>>(ncnt, noff, psumN, N);
    scan_part2<<<nbE, 256, 0, stream>>>(ecnt, eoff, psumE, ecur, M);
    scan_part2<<<nbN, 256, 0, stream>>>(ncnt, noff, psumN, ncur, N);
    fill_kernel<<<(NNZ + 255) / 256, 256, 0, stream>>>(V, E, ecur, ncur, edge_v, node_e, NNZ);

    // ---- input splits ----
    split4_kernel<<<((N * 128 / 4) + 255) / 256, 256, 0, stream>>>(X, Ahi, Alo, N * 128 / 4);
    s_split_kernel<<<((M * 64) + 255) / 256, 256, 0, stream>>>(S, Aehi, Aelo, M);

    // ---- weight transpose+split ----
    wsplitT_kernel<<<(128 * 256 + 255) / 256, 256, 0, stream>>>(Wx0, WxT0h, WxT0l, 128, 8);
    wsplitT_kernel<<<(128 * 256 + 255) / 256, 256, 0, stream>>>(Wv0, WvT0h, WvT0l, 128, 8);
    wsplitT_kernel<<<(320 * 256 + 255) / 256, 256, 0, stream>>>(Wt0, WtT0h, WtT0l, 320, 8);
    wsplitT_kernel<<<(256 * 256 + 255) / 256, 256, 0, stream>>>(Wx1, WxT1h, WxT1l, 256, 8);
    wsplitT_kernel<<<(256 * 256 + 255) / 256, 256, 0, stream>>>(Wv1, WvT1h, WvT1l, 256, 8);
    wsplitT_kernel<<<(320 * 256 + 255) / 256, 256, 0, stream>>>(Wt1, WtT1h, WtT1l, 320, 8);
    wsplitT_kernel<<<(256 * 128 + 255) / 256, 256, 0, stream>>>(Wf, WfTh, WfTl, 256, 7);

    // ---- layers ----
    run_layer(Ahi, Alo, 128, WxT0h, WxT0l, bx0, WvT0h, WvT0l, bv0, a0,
              WtT0h, WtT0l, bt0, Aehi, Aelo, Xinit, Xfeatb, Ybufb, score,
              eoff, edge_v, noff, node_e, N, M, stream);
    run_layer(Ahi, Alo, 256, WxT1h, WxT1l, bx1, WvT1h, WvT1l, bv1, a1,
              WtT1h, WtT1l, bt1, Aehi, Aelo, Xinit, Xfeatb, Ybufb, score,
              eoff, edge_v, noff, node_e, N, M, stream);

    // ---- hyperconv (fp32 end-to-end: direct output path) ----
    float* Xc = Xfeat;   // [N,128] fp32 (bf16 intermediates dead)
    float* Yh = Xinit;   // [M,128] fp32 (Xinit dead)
    gemm(Ahi, Alo, 256, WfTh, WfTl, 256, bf, Xc, N, 128, 256, 0, stream);
    deinv_kernel<<<(M + 255) / 256, 256, 0, stream>>>(eoff, edge_v, noff, Deinv, M);
    yh_kernel<<<(M + 7) / 8, 256, 0, stream>>>(Xc, eoff, edge_v, Deinv, Yh, M);
    xo_final_kernel<<<(N + 7) / 8, 256, 0, stream>>>(Yh, noff, node_e, (float*)d_out, N);
}

// Round 8
// 665.077 us; speedup vs baseline: 1.2562x; 1.0806x over previous
//
#include <hip/hip_runtime.h>
#include <hip/hip_bf16.h>

typedef unsigned short u16;
typedef __attribute__((ext_vector_type(4))) u16 u16x4;
typedef __attribute__((ext_vector_type(8))) u16 u16x8;
typedef __attribute__((ext_vector_type(8))) __bf16 bf16x8;
typedef __attribute__((ext_vector_type(4))) float f32x4;

__device__ __forceinline__ u16 f2bf(float x) {
    unsigned u = __float_as_uint(x);
    unsigned r = u + 0x7FFF + ((u >> 16) & 1);
    return (u16)(r >> 16);
}
__device__ __forceinline__ float bf2f(u16 h) {
    return __uint_as_float(((unsigned)h) << 16);
}

__device__ __forceinline__ void gl_lds16(const void* g, void* l) {
    __builtin_amdgcn_global_load_lds(
        (const __attribute__((address_space(1))) void*)g,
        (__attribute__((address_space(3))) void*)l, 16, 0, 0);
}

// =============== bf16-activation x split-bf16-weight MFMA GEMM ===============
// C[M,Nc] = A[M,K] @ B^T[Nc,K] + bias.  A: plain bf16.  B: (hi,lo) bf16 pair.
// acc = A*Bhi + A*Blo   (weight kept near-fp32; activation bf16-rounded)
// out_bf16: 0 -> fp32 C, 1 -> bf16 (u16) C
__global__ __launch_bounds__(256) void gemm_mfma_kernel(
    const u16* __restrict__ A, int lda,
    const u16* __restrict__ Bhi, const u16* __restrict__ Blo, int ldb,
    const float* __restrict__ bias, void* __restrict__ C,
    int M, int Nc, int K, int out_bf16)
{
    __shared__ __align__(16) u16 lds[3 * 4096];
    u16* sA   = lds;
    u16* sBhi = lds + 4096;
    u16* sBlo = lds + 8192;

    int tid = threadIdx.x;
    int wave = tid >> 6, lane = tid & 63;
    int row0 = blockIdx.x * 128, col0 = blockIdx.y * 128;

    long gA[2], gB[2];
    int sOff[2];
#pragma unroll
    for (int r = 0; r < 2; ++r) {
        int trow = r * 64 + wave * 16 + (lane >> 2);
        int chunk = (lane & 3) ^ ((trow >> 2) & 3);
        int arow = min(row0 + trow, M - 1);
        gA[r] = (long)arow * lda + chunk * 8;
        gB[r] = (long)(col0 + trow) * ldb + chunk * 8;
        sOff[r] = (r * 64 + wave * 16) * 32;
    }

    int m16 = lane & 15, quad = lane >> 4;
    int offA[4], offB[4];
#pragma unroll
    for (int i = 0; i < 4; ++i) {
        int ra = (wave & 1) * 64 + i * 16 + m16;
        offA[i] = ra * 32 + ((quad ^ ((ra >> 2) & 3)) * 8);
        int rb = (wave >> 1) * 64 + i * 16 + m16;
        offB[i] = rb * 32 + ((quad ^ ((rb >> 2) & 3)) * 8);
    }

    f32x4 acc[4][4];
#pragma unroll
    for (int i = 0; i < 4; ++i)
#pragma unroll
        for (int j = 0; j < 4; ++j) {
            f32x4 z = {0.f, 0.f, 0.f, 0.f};
            acc[i][j] = z;
        }

    int nkb = K >> 5;
    for (int kb = 0; kb < nkb; ++kb) {
#pragma unroll
        for (int r = 0; r < 2; ++r) {
            gl_lds16(A + gA[r], sA + sOff[r]);
            gl_lds16(Bhi + gB[r], sBhi + sOff[r]);
            gl_lds16(Blo + gB[r], sBlo + sOff[r]);
        }
        __syncthreads();
        bf16x8 av[4], bh[4], bl[4];
#pragma unroll
        for (int i = 0; i < 4; ++i) {
            av[i] = *(const bf16x8*)(sA + offA[i]);
            bh[i] = *(const bf16x8*)(sBhi + offB[i]);
            bl[i] = *(const bf16x8*)(sBlo + offB[i]);
        }
#pragma unroll
        for (int i = 0; i < 4; ++i)
#pragma unroll
            for (int j = 0; j < 4; ++j) {
                acc[i][j] = __builtin_amdgcn_mfma_f32_16x16x32_bf16(av[i], bh[j], acc[i][j], 0, 0, 0);
                acc[i][j] = __builtin_amdgcn_mfma_f32_16x16x32_bf16(av[i], bl[j], acc[i][j], 0, 0, 0);
            }
        __syncthreads();
#pragma unroll
        for (int r = 0; r < 2; ++r) { gA[r] += 32; gB[r] += 32; }
    }

    int wm = (wave & 1) * 64, wn = (wave >> 1) * 64;
    if (out_bf16) {
        u16* Cb = (u16*)C;
#pragma unroll
        for (int j = 0; j < 4; ++j) {
            int col = col0 + wn + j * 16 + m16;
            float bj = bias[col];
#pragma unroll
            for (int i = 0; i < 4; ++i) {
#pragma unroll
                for (int rr = 0; rr < 4; ++rr) {
                    int row = row0 + wm + i * 16 + quad * 4 + rr;
                    if (row < M) Cb[(size_t)row * Nc + col] = f2bf(acc[i][j][rr] + bj);
                }
            }
        }
    } else {
        float* Cf = (float*)C;
#pragma unroll
        for (int j = 0; j < 4; ++j) {
            int col = col0 + wn + j * 16 + m16;
            float bj = bias[col];
#pragma unroll
            for (int i = 0; i < 4; ++i) {
#pragma unroll
                for (int rr = 0; rr < 4; ++rr) {
                    int row = row0 + wm + i * 16 + quad * 4 + rr;
                    if (row < M) Cf[(size_t)row * Nc + col] = acc[i][j][rr] + bj;
                }
            }
        }
    }
}

// =============== conversion kernels ===============
// fp32 -> bf16, 4 elems/thread
__global__ void cast4_kernel(const float* __restrict__ src, u16* __restrict__ dst, int n4)
{
    int i = blockIdx.x * blockDim.x + threadIdx.x;
    if (i >= n4) return;
    float4 x = ((const float4*)src)[i];
    u16x4 h;
    h.x = f2bf(x.x); h.y = f2bf(x.y); h.z = f2bf(x.z); h.w = f2bf(x.w);
    *(u16x4*)(dst + (size_t)i * 4) = h;
}

// S[M,64] -> bf16 into cols 256..319 of the [M,320]-strided edge A-buffer
__global__ void s_cast_kernel(const float* __restrict__ S, u16* __restrict__ Ae, int M)
{
    int i = blockIdx.x * blockDim.x + threadIdx.x;
    if (i >= M * 64) return;
    int e = i >> 6, c = i & 63;
    Ae[(size_t)e * 320 + 256 + c] = f2bf(S[i]);
}

// W[K,Nc] fp32 -> W^T (hi,lo) bf16 [Nc,K].  Nc = 2^ncShift.
__global__ void wsplitT_kernel(const float* __restrict__ W, u16* __restrict__ Whi,
                               u16* __restrict__ Wlo, int K, int ncShift)
{
    int Nc = 1 << ncShift;
    int idx = blockIdx.x * blockDim.x + threadIdx.x;
    if (idx >= K * Nc) return;
    int k = idx >> ncShift, n = idx & (Nc - 1);
    float x = W[idx];
    u16 h = f2bf(x);
    u16 l = f2bf(x - bf2f(h));
    Whi[(size_t)n * K + k] = h;
    Wlo[(size_t)n * K + k] = l;
}

// =============== CSR build ===============
// 4 incidences/thread -> 8 independent atomics in flight
__global__ void count_kernel(const int* __restrict__ V, const int* __restrict__ E,
                             int* ecnt, int* ncnt, int nnz)
{
    int k0 = (blockIdx.x * blockDim.x + threadIdx.x) * 4;
    if (k0 >= nnz) return;
    int kmax = min(nnz - k0, 4);
    int vv[4], ee[4];
    if (kmax == 4) {
        int4 v4 = *(const int4*)(V + k0);
        int4 e4 = *(const int4*)(E + k0);
        vv[0] = v4.x; vv[1] = v4.y; vv[2] = v4.z; vv[3] = v4.w;
        ee[0] = e4.x; ee[1] = e4.y; ee[2] = e4.z; ee[3] = e4.w;
    } else {
        for (int q = 0; q < kmax; ++q) { vv[q] = V[k0 + q]; ee[q] = E[k0 + q]; }
    }
    for (int q = 0; q < kmax; ++q) atomicAdd(&ecnt[ee[q]], 1);
    for (int q = 0; q < kmax; ++q) atomicAdd(&ncnt[vv[q]], 1);
}

__global__ __launch_bounds__(256) void scan_part1(const int* __restrict__ cnt,
                                                  int* __restrict__ off,
                                                  int* __restrict__ psum, int n)
{
    __shared__ int tsum[256];
    int base = blockIdx.x * 1024;
    int t = threadIdx.x;
    int idx0 = base + t * 4;
    int4 c = make_int4(0, 0, 0, 0);
    if (idx0 + 3 < n) c = *(const int4*)(cnt + idx0);
    else {
        if (idx0 + 0 < n) c.x = cnt[idx0 + 0];
        if (idx0 + 1 < n) c.y = cnt[idx0 + 1];
        if (idx0 + 2 < n) c.z = cnt[idx0 + 2];
        if (idx0 + 3 < n) c.w = cnt[idx0 + 3];
    }
    int s = c.x + c.y + c.z + c.w;
    tsum[t] = s;
    __syncthreads();
    for (int o = 1; o < 256; o <<= 1) {
        int v = (t >= o) ? tsum[t - o] : 0;
        __syncthreads();
        tsum[t] += v;
        __syncthreads();
    }
    int run = tsum[t] - s;
    run += c.x; if (idx0 + 0 < n) off[idx0 + 1] = run;
    run += c.y; if (idx0 + 1 < n) off[idx0 + 2] = run;
    run += c.z; if (idx0 + 2 < n) off[idx0 + 3] = run;
    run += c.w; if (idx0 + 3 < n) off[idx0 + 4] = run;
    if (t == 255) psum[blockIdx.x] = tsum[255];
}

__global__ __launch_bounds__(256) void scan_part2(const int* __restrict__ cnt,
                                                  int* __restrict__ off,
                                                  const int* __restrict__ psum,
                                                  int* __restrict__ cur, int n)
{
    __shared__ int bpref;
    int t = threadIdx.x;
    int b = blockIdx.x;
    if (t < 64) {
        int s = (t < b) ? psum[t] : 0;
#pragma unroll
        for (int o = 32; o; o >>= 1) s += __shfl_xor(s, o);
        if (t == 0) {
            bpref = s;
            if (b == 0) off[0] = 0;
        }
    }
    __syncthreads();
    int base = b * 1024 + t * 4;
#pragma unroll
    for (int q = 0; q < 4; ++q) {
        int i = base + q;
        if (i < n) {
            int inc = off[i + 1] + bpref;
            off[i + 1] = inc;
            cur[i] = inc - cnt[i];
        }
    }
}

// 4 incidences/thread -> 8 independent atomics in flight
__global__ void fill_kernel(const int* __restrict__ V, const int* __restrict__ E,
                            int* ecur, int* ncur, int* edge_v, int* node_e, int nnz)
{
    int k0 = (blockIdx.x * blockDim.x + threadIdx.x) * 4;
    if (k0 >= nnz) return;
    int kmax = min(nnz - k0, 4);
    int vv[4], ee[4], js[4], is_[4];
    if (kmax == 4) {
        int4 v4 = *(const int4*)(V + k0);
        int4 e4 = *(const int4*)(E + k0);
        vv[0] = v4.x; vv[1] = v4.y; vv[2] = v4.z; vv[3] = v4.w;
        ee[0] = e4.x; ee[1] = e4.y; ee[2] = e4.z; ee[3] = e4.w;
    } else {
        for (int q = 0; q < kmax; ++q) { vv[q] = V[k0 + q]; ee[q] = E[k0 + q]; }
    }
    for (int q = 0; q < kmax; ++q) js[q] = atomicAdd(&ecur[ee[q]], 1);
    for (int q = 0; q < kmax; ++q) is_[q] = atomicAdd(&ncur[vv[q]], 1);
    for (int q = 0; q < kmax; ++q) edge_v[js[q]] = vv[q];
    for (int q = 0; q < kmax; ++q) node_e[is_[q]] = ee[q];
}

// =============== graph kernels ===============
// score = Xfeat(bf16) @ a   (wave per row, 4 cols/lane)
__global__ void score_kernel(const u16* __restrict__ Xf, const float* __restrict__ a,
                             float* __restrict__ score, int N)
{
    int row = blockIdx.x * (blockDim.x >> 6) + (threadIdx.x >> 6);
    int lane = threadIdx.x & 63;
    if (row >= N) return;
    u16x4 x = *(const u16x4*)(Xf + (size_t)row * 256 + lane * 4);
    float4 av = *(const float4*)(a + lane * 4);
    float p = bf2f(x.x) * av.x + bf2f(x.y) * av.y + bf2f(x.z) * av.z + bf2f(x.w) * av.w;
#pragma unroll
    for (int off = 32; off; off >>= 1) p += __shfl_down(p, off);
    if (lane == 0) score[row] = p;
}

__device__ __forceinline__ float lrelu(float s) { return s >= 0.f ? s : 0.2f * s; }

// fused segment softmax + weighted gather over bf16 Xfeat; 32 lanes/edge
// (2 edges/wave), 8 cols/lane; writes elu result bf16 into [M,320] edge buffer
__global__ void v2e_fused_kernel(const u16* __restrict__ Xf,
                                 const float* __restrict__ score,
                                 const int* __restrict__ eoff,
                                 const int* __restrict__ edge_v,
                                 u16* __restrict__ Ae, int M)
{
    int e = blockIdx.x * 8 + (threadIdx.x >> 5);
    if (e >= M) return;
    int sl = threadIdx.x & 31;
    int j0 = eoff[e], j1 = eoff[e + 1];
    float m = -INFINITY;
    for (int j = j0 + sl; j < j1; j += 32) m = fmaxf(m, lrelu(score[edge_v[j]]));
#pragma unroll
    for (int o = 16; o; o >>= 1) m = fmaxf(m, __shfl_xor(m, o));
    float sum = 0.f;
    for (int j = j0 + sl; j < j1; j += 32) sum += expf(lrelu(score[edge_v[j]]) - m);
#pragma unroll
    for (int o = 16; o; o >>= 1) sum += __shfl_xor(sum, o);
    float inv = (j1 > j0) ? 1.0f / sum : 0.f;

    float acc[8] = {0.f, 0.f, 0.f, 0.f, 0.f, 0.f, 0.f, 0.f};
    int col = sl * 8;
    int j = j0;
    for (; j + 3 < j1; j += 4) {
        int v0 = edge_v[j + 0], v1 = edge_v[j + 1], v2 = edge_v[j + 2], v3 = edge_v[j + 3];
        float s0 = score[v0], s1 = score[v1], s2 = score[v2], s3 = score[v3];
        u16x8 r0 = *(const u16x8*)(Xf + (size_t)v0 * 256 + col);
        u16x8 r1 = *(const u16x8*)(Xf + (size_t)v1 * 256 + col);
        u16x8 r2 = *(const u16x8*)(Xf + (size_t)v2 * 256 + col);
        u16x8 r3 = *(const u16x8*)(Xf + (size_t)v3 * 256 + col);
        float w0 = expf(lrelu(s0) - m) * inv;
        float w1 = expf(lrelu(s1) - m) * inv;
        float w2 = expf(lrelu(s2) - m) * inv;
        float w3 = expf(lrelu(s3) - m) * inv;
#pragma unroll
        for (int q = 0; q < 8; ++q) {
            acc[q] += bf2f(r0[q]) * w0;
            acc[q] += bf2f(r1[q]) * w1;
            acc[q] += bf2f(r2[q]) * w2;
            acc[q] += bf2f(r3[q]) * w3;
        }
    }
    for (; j < j1; ++j) {
        int v = edge_v[j];
        float ww = expf(lrelu(score[v]) - m) * inv;
        u16x8 r = *(const u16x8*)(Xf + (size_t)v * 256 + col);
#pragma unroll
        for (int q = 0; q < 8; ++q) acc[q] += bf2f(r[q]) * ww;
    }
    u16x8 hv;
#pragma unroll
    for (int q = 0; q < 8; ++q) {
        float vq = acc[q];
        vq = vq > 0.f ? vq : expm1f(vq);
        hv[q] = f2bf(vq);
    }
    *(u16x8*)(Ae + (size_t)e * 320 + col) = hv;
}

// h[v,:] = elu(mean_i Y[node_e[i],:]) + Xinit[v,:] -> bf16
// Y bf16; 32 lanes/node (2 nodes/wave), 8 cols/lane, 4-wide index unroll
__global__ void e2v_finish_kernel(const u16* __restrict__ Y,
                                  const int* __restrict__ noff,
                                  const int* __restrict__ node_e,
                                  const float* __restrict__ Xinit,
                                  u16* __restrict__ H, int N)
{
    int v = blockIdx.x * 8 + (threadIdx.x >> 5);
    if (v >= N) return;
    int sl = threadIdx.x & 31;
    int col = sl * 8;
    int i0 = noff[v], i1 = noff[v + 1];
    float acc[8] = {0.f, 0.f, 0.f, 0.f, 0.f, 0.f, 0.f, 0.f};
    int i = i0;
    for (; i + 3 < i1; i += 4) {
        int e0 = node_e[i + 0], e1 = node_e[i + 1], e2 = node_e[i + 2], e3 = node_e[i + 3];
        u16x8 r0 = *(const u16x8*)(Y + (size_t)e0 * 256 + col);
        u16x8 r1 = *(const u16x8*)(Y + (size_t)e1 * 256 + col);
        u16x8 r2 = *(const u16x8*)(Y + (size_t)e2 * 256 + col);
        u16x8 r3 = *(const u16x8*)(Y + (size_t)e3 * 256 + col);
#pragma unroll
        for (int q = 0; q < 8; ++q) {
            acc[q] += bf2f(r0[q]);
            acc[q] += bf2f(r1[q]);
            acc[q] += bf2f(r2[q]);
            acc[q] += bf2f(r3[q]);
        }
    }
    for (; i < i1; ++i) {
        int e = node_e[i];
        u16x8 r = *(const u16x8*)(Y + (size_t)e * 256 + col);
#pragma unroll
        for (int q = 0; q < 8; ++q) acc[q] += bf2f(r[q]);
    }
    float inv = (i1 > i0) ? 1.0f / (float)(i1 - i0) : 0.f;
    size_t base = (size_t)v * 256 + col;
    float4 xiA = *(const float4*)(Xinit + base);
    float4 xiB = *(const float4*)(Xinit + base + 4);
    float x8[8] = {xiA.x, xiA.y, xiA.z, xiA.w, xiB.x, xiB.y, xiB.z, xiB.w};
    u16x8 hv;
#pragma unroll
    for (int q = 0; q < 8; ++q) {
        float mm = acc[q] * inv;
        float oq = (mm > 0.f ? mm : expm1f(mm)) + x8[q];
        hv[q] = f2bf(oq);
    }
    *(u16x8*)(H + base) = hv;
}

// =============== hyperconv ===============
__global__ void deinv_kernel(const int* __restrict__ eoff, const int* __restrict__ edge_v,
                             const int* __restrict__ noff, float* __restrict__ Deinv, int M)
{
    int e = blockIdx.x * blockDim.x + threadIdx.x;
    if (e >= M) return;
    int j0 = eoff[e], j1 = eoff[e + 1];
    float s = 0.f;
    for (int j = j0; j < j1; ++j) {
        int v = edge_v[j];
        s += (float)(noff[v + 1] - noff[v]);
    }
    float De = s / ((float)(j1 - j0) + 1.0f);
    Deinv[e] = De > 0.f ? rsqrtf(De) : 1.0f;
}

__device__ __forceinline__ void add4(float4& a, const float4& x) {
    a.x += x.x; a.y += x.y; a.z += x.z; a.w += x.w;
}

// Yh[e,:] = Deinv[e] * mean_j Xc[edge_v[j],:]  — 32 lanes/edge, float4/lane
__global__ void yh_kernel(const float* __restrict__ Xc,
                          const int* __restrict__ eoff, const int* __restrict__ edge_v,
                          const float* __restrict__ Deinv, float* __restrict__ Yh, int M)
{
    int e = blockIdx.x * 8 + (threadIdx.x >> 5);
    if (e >= M) return;
    int sl = threadIdx.x & 31;
    int col = sl * 4;
    int j0 = eoff[e], j1 = eoff[e + 1];
    float4 acc = make_float4(0.f, 0.f, 0.f, 0.f);
    int j = j0;
    for (; j + 3 < j1; j += 4) {
        int v0 = edge_v[j + 0], v1 = edge_v[j + 1], v2 = edge_v[j + 2], v3 = edge_v[j + 3];
        float4 x0 = *(const float4*)(Xc + (size_t)v0 * 128 + col);
        float4 x1 = *(const float4*)(Xc + (size_t)v1 * 128 + col);
        float4 x2 = *(const float4*)(Xc + (size_t)v2 * 128 + col);
        float4 x3 = *(const float4*)(Xc + (size_t)v3 * 128 + col);
        add4(acc, x0); add4(acc, x1); add4(acc, x2); add4(acc, x3);
    }
    for (; j < j1; ++j) {
        int v = edge_v[j];
        float4 x = *(const float4*)(Xc + (size_t)v * 128 + col);
        add4(acc, x);
    }
    float sc = ((j1 > j0) ? 1.0f / (float)(j1 - j0) : 0.f) * Deinv[e];
    float4 o;
    o.x = acc.x * sc; o.y = acc.y * sc; o.z = acc.z * sc; o.w = acc.w * sc;
    *(float4*)(Yh + (size_t)e * 128 + col) = o;
}

// out[v,:] = Dv^-0.5 * sum_i Yh[node_e[i],:]  — 32 lanes/node, float4/lane
__global__ void xo_final_kernel(const float* __restrict__ Yh,
                                const int* __restrict__ noff, const int* __restrict__ node_e,
                                float* __restrict__ out, int N)
{
    int v = blockIdx.x * 8 + (threadIdx.x >> 5);
    if (v >= N) return;
    int sl = threadIdx.x & 31;
    int col = sl * 4;
    int i0 = noff[v], i1 = noff[v + 1];
    float4 acc = make_float4(0.f, 0.f, 0.f, 0.f);
    int i = i0;
    for (; i + 3 < i1; i += 4) {
        int e0 = node_e[i + 0], e1 = node_e[i + 1], e2 = node_e[i + 2], e3 = node_e[i + 3];
        float4 y0 = *(const float4*)(Yh + (size_t)e0 * 128 + col);
        float4 y1 = *(const float4*)(Yh + (size_t)e1 * 128 + col);
        float4 y2 = *(const float4*)(Yh + (size_t)e2 * 128 + col);
        float4 y3 = *(const float4*)(Yh + (size_t)e3 * 128 + col);
        add4(acc, y0); add4(acc, y1); add4(acc, y2); add4(acc, y3);
    }
    for (; i < i1; ++i) {
        int e = node_e[i];
        float4 y = *(const float4*)(Yh + (size_t)e * 128 + col);
        add4(acc, y);
    }
    float sc = (i1 > i0) ? rsqrtf((float)(i1 - i0)) : 0.f;
    float4 o;
    o.x = acc.x * sc; o.y = acc.y * sc; o.z = acc.z * sc; o.w = acc.w * sc;
    *(float4*)(out + (size_t)v * 128 + col) = o;
}

// =============== host-side ===============
static void gemm(const u16* A, int lda,
                 const u16* Bhi, const u16* Blo, int ldb,
                 const float* bias, void* C, int M, int Nc, int K, int out_bf16,
                 hipStream_t stream)
{
    dim3 g((M + 127) / 128, Nc / 128);
    gemm_mfma_kernel<<<g, 256, 0, stream>>>(A, lda, Bhi, Blo, ldb, bias, C, M, Nc, K, out_bf16);
}

static void run_layer(u16* A, int K,
                      const u16* WxThi, const u16* WxTlo, const float* bx,
                      const u16* WvThi, const u16* WvTlo, const float* bv,
                      const float* a,
                      const u16* WtThi, const u16* WtTlo, const float* bt,
                      u16* Ae,
                      float* Xinit, u16* Xfeatb, u16* Ybufb, float* score,
                      const int* eoff, const int* edge_v,
                      const int* noff, const int* node_e,
                      int N, int M, hipStream_t stream)
{
    gemm(A, K, WxThi, WxTlo, K, bx, Xinit, N, 256, K, 0, stream);
    gemm(A, K, WvThi, WvTlo, K, bv, Xfeatb, N, 256, K, 1, stream);
    score_kernel<<<(N + 3) / 4, 256, 0, stream>>>(Xfeatb, a, score, N);
    v2e_fused_kernel<<<(M + 7) / 8, 256, 0, stream>>>(Xfeatb, score, eoff, edge_v, Ae, M);
    gemm(Ae, 320, WtThi, WtTlo, 320, bt, Ybufb, M, 256, 320, 1, stream);
    e2v_finish_kernel<<<(N + 7) / 8, 256, 0, stream>>>(Ybufb, noff, node_e, Xinit, A, N);
}

extern "C" void kernel_launch(void* const* d_in, const int* in_sizes, int n_in,
                              void* d_out, int out_size, void* d_ws, size_t ws_size,
                              hipStream_t stream)
{
    const float* X   = (const float*)d_in[0];
    const int*   V   = (const int*)d_in[1];
    const int*   E   = (const int*)d_in[2];
    const float* S   = (const float*)d_in[3];
    const float* Wx0 = (const float*)d_in[4];  const float* bx0 = (const float*)d_in[5];
    const float* Wv0 = (const float*)d_in[6];  const float* bv0 = (const float*)d_in[7];
    const float* a0  = (const float*)d_in[8];
    const float* Wt0 = (const float*)d_in[9];  const float* bt0 = (const float*)d_in[10];
    const float* Wx1 = (const float*)d_in[11]; const float* bx1 = (const float*)d_in[12];
    const float* Wv1 = (const float*)d_in[13]; const float* bv1 = (const float*)d_in[14];
    const float* a1  = (const float*)d_in[15];
    const float* Wt1 = (const float*)d_in[16]; const float* bt1 = (const float*)d_in[17];
    const float* Wf  = (const float*)d_in[18]; const float* bf  = (const float*)d_in[19];

    int N   = in_sizes[0] / 128;
    int NNZ = in_sizes[1];
    int M   = in_sizes[3] / 64;

    float* ws = (float*)d_ws;
    size_t off = 0;
    float* Xinit = ws + off; off += (size_t)N * 256;   // also Yh [M,128] fp32 in hyperconv
    float* Xfeat = ws + off; off += (size_t)N * 256;   // Xfeatb/Ybufb bf16; Xc [N,128] fp32
    u16*   Xfeatb = (u16*)Xfeat;
    u16*   Ybufb  = (u16*)Xfeat;      // Xfeatb dead when Ybuf GEMM runs
    u16* Abuf = (u16*)(ws + off); off += (size_t)N * 128;  // N*256 u16: X cast / h bf16
    u16* Ae   = (u16*)(ws + off); off += (size_t)M * 160;  // M*320 u16 edge A-buffer
    u16* WxT0h = (u16*)(ws + off); off += (size_t)(256 * 128) / 2;
    u16* WxT0l = (u16*)(ws + off); off += (size_t)(256 * 128) / 2;
    u16* WvT0h = (u16*)(ws + off); off += (size_t)(256 * 128) / 2;
    u16* WvT0l = (u16*)(ws + off); off += (size_t)(256 * 128) / 2;
    u16* WtT0h = (u16*)(ws + off); off += (size_t)(256 * 320) / 2;
    u16* WtT0l = (u16*)(ws + off); off += (size_t)(256 * 320) / 2;
    u16* WxT1h = (u16*)(ws + off); off += (size_t)(256 * 256) / 2;
    u16* WxT1l = (u16*)(ws + off); off += (size_t)(256 * 256) / 2;
    u16* WvT1h = (u16*)(ws + off); off += (size_t)(256 * 256) / 2;
    u16* WvT1l = (u16*)(ws + off); off += (size_t)(256 * 256) / 2;
    u16* WtT1h = (u16*)(ws + off); off += (size_t)(256 * 320) / 2;
    u16* WtT1l = (u16*)(ws + off); off += (size_t)(256 * 320) / 2;
    u16* WfTh  = (u16*)(ws + off); off += (size_t)(128 * 256) / 2;
    u16* WfTl  = (u16*)(ws + off); off += (size_t)(128 * 256) / 2;
    float* score = ws + off; off += (size_t)N;
    float* Deinv = ws + off; off += (size_t)M;
    int* eoff   = (int*)(ws + off); off += (size_t)(M + 1);
    int* ecnt   = (int*)(ws + off); off += (size_t)M;
    int* ecur   = (int*)(ws + off); off += (size_t)M;
    int* psumE  = (int*)(ws + off); off += 64;
    int* edge_v = (int*)(ws + off); off += (size_t)NNZ;
    int* noff   = (int*)(ws + off); off += (size_t)(N + 1);
    int* ncnt   = (int*)(ws + off); off += (size_t)N;
    int* ncur   = (int*)(ws + off); off += (size_t)N;
    int* psumN  = (int*)(ws + off); off += 64;
    int* node_e = (int*)(ws + off); off += (size_t)NNZ;

    // ---- CSR build (parallel scan) ----
    hipMemsetAsync(ecnt, 0, (size_t)M * 4, stream);
    hipMemsetAsync(ncnt, 0, (size_t)N * 4, stream);
    count_kernel<<<((NNZ + 3) / 4 + 255) / 256, 256, 0, stream>>>(V, E, ecnt, ncnt, NNZ);
    int nbE = (M + 1023) / 1024, nbN = (N + 1023) / 1024;
    scan_part1<<<nbE, 256, 0, stream>>>(ecnt, eoff, psumE, M);
    scan_part1<<<nbN, 256, 0, stream>>>(ncnt, noff, psumN, N);
    scan_part2<<<nbE, 256, 0, stream>>>(ecnt, eoff, psumE, ecur, M);
    scan_part2<<<nbN, 256, 0, stream>>>(ncnt, noff, psumN, ncur, N);
    fill_kernel<<<((NNZ + 3) / 4 + 255) / 256, 256, 0, stream>>>(V, E, ecur, ncur, edge_v, node_e, NNZ);

    // ---- input casts ----
    cast4_kernel<<<((N * 128 / 4) + 255) / 256, 256, 0, stream>>>(X, Abuf, N * 128 / 4);
    s_cast_kernel<<<((M * 64) + 255) / 256, 256, 0, stream>>>(S, Ae, M);

    // ---- weight transpose+split ----
    wsplitT_kernel<<<(128 * 256 + 255) / 256, 256, 0, stream>>>(Wx0, WxT0h, WxT0l, 128, 8);
    wsplitT_kernel<<<(128 * 256 + 255) / 256, 256, 0, stream>>>(Wv0, WvT0h, WvT0l, 128, 8);
    wsplitT_kernel<<<(320 * 256 + 255) / 256, 256, 0, stream>>>(Wt0, WtT0h, WtT0l, 320, 8);
    wsplitT_kernel<<<(256 * 256 + 255) / 256, 256, 0, stream>>>(Wx1, WxT1h, WxT1l, 256, 8);
    wsplitT_kernel<<<(256 * 256 + 255) / 256, 256, 0, stream>>>(Wv1, WvT1h, WvT1l, 256, 8);
    wsplitT_kernel<<<(320 * 256 + 255) / 256, 256, 0, stream>>>(Wt1, WtT1h, WtT1l, 320, 8);
    wsplitT_kernel<<<(256 * 128 + 255) / 256, 256, 0, stream>>>(Wf, WfTh, WfTl, 256, 7);

    // ---- layers (h bf16 lands back in Abuf) ----
    run_layer(Abuf, 128, WxT0h, WxT0l, bx0, WvT0h, WvT0l, bv0, a0,
              WtT0h, WtT0l, bt0, Ae, Xinit, Xfeatb, Ybufb, score,
              eoff, edge_v, noff, node_e, N, M, stream);
    run_layer(Abuf, 256, WxT1h, WxT1l, bx1, WvT1h, WvT1l, bv1, a1,
              WtT1h, WtT1l, bt1, Ae, Xinit, Xfeatb, Ybufb, score,
              eoff, edge_v, noff, node_e, N, M, stream);

    // ---- hyperconv (fp32 output path) ----
    float* Xc = Xfeat;   // [N,128] fp32 (bf16 intermediates dead)
    float* Yh = Xinit;   // [M,128] fp32 (Xinit dead)
    gemm(Abuf, 256, WfTh, WfTl, 256, bf, Xc, N, 128, 256, 0, stream);
    deinv_kernel<<<(M + 255) / 256, 256, 0, stream>>>(eoff, edge_v, noff, Deinv, M);
    yh_kernel<<<(M + 7) / 8, 256, 0, stream>>>(Xc, eoff, edge_v, Deinv, Yh, M);
    xo_final_kernel<<<(N + 7) / 8, 256, 0, stream>>>(Yh, noff, node_e, (float*)d_out, N);
}

// Round 10
// 623.723 us; speedup vs baseline: 1.3395x; 1.0663x over previous
//
#include <hip/hip_runtime.h>
#include <hip/hip_bf16.h>

typedef unsigned short u16;
typedef __attribute__((ext_vector_type(4))) u16 u16x4;
typedef __attribute__((ext_vector_type(8))) u16 u16x8;
typedef __attribute__((ext_vector_type(8))) __bf16 bf16x8;
typedef __attribute__((ext_vector_type(4))) float f32x4;

__device__ __forceinline__ u16 f2bf(float x) {
    unsigned u = __float_as_uint(x);
    unsigned r = u + 0x7FFF + ((u >> 16) & 1);
    return (u16)(r >> 16);
}
__device__ __forceinline__ float bf2f(u16 h) {
    return __uint_as_float(((unsigned)h) << 16);
}

__device__ __forceinline__ void gl_lds16(const void* g, void* l) {
    __builtin_amdgcn_global_load_lds(
        (const __attribute__((address_space(1))) void*)g,
        (__attribute__((address_space(3))) void*)l, 16, 0, 0);
}

// =============== bf16-activation x split-bf16-weight MFMA GEMM ===============
// Out[M,Nc] = A[M,K] @ B^T[Nc,K] + bias.  A: plain bf16.  B: (hi,lo) pair.
// Split epilogue: cols [0,ncSplit) -> Cf fp32 (stride ncSplit, bias biasF);
//                 cols [ncSplit,Nc) -> Cb bf16 (stride Nc-ncSplit, bias biasB).
__global__ __launch_bounds__(256) void gemm_mfma_kernel(
    const u16* __restrict__ A, int lda,
    const u16* __restrict__ Bhi, const u16* __restrict__ Blo, int ldb,
    const float* __restrict__ biasF, const float* __restrict__ biasB,
    float* __restrict__ Cf, u16* __restrict__ Cb,
    int M, int Nc, int ncSplit, int K)
{
    __shared__ __align__(16) u16 lds[3 * 4096];
    u16* sA   = lds;
    u16* sBhi = lds + 4096;
    u16* sBlo = lds + 8192;

    int tid = threadIdx.x;
    int wave = tid >> 6, lane = tid & 63;
    int row0 = blockIdx.x * 128, col0 = blockIdx.y * 128;

    long gA[2], gB[2];
    int sOff[2];
#pragma unroll
    for (int r = 0; r < 2; ++r) {
        int trow = r * 64 + wave * 16 + (lane >> 2);
        int chunk = (lane & 3) ^ ((trow >> 2) & 3);
        int arow = min(row0 + trow, M - 1);
        gA[r] = (long)arow * lda + chunk * 8;
        gB[r] = (long)(col0 + trow) * ldb + chunk * 8;
        sOff[r] = (r * 64 + wave * 16) * 32;
    }

    int m16 = lane & 15, quad = lane >> 4;
    int offA[4], offB[4];
#pragma unroll
    for (int i = 0; i < 4; ++i) {
        int ra = (wave & 1) * 64 + i * 16 + m16;
        offA[i] = ra * 32 + ((quad ^ ((ra >> 2) & 3)) * 8);
        int rb = (wave >> 1) * 64 + i * 16 + m16;
        offB[i] = rb * 32 + ((quad ^ ((rb >> 2) & 3)) * 8);
    }

    f32x4 acc[4][4];
#pragma unroll
    for (int i = 0; i < 4; ++i)
#pragma unroll
        for (int j = 0; j < 4; ++j) {
            f32x4 z = {0.f, 0.f, 0.f, 0.f};
            acc[i][j] = z;
        }

    int nkb = K >> 5;
    for (int kb = 0; kb < nkb; ++kb) {
#pragma unroll
        for (int r = 0; r < 2; ++r) {
            gl_lds16(A + gA[r], sA + sOff[r]);
            gl_lds16(Bhi + gB[r], sBhi + sOff[r]);
            gl_lds16(Blo + gB[r], sBlo + sOff[r]);
        }
        __syncthreads();
        bf16x8 av[4], bh[4], bl[4];
#pragma unroll
        for (int i = 0; i < 4; ++i) {
            av[i] = *(const bf16x8*)(sA + offA[i]);
            bh[i] = *(const bf16x8*)(sBhi + offB[i]);
            bl[i] = *(const bf16x8*)(sBlo + offB[i]);
        }
#pragma unroll
        for (int i = 0; i < 4; ++i)
#pragma unroll
            for (int j = 0; j < 4; ++j) {
                acc[i][j] = __builtin_amdgcn_mfma_f32_16x16x32_bf16(av[i], bh[j], acc[i][j], 0, 0, 0);
                acc[i][j] = __builtin_amdgcn_mfma_f32_16x16x32_bf16(av[i], bl[j], acc[i][j], 0, 0, 0);
            }
        __syncthreads();
#pragma unroll
        for (int r = 0; r < 2; ++r) { gA[r] += 32; gB[r] += 32; }
    }

    int wm = (wave & 1) * 64, wn = (wave >> 1) * 64;
#pragma unroll
    for (int j = 0; j < 4; ++j) {
        int col = col0 + wn + j * 16 + m16;
        bool isB = (col >= ncSplit);
        float bj = isB ? biasB[col - ncSplit] : biasF[col];
        if (isB) {
            int cb = col - ncSplit;
            int strideB = Nc - ncSplit;
#pragma unroll
            for (int i = 0; i < 4; ++i)
#pragma unroll
                for (int rr = 0; rr < 4; ++rr) {
                    int row = row0 + wm + i * 16 + quad * 4 + rr;
                    if (row < M) Cb[(size_t)row * strideB + cb] = f2bf(acc[i][j][rr] + bj);
                }
        } else {
#pragma unroll
            for (int i = 0; i < 4; ++i)
#pragma unroll
                for (int rr = 0; rr < 4; ++rr) {
                    int row = row0 + wm + i * 16 + quad * 4 + rr;
                    if (row < M) Cf[(size_t)row * ncSplit + col] = acc[i][j][rr] + bj;
                }
        }
    }
}

// =============== prep kernels (merged) ===============
struct WJob { const float* W; u16* Whi; u16* Wlo; int K; int ncShift; };
struct WJobs { WJob j[7]; };

// one launch, blockIdx.y = job id; W[K,Nc] fp32 -> W^T (hi,lo) bf16 [Nc,K]
__global__ void wsplit_all_kernel(WJobs jobs)
{
    WJob jb = jobs.j[blockIdx.y];
    int Nc = 1 << jb.ncShift;
    int idx = blockIdx.x * blockDim.x + threadIdx.x;
    if (idx >= jb.K * Nc) return;
    int k = idx >> jb.ncShift, n = idx & (Nc - 1);
    float x = jb.W[idx];
    u16 h = f2bf(x);
    u16 l = f2bf(x - bf2f(h));
    jb.Whi[(size_t)n * jb.K + k] = h;
    jb.Wlo[(size_t)n * jb.K + k] = l;
}

// X -> bf16 Abuf (float4 granules) AND S -> bf16 cols 256.. of Ae, one launch
__global__ void cast_inputs_kernel(const float* __restrict__ X, u16* __restrict__ Abuf, int n4x,
                                   const float* __restrict__ S, u16* __restrict__ Ae, int nS)
{
    int id = blockIdx.x * blockDim.x + threadIdx.x;
    if (id < n4x) {
        float4 x = ((const float4*)X)[id];
        u16x4 h;
        h.x = f2bf(x.x); h.y = f2bf(x.y); h.z = f2bf(x.z); h.w = f2bf(x.w);
        *(u16x4*)(Abuf + (size_t)id * 4) = h;
    } else {
        int i = id - n4x;
        if (i < nS) {
            int e = i >> 6, c = i & 63;
            Ae[(size_t)e * 320 + 256 + c] = f2bf(S[i]);
        }
    }
}

// =============== CSR build ===============
__global__ void count_kernel(const int* __restrict__ V, const int* __restrict__ E,
                             int* ecnt, int* ncnt, int nnz)
{
    int k0 = (blockIdx.x * blockDim.x + threadIdx.x) * 4;
    if (k0 >= nnz) return;
    int kmax = min(nnz - k0, 4);
    int vv[4], ee[4];
    if (kmax == 4) {
        int4 v4 = *(const int4*)(V + k0);
        int4 e4 = *(const int4*)(E + k0);
        vv[0] = v4.x; vv[1] = v4.y; vv[2] = v4.z; vv[3] = v4.w;
        ee[0] = e4.x; ee[1] = e4.y; ee[2] = e4.z; ee[3] = e4.w;
    } else {
        for (int q = 0; q < kmax; ++q) { vv[q] = V[k0 + q]; ee[q] = E[k0 + q]; }
    }
    for (int q = 0; q < kmax; ++q) atomicAdd(&ecnt[ee[q]], 1);
    for (int q = 0; q < kmax; ++q) atomicAdd(&ncnt[vv[q]], 1);
}

__global__ __launch_bounds__(256) void scan_part1(const int* __restrict__ cnt,
                                                  int* __restrict__ off,
                                                  int* __restrict__ psum, int n)
{
    __shared__ int tsum[256];
    int base = blockIdx.x * 1024;
    int t = threadIdx.x;
    int idx0 = base + t * 4;
    int4 c = make_int4(0, 0, 0, 0);
    if (idx0 + 3 < n) c = *(const int4*)(cnt + idx0);
    else {
        if (idx0 + 0 < n) c.x = cnt[idx0 + 0];
        if (idx0 + 1 < n) c.y = cnt[idx0 + 1];
        if (idx0 + 2 < n) c.z = cnt[idx0 + 2];
        if (idx0 + 3 < n) c.w = cnt[idx0 + 3];
    }
    int s = c.x + c.y + c.z + c.w;
    tsum[t] = s;
    __syncthreads();
    for (int o = 1; o < 256; o <<= 1) {
        int v = (t >= o) ? tsum[t - o] : 0;
        __syncthreads();
        tsum[t] += v;
        __syncthreads();
    }
    int run = tsum[t] - s;
    run += c.x; if (idx0 + 0 < n) off[idx0 + 1] = run;
    run += c.y; if (idx0 + 1 < n) off[idx0 + 2] = run;
    run += c.z; if (idx0 + 2 < n) off[idx0 + 3] = run;
    run += c.w; if (idx0 + 3 < n) off[idx0 + 4] = run;
    if (t == 255) psum[blockIdx.x] = tsum[255];
}

__global__ __launch_bounds__(256) void scan_part2(const int* __restrict__ cnt,
                                                  int* __restrict__ off,
                                                  const int* __restrict__ psum,
                                                  int* __restrict__ cur, int n)
{
    __shared__ int bpref;
    int t = threadIdx.x;
    int b = blockIdx.x;
    if (t < 64) {
        int s = (t < b) ? psum[t] : 0;
#pragma unroll
        for (int o = 32; o; o >>= 1) s += __shfl_xor(s, o);
        if (t == 0) {
            bpref = s;
            if (b == 0) off[0] = 0;
        }
    }
    __syncthreads();
    int base = b * 1024 + t * 4;
#pragma unroll
    for (int q = 0; q < 4; ++q) {
        int i = base + q;
        if (i < n) {
            int inc = off[i + 1] + bpref;
            off[i + 1] = inc;
            cur[i] = inc - cnt[i];
        }
    }
}

__global__ void fill_kernel(const int* __restrict__ V, const int* __restrict__ E,
                            int* ecur, int* ncur, int* edge_v, int* node_e, int nnz)
{
    int k0 = (blockIdx.x * blockDim.x + threadIdx.x) * 4;
    if (k0 >= nnz) return;
    int kmax = min(nnz - k0, 4);
    int vv[4], ee[4], js[4], is_[4];
    if (kmax == 4) {
        int4 v4 = *(const int4*)(V + k0);
        int4 e4 = *(const int4*)(E + k0);
        vv[0] = v4.x; vv[1] = v4.y; vv[2] = v4.z; vv[3] = v4.w;
        ee[0] = e4.x; ee[1] = e4.y; ee[2] = e4.z; ee[3] = e4.w;
    } else {
        for (int q = 0; q < kmax; ++q) { vv[q] = V[k0 + q]; ee[q] = E[k0 + q]; }
    }
    for (int q = 0; q < kmax; ++q) js[q] = atomicAdd(&ecur[ee[q]], 1);
    for (int q = 0; q < kmax; ++q) is_[q] = atomicAdd(&ncur[vv[q]], 1);
    for (int q = 0; q < kmax; ++q) edge_v[js[q]] = vv[q];
    for (int q = 0; q < kmax; ++q) node_e[is_[q]] = ee[q];
}

// =============== graph kernels ===============
__global__ void score_kernel(const u16* __restrict__ Xf, const float* __restrict__ a,
                             float* __restrict__ score, int N)
{
    int row = blockIdx.x * (blockDim.x >> 6) + (threadIdx.x >> 6);
    int lane = threadIdx.x & 63;
    if (row >= N) return;
    u16x4 x = *(const u16x4*)(Xf + (size_t)row * 256 + lane * 4);
    float4 av = *(const float4*)(a + lane * 4);
    float p = bf2f(x.x) * av.x + bf2f(x.y) * av.y + bf2f(x.z) * av.z + bf2f(x.w) * av.w;
#pragma unroll
    for (int off = 32; off; off >>= 1) p += __shfl_down(p, off);
    if (lane == 0) score[row] = p;
}

__device__ __forceinline__ float lrelu(float s) { return s >= 0.f ? s : 0.2f * s; }

__global__ void v2e_fused_kernel(const u16* __restrict__ Xf,
                                 const float* __restrict__ score,
                                 const int* __restrict__ eoff,
                                 const int* __restrict__ edge_v,
                                 u16* __restrict__ Ae, int M)
{
    int e = blockIdx.x * 8 + (threadIdx.x >> 5);
    if (e >= M) return;
    int sl = threadIdx.x & 31;
    int j0 = eoff[e], j1 = eoff[e + 1];
    float m = -INFINITY;
    for (int j = j0 + sl; j < j1; j += 32) m = fmaxf(m, lrelu(score[edge_v[j]]));
#pragma unroll
    for (int o = 16; o; o >>= 1) m = fmaxf(m, __shfl_xor(m, o));
    float sum = 0.f;
    for (int j = j0 + sl; j < j1; j += 32) sum += expf(lrelu(score[edge_v[j]]) - m);
#pragma unroll
    for (int o = 16; o; o >>= 1) sum += __shfl_xor(sum, o);
    float inv = (j1 > j0) ? 1.0f / sum : 0.f;

    float acc[8] = {0.f, 0.f, 0.f, 0.f, 0.f, 0.f, 0.f, 0.f};
    int col = sl * 8;
    int j = j0;
    for (; j + 3 < j1; j += 4) {
        int v0 = edge_v[j + 0], v1 = edge_v[j + 1], v2 = edge_v[j + 2], v3 = edge_v[j + 3];
        float s0 = score[v0], s1 = score[v1], s2 = score[v2], s3 = score[v3];
        u16x8 r0 = *(const u16x8*)(Xf + (size_t)v0 * 256 + col);
        u16x8 r1 = *(const u16x8*)(Xf + (size_t)v1 * 256 + col);
        u16x8 r2 = *(const u16x8*)(Xf + (size_t)v2 * 256 + col);
        u16x8 r3 = *(const u16x8*)(Xf + (size_t)v3 * 256 + col);
        float w0 = expf(lrelu(s0) - m) * inv;
        float w1 = expf(lrelu(s1) - m) * inv;
        float w2 = expf(lrelu(s2) - m) * inv;
        float w3 = expf(lrelu(s3) - m) * inv;
#pragma unroll
        for (int q = 0; q < 8; ++q) {
            acc[q] += bf2f(r0[q]) * w0;
            acc[q] += bf2f(r1[q]) * w1;
            acc[q] += bf2f(r2[q]) * w2;
            acc[q] += bf2f(r3[q]) * w3;
        }
    }
    for (; j < j1; ++j) {
        int v = edge_v[j];
        float ww = expf(lrelu(score[v]) - m) * inv;
        u16x8 r = *(const u16x8*)(Xf + (size_t)v * 256 + col);
#pragma unroll
        for (int q = 0; q < 8; ++q) acc[q] += bf2f(r[q]) * ww;
    }
    u16x8 hv;
#pragma unroll
    for (int q = 0; q < 8; ++q) {
        float vq = acc[q];
        vq = vq > 0.f ? vq : expm1f(vq);
        hv[q] = f2bf(vq);
    }
    *(u16x8*)(Ae + (size_t)e * 320 + col) = hv;
}

__global__ void e2v_finish_kernel(const u16* __restrict__ Y,
                                  const int* __restrict__ noff,
                                  const int* __restrict__ node_e,
                                  const float* __restrict__ Xinit,
                                  u16* __restrict__ H, int N)
{
    int v = blockIdx.x * 8 + (threadIdx.x >> 5);
    if (v >= N) return;
    int sl = threadIdx.x & 31;
    int col = sl * 8;
    int i0 = noff[v], i1 = noff[v + 1];
    float acc[8] = {0.f, 0.f, 0.f, 0.f, 0.f, 0.f, 0.f, 0.f};
    int i = i0;
    for (; i + 3 < i1; i += 4) {
        int e0 = node_e[i + 0], e1 = node_e[i + 1], e2 = node_e[i + 2], e3 = node_e[i + 3];
        u16x8 r0 = *(const u16x8*)(Y + (size_t)e0 * 256 + col);
        u16x8 r1 = *(const u16x8*)(Y + (size_t)e1 * 256 + col);
        u16x8 r2 = *(const u16x8*)(Y + (size_t)e2 * 256 + col);
        u16x8 r3 = *(const u16x8*)(Y + (size_t)e3 * 256 + col);
#pragma unroll
        for (int q = 0; q < 8; ++q) {
            acc[q] += bf2f(r0[q]);
            acc[q] += bf2f(r1[q]);
            acc[q] += bf2f(r2[q]);
            acc[q] += bf2f(r3[q]);
        }
    }
    for (; i < i1; ++i) {
        int e = node_e[i];
        u16x8 r = *(const u16x8*)(Y + (size_t)e * 256 + col);
#pragma unroll
        for (int q = 0; q < 8; ++q) acc[q] += bf2f(r[q]);
    }
    float inv = (i1 > i0) ? 1.0f / (float)(i1 - i0) : 0.f;
    size_t base = (size_t)v * 256 + col;
    float4 xiA = *(const float4*)(Xinit + base);
    float4 xiB = *(const float4*)(Xinit + base + 4);
    float x8[8] = {xiA.x, xiA.y, xiA.z, xiA.w, xiB.x, xiB.y, xiB.z, xiB.w};
    u16x8 hv;
#pragma unroll
    for (int q = 0; q < 8; ++q) {
        float mm = acc[q] * inv;
        float oq = (mm > 0.f ? mm : expm1f(mm)) + x8[q];
        hv[q] = f2bf(oq);
    }
    *(u16x8*)(H + base) = hv;
}

// =============== hyperconv ===============
__global__ void deinv_kernel(const int* __restrict__ eoff, const int* __restrict__ edge_v,
                             const int* __restrict__ noff, float* __restrict__ Deinv, int M)
{
    int e = blockIdx.x * blockDim.x + threadIdx.x;
    if (e >= M) return;
    int j0 = eoff[e], j1 = eoff[e + 1];
    float s = 0.f;
    for (int j = j0; j < j1; ++j) {
        int v = edge_v[j];
        s += (float)(noff[v + 1] - noff[v]);
    }
    float De = s / ((float)(j1 - j0) + 1.0f);
    Deinv[e] = De > 0.f ? rsqrtf(De) : 1.0f;
}

__device__ __forceinline__ void add4(float4& a, const float4& x) {
    a.x += x.x; a.y += x.y; a.z += x.z; a.w += x.w;
}

__global__ void yh_kernel(const float* __restrict__ Xc,
                          const int* __restrict__ eoff, const int* __restrict__ edge_v,
                          const float* __restrict__ Deinv, float* __restrict__ Yh, int M)
{
    int e = blockIdx.x * 8 + (threadIdx.x >> 5);
    if (e >= M) return;
    int sl = threadIdx.x & 31;
    int col = sl * 4;
    int j0 = eoff[e], j1 = eoff[e + 1];
    float4 acc = make_float4(0.f, 0.f, 0.f, 0.f);
    int j = j0;
    for (; j + 3 < j1; j += 4) {
        int v0 = edge_v[j + 0], v1 = edge_v[j + 1], v2 = edge_v[j + 2], v3 = edge_v[j + 3];
        float4 x0 = *(const float4*)(Xc + (size_t)v0 * 128 + col);
        float4 x1 = *(const float4*)(Xc + (size_t)v1 * 128 + col);
        float4 x2 = *(const float4*)(Xc + (size_t)v2 * 128 + col);
        float4 x3 = *(const float4*)(Xc + (size_t)v3 * 128 + col);
        add4(acc, x0); add4(acc, x1); add4(acc, x2); add4(acc, x3);
    }
    for (; j < j1; ++j) {
        int v = edge_v[j];
        float4 x = *(const float4*)(Xc + (size_t)v * 128 + col);
        add4(acc, x);
    }
    float sc = ((j1 > j0) ? 1.0f / (float)(j1 - j0) : 0.f) * Deinv[e];
    float4 o;
    o.x = acc.x * sc; o.y = acc.y * sc; o.z = acc.z * sc; o.w = acc.w * sc;
    *(float4*)(Yh + (size_t)e * 128 + col) = o;
}

__global__ void xo_final_kernel(const float* __restrict__ Yh,
                                const int* __restrict__ noff, const int* __restrict__ node_e,
                                float* __restrict__ out, int N)
{
    int v = blockIdx.x * 8 + (threadIdx.x >> 5);
    if (v >= N) return;
    int sl = threadIdx.x & 31;
    int col = sl * 4;
    int i0 = noff[v], i1 = noff[v + 1];
    float4 acc = make_float4(0.f, 0.f, 0.f, 0.f);
    int i = i0;
    for (; i + 3 < i1; i += 4) {
        int e0 = node_e[i + 0], e1 = node_e[i + 1], e2 = node_e[i + 2], e3 = node_e[i + 3];
        float4 y0 = *(const float4*)(Yh + (size_t)e0 * 128 + col);
        float4 y1 = *(const float4*)(Yh + (size_t)e1 * 128 + col);
        float4 y2 = *(const float4*)(Yh + (size_t)e2 * 128 + col);
        float4 y3 = *(const float4*)(Yh + (size_t)e3 * 128 + col);
        add4(acc, y0); add4(acc, y1); add4(acc, y2); add4(acc, y3);
    }
    for (; i < i1; ++i) {
        int e = node_e[i];
        float4 y = *(const float4*)(Yh + (size_t)e * 128 + col);
        add4(acc, y);
    }
    float sc = (i1 > i0) ? rsqrtf((float)(i1 - i0)) : 0.f;
    float4 o;
    o.x = acc.x * sc; o.y = acc.y * sc; o.z = acc.z * sc; o.w = acc.w * sc;
    *(float4*)(out + (size_t)v * 128 + col) = o;
}

// =============== host-side ===============
static void gemm(const u16* A, int lda,
                 const u16* Bhi, const u16* Blo, int ldb,
                 const float* biasF, const float* biasB,
                 float* Cf, u16* Cb, int M, int Nc, int ncSplit, int K,
                 hipStream_t stream)
{
    dim3 g((M + 127) / 128, Nc / 128);
    gemm_mfma_kernel<<<g, 256, 0, stream>>>(A, lda, Bhi, Blo, ldb, biasF, biasB,
                                            Cf, Cb, M, Nc, ncSplit, K);
}

static void run_layer(u16* A, int K,
                      const u16* WxvThi, const u16* WxvTlo,
                      const float* bx, const float* bv, const float* a,
                      const u16* WtThi, const u16* WtTlo, const float* bt,
                      u16* Ae,
                      float* Xinit, u16* Xfeatb, u16* Ybufb, float* score,
                      const int* eoff, const int* edge_v,
                      const int* noff, const int* node_e,
                      int N, int M, hipStream_t stream)
{
    // merged: cols 0-255 -> Xinit fp32 (bias bx), cols 256-511 -> Xfeat bf16 (bias bv)
    gemm(A, K, WxvThi, WxvTlo, K, bx, bv, Xinit, Xfeatb, N, 512, 256, K, stream);
    score_kernel<<<(N + 3) / 4, 256, 0, stream>>>(Xfeatb, a, score, N);
    v2e_fused_kernel<<<(M + 7) / 8, 256, 0, stream>>>(Xfeatb, score, eoff, edge_v, Ae, M);
    gemm(Ae, 320, WtThi, WtTlo, 320, nullptr, bt, nullptr, Ybufb, M, 256, 0, 320, stream);
    e2v_finish_kernel<<<(N + 7) / 8, 256, 0, stream>>>(Ybufb, noff, node_e, Xinit, A, N);
}

extern "C" void kernel_launch(void* const* d_in, const int* in_sizes, int n_in,
                              void* d_out, int out_size, void* d_ws, size_t ws_size,
                              hipStream_t stream)
{
    const float* X   = (const float*)d_in[0];
    const int*   V   = (const int*)d_in[1];
    const int*   E   = (const int*)d_in[2];
    const float* S   = (const float*)d_in[3];
    const float* Wx0 = (const float*)d_in[4];  const float* bx0 = (const float*)d_in[5];
    const float* Wv0 = (const float*)d_in[6];  const float* bv0 = (const float*)d_in[7];
    const float* a0  = (const float*)d_in[8];
    const float* Wt0 = (const float*)d_in[9];  const float* bt0 = (const float*)d_in[10];
    const float* Wx1 = (const float*)d_in[11]; const float* bx1 = (const float*)d_in[12];
    const float* Wv1 = (const float*)d_in[13]; const float* bv1 = (const float*)d_in[14];
    const float* a1  = (const float*)d_in[15];
    const float* Wt1 = (const float*)d_in[16]; const float* bt1 = (const float*)d_in[17];
    const float* Wf  = (const float*)d_in[18]; const float* bf  = (const float*)d_in[19];

    int N   = in_sizes[0] / 128;
    int NNZ = in_sizes[1];
    int M   = in_sizes[3] / 64;

    float* ws = (float*)d_ws;
    size_t off = 0;
    float* Xinit = ws + off; off += (size_t)N * 256;   // also Yh [M,128] fp32 in hyperconv
    float* Xfeat = ws + off; off += (size_t)N * 256;   // Xfeatb/Ybufb bf16; Xc [N,128] fp32
    u16*   Xfeatb = (u16*)Xfeat;
    u16*   Ybufb  = (u16*)Xfeat;
    u16* Abuf = (u16*)(ws + off); off += (size_t)N * 128;  // N*256 u16: X cast / h bf16
    u16* Ae   = (u16*)(ws + off); off += (size_t)M * 160;  // M*320 u16 edge A-buffer
    // combined W^T buffers: Wxv = [Wx^T ; Wv^T] (512 rows)
    u16* WxvT0h = (u16*)(ws + off); off += (size_t)(512 * 128) / 2;
    u16* WxvT0l = (u16*)(ws + off); off += (size_t)(512 * 128) / 2;
    u16* WtT0h  = (u16*)(ws + off); off += (size_t)(256 * 320) / 2;
    u16* WtT0l  = (u16*)(ws + off); off += (size_t)(256 * 320) / 2;
    u16* WxvT1h = (u16*)(ws + off); off += (size_t)(512 * 256) / 2;
    u16* WxvT1l = (u16*)(ws + off); off += (size_t)(512 * 256) / 2;
    u16* WtT1h  = (u16*)(ws + off); off += (size_t)(256 * 320) / 2;
    u16* WtT1l  = (u16*)(ws + off); off += (size_t)(256 * 320) / 2;
    u16* WfTh   = (u16*)(ws + off); off += (size_t)(128 * 256) / 2;
    u16* WfTl   = (u16*)(ws + off); off += (size_t)(128 * 256) / 2;
    float* score = ws + off; off += (size_t)N;
    float* Deinv = ws + off; off += (size_t)M;
    int* eoff   = (int*)(ws + off); off += (size_t)(M + 1);
    int* ecnt   = (int*)(ws + off); off += (size_t)M;
    int* ecur   = (int*)(ws + off); off += (size_t)M;
    int* psumE  = (int*)(ws + off); off += 64;
    int* edge_v = (int*)(ws + off); off += (size_t)NNZ;
    int* noff   = (int*)(ws + off); off += (size_t)(N + 1);
    int* ncnt   = (int*)(ws + off); off += (size_t)N;
    int* ncur   = (int*)(ws + off); off += (size_t)N;
    int* psumN  = (int*)(ws + off); off += 64;
    int* node_e = (int*)(ws + off); off += (size_t)NNZ;

    // ---- CSR build ----
    hipMemsetAsync(ecnt, 0, (size_t)M * 4, stream);
    hipMemsetAsync(ncnt, 0, (size_t)N * 4, stream);
    count_kernel<<<((NNZ + 3) / 4 + 255) / 256, 256, 0, stream>>>(V, E, ecnt, ncnt, NNZ);
    int nbE = (M + 1023) / 1024, nbN = (N + 1023) / 1024;
    scan_part1<<<nbE, 256, 0, stream>>>(ecnt, eoff, psumE, M);
    scan_part1<<<nbN, 256, 0, stream>>>(ncnt, noff, psumN, N);
    scan_part2<<<nbE, 256, 0, stream>>>(ecnt, eoff, psumE, ecur, M);
    scan_part2<<<nbN, 256, 0, stream>>>(ncnt, noff, psumN, ncur, N);
    fill_kernel<<<((NNZ + 3) / 4 + 255) / 256, 256, 0, stream>>>(V, E, ecur, ncur, edge_v, node_e, NNZ);

    // ---- input casts (one launch) ----
    int n4x = N * 128 / 4, nS = M * 64;
    cast_inputs_kernel<<<(n4x + nS + 255) / 256, 256, 0, stream>>>(X, Abuf, n4x, S, Ae, nS);

    // ---- weight transpose+split (one launch, 7 jobs) ----
    WJobs jobs;
    jobs.j[0] = {Wx0, WxvT0h,                WxvT0l,                128, 8};
    jobs.j[1] = {Wv0, WxvT0h + 256 * 128,    WxvT0l + 256 * 128,    128, 8};
    jobs.j[2] = {Wt0, WtT0h,                 WtT0l,                 320, 8};
    jobs.j[3] = {Wx1, WxvT1h,                WxvT1l,                256, 8};
    jobs.j[4] = {Wv1, WxvT1h + 256 * 256,    WxvT1l + 256 * 256,    256, 8};
    jobs.j[5] = {Wt1, WtT1h,                 WtT1l,                 320, 8};
    jobs.j[6] = {Wf,  WfTh,                  WfTl,                  256, 7};
    dim3 wg((320 * 256 + 255) / 256, 7);
    wsplit_all_kernel<<<wg, 256, 0, stream>>>(jobs);

    // ---- layers (h bf16 lands back in Abuf) ----
    run_layer(Abuf, 128, WxvT0h, WxvT0l, bx0, bv0, a0,
              WtT0h, WtT0l, bt0, Ae, Xinit, Xfeatb, Ybufb, score,
              eoff, edge_v, noff, node_e, N, M, stream);
    run_layer(Abuf, 256, WxvT1h, WxvT1l, bx1, bv1, a1,
              WtT1h, WtT1l, bt1, Ae, Xinit, Xfeatb, Ybufb, score,
              eoff, edge_v, noff, node_e, N, M, stream);

    // ---- hyperconv (fp32 output path) ----
    float* Xc = Xfeat;   // [N,128] fp32
    float* Yh = Xinit;   // [M,128] fp32
    gemm(Abuf, 256, WfTh, WfTl, 256, bf, nullptr, Xc, nullptr, N, 128, 128, 256, stream);
    deinv_kernel<<<(M + 255) / 256, 256, 0, stream>>>(eoff, edge_v, noff, Deinv, M);
    yh_kernel<<<(M + 7) / 8, 256, 0, stream>>>(Xc, eoff, edge_v, Deinv, Yh, M);
    xo_final_kernel<<<(N + 7) / 8, 256, 0, stream>>>(Yh, noff, node_e, (float*)d_out, N);
}

// Round 11
// 583.212 us; speedup vs baseline: 1.4326x; 1.0695x over previous
//
#include <hip/hip_runtime.h>
#include <hip/hip_bf16.h>

typedef unsigned short u16;
typedef __attribute__((ext_vector_type(4))) u16 u16x4;
typedef __attribute__((ext_vector_type(8))) u16 u16x8;
typedef __attribute__((ext_vector_type(8))) __bf16 bf16x8;
typedef __attribute__((ext_vector_type(4))) float f32x4;

__device__ __forceinline__ u16 f2bf(float x) {
    unsigned u = __float_as_uint(x);
    unsigned r = u + 0x7FFF + ((u >> 16) & 1);
    return (u16)(r >> 16);
}
__device__ __forceinline__ float bf2f(u16 h) {
    return __uint_as_float(((unsigned)h) << 16);
}

__device__ __forceinline__ void gl_lds16(const void* g, void* l) {
    __builtin_amdgcn_global_load_lds(
        (const __attribute__((address_space(1))) void*)g,
        (__attribute__((address_space(3))) void*)l, 16, 0, 0);
}

// =============== bf16-activation x split-bf16-weight MFMA GEMM ===============
// Out[M,Nc] = A[M,K] @ B^T[Nc,K] + bias.  A: plain bf16.  B: (hi,lo) pair.
// acc = A*Bhi + A*Blo.  Output bf16, split into two regions:
//   cols [0,ncSplit)   -> CbA (stride ncSplit,   bias biasF)
//   cols [ncSplit,Nc)  -> CbB (stride Nc-ncSplit, bias biasB)
__global__ __launch_bounds__(256) void gemm_mfma_kernel(
    const u16* __restrict__ A, int lda,
    const u16* __restrict__ Bhi, const u16* __restrict__ Blo, int ldb,
    const float* __restrict__ biasF, const float* __restrict__ biasB,
    u16* __restrict__ CbA, u16* __restrict__ CbB,
    int M, int Nc, int ncSplit, int K)
{
    __shared__ __align__(16) u16 lds[3 * 4096];
    u16* sA   = lds;
    u16* sBhi = lds + 4096;
    u16* sBlo = lds + 8192;

    int tid = threadIdx.x;
    int wave = tid >> 6, lane = tid & 63;
    int row0 = blockIdx.x * 128, col0 = blockIdx.y * 128;

    long gA[2], gB[2];
    int sOff[2];
#pragma unroll
    for (int r = 0; r < 2; ++r) {
        int trow = r * 64 + wave * 16 + (lane >> 2);
        int chunk = (lane & 3) ^ ((trow >> 2) & 3);
        int arow = min(row0 + trow, M - 1);
        gA[r] = (long)arow * lda + chunk * 8;
        gB[r] = (long)(col0 + trow) * ldb + chunk * 8;
        sOff[r] = (r * 64 + wave * 16) * 32;
    }

    int m16 = lane & 15, quad = lane >> 4;
    int offA[4], offB[4];
#pragma unroll
    for (int i = 0; i < 4; ++i) {
        int ra = (wave & 1) * 64 + i * 16 + m16;
        offA[i] = ra * 32 + ((quad ^ ((ra >> 2) & 3)) * 8);
        int rb = (wave >> 1) * 64 + i * 16 + m16;
        offB[i] = rb * 32 + ((quad ^ ((rb >> 2) & 3)) * 8);
    }

    f32x4 acc[4][4];
#pragma unroll
    for (int i = 0; i < 4; ++i)
#pragma unroll
        for (int j = 0; j < 4; ++j) {
            f32x4 z = {0.f, 0.f, 0.f, 0.f};
            acc[i][j] = z;
        }

    int nkb = K >> 5;
    for (int kb = 0; kb < nkb; ++kb) {
#pragma unroll
        for (int r = 0; r < 2; ++r) {
            gl_lds16(A + gA[r], sA + sOff[r]);
            gl_lds16(Bhi + gB[r], sBhi + sOff[r]);
            gl_lds16(Blo + gB[r], sBlo + sOff[r]);
        }
        __syncthreads();
        bf16x8 av[4], bh[4], bl[4];
#pragma unroll
        for (int i = 0; i < 4; ++i) {
            av[i] = *(const bf16x8*)(sA + offA[i]);
            bh[i] = *(const bf16x8*)(sBhi + offB[i]);
            bl[i] = *(const bf16x8*)(sBlo + offB[i]);
        }
#pragma unroll
        for (int i = 0; i < 4; ++i)
#pragma unroll
            for (int j = 0; j < 4; ++j) {
                acc[i][j] = __builtin_amdgcn_mfma_f32_16x16x32_bf16(av[i], bh[j], acc[i][j], 0, 0, 0);
                acc[i][j] = __builtin_amdgcn_mfma_f32_16x16x32_bf16(av[i], bl[j], acc[i][j], 0, 0, 0);
            }
        __syncthreads();
#pragma unroll
        for (int r = 0; r < 2; ++r) { gA[r] += 32; gB[r] += 32; }
    }

    int wm = (wave & 1) * 64, wn = (wave >> 1) * 64;
#pragma unroll
    for (int j = 0; j < 4; ++j) {
        int col = col0 + wn + j * 16 + m16;
        bool isB = (col >= ncSplit);
        float bj = isB ? biasB[col - ncSplit] : biasF[col];
        u16* Cp = isB ? CbB : CbA;
        int cc = isB ? (col - ncSplit) : col;
        int stride = isB ? (Nc - ncSplit) : ncSplit;
#pragma unroll
        for (int i = 0; i < 4; ++i)
#pragma unroll
            for (int rr = 0; rr < 4; ++rr) {
                int row = row0 + wm + i * 16 + quad * 4 + rr;
                if (row < M) Cp[(size_t)row * stride + cc] = f2bf(acc[i][j][rr] + bj);
            }
    }
}

// =============== prep kernels (merged) ===============
struct WJob { const float* W; u16* Whi; u16* Wlo; int K; int ncShift; };
struct WJobs { WJob j[7]; };

__global__ void wsplit_all_kernel(WJobs jobs)
{
    WJob jb = jobs.j[blockIdx.y];
    int Nc = 1 << jb.ncShift;
    int idx = blockIdx.x * blockDim.x + threadIdx.x;
    if (idx >= jb.K * Nc) return;
    int k = idx >> jb.ncShift, n = idx & (Nc - 1);
    float x = jb.W[idx];
    u16 h = f2bf(x);
    u16 l = f2bf(x - bf2f(h));
    jb.Whi[(size_t)n * jb.K + k] = h;
    jb.Wlo[(size_t)n * jb.K + k] = l;
}

__global__ void cast_inputs_kernel(const float* __restrict__ X, u16* __restrict__ Abuf, int n4x,
                                   const float* __restrict__ S, u16* __restrict__ Ae, int nS)
{
    int id = blockIdx.x * blockDim.x + threadIdx.x;
    if (id < n4x) {
        float4 x = ((const float4*)X)[id];
        u16x4 h;
        h.x = f2bf(x.x); h.y = f2bf(x.y); h.z = f2bf(x.z); h.w = f2bf(x.w);
        *(u16x4*)(Abuf + (size_t)id * 4) = h;
    } else {
        int i = id - n4x;
        if (i < nS) {
            int e = i >> 6, c = i & 63;
            Ae[(size_t)e * 320 + 256 + c] = f2bf(S[i]);
        }
    }
}

// =============== CSR build ===============
__global__ void count_kernel(const int* __restrict__ V, const int* __restrict__ E,
                             int* ecnt, int* ncnt, int nnz)
{
    int k0 = (blockIdx.x * blockDim.x + threadIdx.x) * 4;
    if (k0 >= nnz) return;
    int kmax = min(nnz - k0, 4);
    int vv[4], ee[4];
    if (kmax == 4) {
        int4 v4 = *(const int4*)(V + k0);
        int4 e4 = *(const int4*)(E + k0);
        vv[0] = v4.x; vv[1] = v4.y; vv[2] = v4.z; vv[3] = v4.w;
        ee[0] = e4.x; ee[1] = e4.y; ee[2] = e4.z; ee[3] = e4.w;
    } else {
        for (int q = 0; q < kmax; ++q) { vv[q] = V[k0 + q]; ee[q] = E[k0 + q]; }
    }
    for (int q = 0; q < kmax; ++q) atomicAdd(&ecnt[ee[q]], 1);
    for (int q = 0; q < kmax; ++q) atomicAdd(&ncnt[vv[q]], 1);
}

__global__ __launch_bounds__(256) void scan_part1(const int* __restrict__ cnt,
                                                  int* __restrict__ off,
                                                  int* __restrict__ psum, int n)
{
    __shared__ int tsum[256];
    int base = blockIdx.x * 1024;
    int t = threadIdx.x;
    int idx0 = base + t * 4;
    int4 c = make_int4(0, 0, 0, 0);
    if (idx0 + 3 < n) c = *(const int4*)(cnt + idx0);
    else {
        if (idx0 + 0 < n) c.x = cnt[idx0 + 0];
        if (idx0 + 1 < n) c.y = cnt[idx0 + 1];
        if (idx0 + 2 < n) c.z = cnt[idx0 + 2];
        if (idx0 + 3 < n) c.w = cnt[idx0 + 3];
    }
    int s = c.x + c.y + c.z + c.w;
    tsum[t] = s;
    __syncthreads();
    for (int o = 1; o < 256; o <<= 1) {
        int v = (t >= o) ? tsum[t - o] : 0;
        __syncthreads();
        tsum[t] += v;
        __syncthreads();
    }
    int run = tsum[t] - s;
    run += c.x; if (idx0 + 0 < n) off[idx0 + 1] = run;
    run += c.y; if (idx0 + 1 < n) off[idx0 + 2] = run;
    run += c.z; if (idx0 + 2 < n) off[idx0 + 3] = run;
    run += c.w; if (idx0 + 3 < n) off[idx0 + 4] = run;
    if (t == 255) psum[blockIdx.x] = tsum[255];
}

__global__ __launch_bounds__(256) void scan_part2(const int* __restrict__ cnt,
                                                  int* __restrict__ off,
                                                  const int* __restrict__ psum,
                                                  int* __restrict__ cur, int n)
{
    __shared__ int bpref;
    int t = threadIdx.x;
    int b = blockIdx.x;
    if (t < 64) {
        int s = (t < b) ? psum[t] : 0;
#pragma unroll
        for (int o = 32; o; o >>= 1) s += __shfl_xor(s, o);
        if (t == 0) {
            bpref = s;
            if (b == 0) off[0] = 0;
        }
    }
    __syncthreads();
    int base = b * 1024 + t * 4;
#pragma unroll
    for (int q = 0; q < 4; ++q) {
        int i = base + q;
        if (i < n) {
            int inc = off[i + 1] + bpref;
            off[i + 1] = inc;
            cur[i] = inc - cnt[i];
        }
    }
}

__global__ void fill_kernel(const int* __restrict__ V, const int* __restrict__ E,
                            int* ecur, int* ncur, int* edge_v, int* node_e, int nnz)
{
    int k0 = (blockIdx.x * blockDim.x + threadIdx.x) * 4;
    if (k0 >= nnz) return;
    int kmax = min(nnz - k0, 4);
    int vv[4], ee[4], js[4], is_[4];
    if (kmax == 4) {
        int4 v4 = *(const int4*)(V + k0);
        int4 e4 = *(const int4*)(E + k0);
        vv[0] = v4.x; vv[1] = v4.y; vv[2] = v4.z; vv[3] = v4.w;
        ee[0] = e4.x; ee[1] = e4.y; ee[2] = e4.z; ee[3] = e4.w;
    } else {
        for (int q = 0; q < kmax; ++q) { vv[q] = V[k0 + q]; ee[q] = E[k0 + q]; }
    }
    for (int q = 0; q < kmax; ++q) js[q] = atomicAdd(&ecur[ee[q]], 1);
    for (int q = 0; q < kmax; ++q) is_[q] = atomicAdd(&ncur[vv[q]], 1);
    for (int q = 0; q < kmax; ++q) edge_v[js[q]] = vv[q];
    for (int q = 0; q < kmax; ++q) node_e[is_[q]] = ee[q];
}

// =============== graph kernels ===============
__global__ void score_kernel(const u16* __restrict__ Xf, const float* __restrict__ a,
                             float* __restrict__ score, int N)
{
    int row = blockIdx.x * (blockDim.x >> 6) + (threadIdx.x >> 6);
    int lane = threadIdx.x & 63;
    if (row >= N) return;
    u16x4 x = *(const u16x4*)(Xf + (size_t)row * 256 + lane * 4);
    float4 av = *(const float4*)(a + lane * 4);
    float p = bf2f(x.x) * av.x + bf2f(x.y) * av.y + bf2f(x.z) * av.z + bf2f(x.w) * av.w;
#pragma unroll
    for (int off = 32; off; off >>= 1) p += __shfl_down(p, off);
    if (lane == 0) score[row] = p;
}

__device__ __forceinline__ float lrelu(float s) { return s >= 0.f ? s : 0.2f * s; }

__global__ void v2e_fused_kernel(const u16* __restrict__ Xf,
                                 const float* __restrict__ score,
                                 const int* __restrict__ eoff,
                                 const int* __restrict__ edge_v,
                                 u16* __restrict__ Ae, int M)
{
    int e = blockIdx.x * 8 + (threadIdx.x >> 5);
    if (e >= M) return;
    int sl = threadIdx.x & 31;
    int j0 = eoff[e], j1 = eoff[e + 1];
    float m = -INFINITY;
    for (int j = j0 + sl; j < j1; j += 32) m = fmaxf(m, lrelu(score[edge_v[j]]));
#pragma unroll
    for (int o = 16; o; o >>= 1) m = fmaxf(m, __shfl_xor(m, o));
    float sum = 0.f;
    for (int j = j0 + sl; j < j1; j += 32) sum += expf(lrelu(score[edge_v[j]]) - m);
#pragma unroll
    for (int o = 16; o; o >>= 1) sum += __shfl_xor(sum, o);
    float inv = (j1 > j0) ? 1.0f / sum : 0.f;

    float acc[8] = {0.f, 0.f, 0.f, 0.f, 0.f, 0.f, 0.f, 0.f};
    int col = sl * 8;
    int j = j0;
    for (; j + 3 < j1; j += 4) {
        int v0 = edge_v[j + 0], v1 = edge_v[j + 1], v2 = edge_v[j + 2], v3 = edge_v[j + 3];
        float s0 = score[v0], s1 = score[v1], s2 = score[v2], s3 = score[v3];
        u16x8 r0 = *(const u16x8*)(Xf + (size_t)v0 * 256 + col);
        u16x8 r1 = *(const u16x8*)(Xf + (size_t)v1 * 256 + col);
        u16x8 r2 = *(const u16x8*)(Xf + (size_t)v2 * 256 + col);
        u16x8 r3 = *(const u16x8*)(Xf + (size_t)v3 * 256 + col);
        float w0 = expf(lrelu(s0) - m) * inv;
        float w1 = expf(lrelu(s1) - m) * inv;
        float w2 = expf(lrelu(s2) - m) * inv;
        float w3 = expf(lrelu(s3) - m) * inv;
#pragma unroll
        for (int q = 0; q < 8; ++q) {
            acc[q] += bf2f(r0[q]) * w0;
            acc[q] += bf2f(r1[q]) * w1;
            acc[q] += bf2f(r2[q]) * w2;
            acc[q] += bf2f(r3[q]) * w3;
        }
    }
    for (; j < j1; ++j) {
        int v = edge_v[j];
        float ww = expf(lrelu(score[v]) - m) * inv;
        u16x8 r = *(const u16x8*)(Xf + (size_t)v * 256 + col);
#pragma unroll
        for (int q = 0; q < 8; ++q) acc[q] += bf2f(r[q]) * ww;
    }
    u16x8 hv;
#pragma unroll
    for (int q = 0; q < 8; ++q) {
        float vq = acc[q];
        vq = vq > 0.f ? vq : expm1f(vq);
        hv[q] = f2bf(vq);
    }
    *(u16x8*)(Ae + (size_t)e * 320 + col) = hv;
}

// h[v,:] = elu(mean_i Y[node_e[i],:]) + Xinit[v,:] -> bf16   (Xinit now bf16)
__global__ void e2v_finish_kernel(const u16* __restrict__ Y,
                                  const int* __restrict__ noff,
                                  const int* __restrict__ node_e,
                                  const u16* __restrict__ Xinit,
                                  u16* __restrict__ H, int N)
{
    int v = blockIdx.x * 8 + (threadIdx.x >> 5);
    if (v >= N) return;
    int sl = threadIdx.x & 31;
    int col = sl * 8;
    int i0 = noff[v], i1 = noff[v + 1];
    float acc[8] = {0.f, 0.f, 0.f, 0.f, 0.f, 0.f, 0.f, 0.f};
    int i = i0;
    for (; i + 3 < i1; i += 4) {
        int e0 = node_e[i + 0], e1 = node_e[i + 1], e2 = node_e[i + 2], e3 = node_e[i + 3];
        u16x8 r0 = *(const u16x8*)(Y + (size_t)e0 * 256 + col);
        u16x8 r1 = *(const u16x8*)(Y + (size_t)e1 * 256 + col);
        u16x8 r2 = *(const u16x8*)(Y + (size_t)e2 * 256 + col);
        u16x8 r3 = *(const u16x8*)(Y + (size_t)e3 * 256 + col);
#pragma unroll
        for (int q = 0; q < 8; ++q) {
            acc[q] += bf2f(r0[q]);
            acc[q] += bf2f(r1[q]);
            acc[q] += bf2f(r2[q]);
            acc[q] += bf2f(r3[q]);
        }
    }
    for (; i < i1; ++i) {
        int e = node_e[i];
        u16x8 r = *(const u16x8*)(Y + (size_t)e * 256 + col);
#pragma unroll
        for (int q = 0; q < 8; ++q) acc[q] += bf2f(r[q]);
    }
    float inv = (i1 > i0) ? 1.0f / (float)(i1 - i0) : 0.f;
    size_t base = (size_t)v * 256 + col;
    u16x8 xi = *(const u16x8*)(Xinit + base);
    u16x8 hv;
#pragma unroll
    for (int q = 0; q < 8; ++q) {
        float mm = acc[q] * inv;
        float oq = (mm > 0.f ? mm : expm1f(mm)) + bf2f(xi[q]);
        hv[q] = f2bf(oq);
    }
    *(u16x8*)(H + base) = hv;
}

// =============== hyperconv ===============
// Yh[e,:] = Deinv[e] * mean_j Xc[edge_v[j],:]  (Xc bf16, Yh bf16)
// fused De^-1/2 computation; 16 lanes/edge (4 edges/wave), 8 cols/lane
__global__ void yh_kernel(const u16* __restrict__ Xc,
                          const int* __restrict__ eoff, const int* __restrict__ edge_v,
                          const int* __restrict__ noff, u16* __restrict__ Yh, int M)
{
    int e = blockIdx.x * 16 + (threadIdx.x >> 4);
    if (e >= M) return;
    int sl = threadIdx.x & 15;
    int col = sl * 8;
    int j0 = eoff[e], j1 = eoff[e + 1];

    float dsum = 0.f;
    for (int j = j0 + sl; j < j1; j += 16) {
        int v = edge_v[j];
        dsum += (float)(noff[v + 1] - noff[v]);
    }
#pragma unroll
    for (int o = 8; o; o >>= 1) dsum += __shfl_xor(dsum, o);
    float De = dsum / ((float)(j1 - j0) + 1.0f);
    float deinv = De > 0.f ? rsqrtf(De) : 1.0f;

    float acc[8] = {0.f, 0.f, 0.f, 0.f, 0.f, 0.f, 0.f, 0.f};
    int j = j0;
    for (; j + 3 < j1; j += 4) {
        int v0 = edge_v[j + 0], v1 = edge_v[j + 1], v2 = edge_v[j + 2], v3 = edge_v[j + 3];
        u16x8 r0 = *(const u16x8*)(Xc + (size_t)v0 * 128 + col);
        u16x8 r1 = *(const u16x8*)(Xc + (size_t)v1 * 128 + col);
        u16x8 r2 = *(const u16x8*)(Xc + (size_t)v2 * 128 + col);
        u16x8 r3 = *(const u16x8*)(Xc + (size_t)v3 * 128 + col);
#pragma unroll
        for (int q = 0; q < 8; ++q) {
            acc[q] += bf2f(r0[q]);
            acc[q] += bf2f(r1[q]);
            acc[q] += bf2f(r2[q]);
            acc[q] += bf2f(r3[q]);
        }
    }
    for (; j < j1; ++j) {
        int v = edge_v[j];
        u16x8 r = *(const u16x8*)(Xc + (size_t)v * 128 + col);
#pragma unroll
        for (int q = 0; q < 8; ++q) acc[q] += bf2f(r[q]);
    }
    float sc = ((j1 > j0) ? 1.0f / (float)(j1 - j0) : 0.f) * deinv;
    u16x8 o8;
#pragma unroll
    for (int q = 0; q < 8; ++q) o8[q] = f2bf(acc[q] * sc);
    *(u16x8*)(Yh + (size_t)e * 128 + col) = o8;
}

// out[v,:] = Dv^-0.5 * sum_i Yh[node_e[i],:]  (Yh bf16, out fp32)
__global__ void xo_final_kernel(const u16* __restrict__ Yh,
                                const int* __restrict__ noff, const int* __restrict__ node_e,
                                float* __restrict__ out, int N)
{
    int v = blockIdx.x * 16 + (threadIdx.x >> 4);
    if (v >= N) return;
    int sl = threadIdx.x & 15;
    int col = sl * 8;
    int i0 = noff[v], i1 = noff[v + 1];
    float acc[8] = {0.f, 0.f, 0.f, 0.f, 0.f, 0.f, 0.f, 0.f};
    int i = i0;
    for (; i + 3 < i1; i += 4) {
        int e0 = node_e[i + 0], e1 = node_e[i + 1], e2 = node_e[i + 2], e3 = node_e[i + 3];
        u16x8 r0 = *(const u16x8*)(Yh + (size_t)e0 * 128 + col);
        u16x8 r1 = *(const u16x8*)(Yh + (size_t)e1 * 128 + col);
        u16x8 r2 = *(const u16x8*)(Yh + (size_t)e2 * 128 + col);
        u16x8 r3 = *(const u16x8*)(Yh + (size_t)e3 * 128 + col);
#pragma unroll
        for (int q = 0; q < 8; ++q) {
            acc[q] += bf2f(r0[q]);
            acc[q] += bf2f(r1[q]);
            acc[q] += bf2f(r2[q]);
            acc[q] += bf2f(r3[q]);
        }
    }
    for (; i < i1; ++i) {
        int e = node_e[i];
        u16x8 r = *(const u16x8*)(Yh + (size_t)e * 128 + col);
#pragma unroll
        for (int q = 0; q < 8; ++q) acc[q] += bf2f(r[q]);
    }
    float sc = (i1 > i0) ? rsqrtf((float)(i1 - i0)) : 0.f;
    float4 oA, oB;
    oA.x = acc[0] * sc; oA.y = acc[1] * sc; oA.z = acc[2] * sc; oA.w = acc[3] * sc;
    oB.x = acc[4] * sc; oB.y = acc[5] * sc; oB.z = acc[6] * sc; oB.w = acc[7] * sc;
    float* d = out + (size_t)v * 128 + col;
    *(float4*)d = oA;
    *(float4*)(d + 4) = oB;
}

// =============== host-side ===============
static void gemm(const u16* A, int lda,
                 const u16* Bhi, const u16* Blo, int ldb,
                 const float* biasF, const float* biasB,
                 u16* CbA, u16* CbB, int M, int Nc, int ncSplit, int K,
                 hipStream_t stream)
{
    dim3 g((M + 127) / 128, Nc / 128);
    gemm_mfma_kernel<<<g, 256, 0, stream>>>(A, lda, Bhi, Blo, ldb, biasF, biasB,
                                            CbA, CbB, M, Nc, ncSplit, K);
}

static void run_layer(u16* A, int K,
                      const u16* WxvThi, const u16* WxvTlo,
                      const float* bx, const float* bv, const float* a,
                      const u16* WtThi, const u16* WtTlo, const float* bt,
                      u16* Ae,
                      u16* XinitB, u16* Xfeatb, u16* Ybufb, float* score,
                      const int* eoff, const int* edge_v,
                      const int* noff, const int* node_e,
                      int N, int M, hipStream_t stream)
{
    // merged: cols 0-255 -> Xinit bf16 (bias bx), cols 256-511 -> Xfeat bf16 (bias bv)
    gemm(A, K, WxvThi, WxvTlo, K, bx, bv, XinitB, Xfeatb, N, 512, 256, K, stream);
    score_kernel<<<(N + 3) / 4, 256, 0, stream>>>(Xfeatb, a, score, N);
    v2e_fused_kernel<<<(M + 7) / 8, 256, 0, stream>>>(Xfeatb, score, eoff, edge_v, Ae, M);
    gemm(Ae, 320, WtThi, WtTlo, 320, nullptr, bt, nullptr, Ybufb, M, 256, 0, 320, stream);
    e2v_finish_kernel<<<(N + 7) / 8, 256, 0, stream>>>(Ybufb, noff, node_e, XinitB, A, N);
}

extern "C" void kernel_launch(void* const* d_in, const int* in_sizes, int n_in,
                              void* d_out, int out_size, void* d_ws, size_t ws_size,
                              hipStream_t stream)
{
    const float* X   = (const float*)d_in[0];
    const int*   V   = (const int*)d_in[1];
    const int*   E   = (const int*)d_in[2];
    const float* S   = (const float*)d_in[3];
    const float* Wx0 = (const float*)d_in[4];  const float* bx0 = (const float*)d_in[5];
    const float* Wv0 = (const float*)d_in[6];  const float* bv0 = (const float*)d_in[7];
    const float* a0  = (const float*)d_in[8];
    const float* Wt0 = (const float*)d_in[9];  const float* bt0 = (const float*)d_in[10];
    const float* Wx1 = (const float*)d_in[11]; const float* bx1 = (const float*)d_in[12];
    const float* Wv1 = (const float*)d_in[13]; const float* bv1 = (const float*)d_in[14];
    const float* a1  = (const float*)d_in[15];
    const float* Wt1 = (const float*)d_in[16]; const float* bt1 = (const float*)d_in[17];
    const float* Wf  = (const float*)d_in[18]; const float* bf  = (const float*)d_in[19];

    int N   = in_sizes[0] / 128;
    int NNZ = in_sizes[1];
    int M   = in_sizes[3] / 64;

    float* ws = (float*)d_ws;
    size_t off = 0;
    u16* XinitB = (u16*)(ws + off); off += (size_t)N * 128;  // [N,256] bf16; also Yh [M,128] bf16
    u16* XfeatR = (u16*)(ws + off); off += (size_t)N * 128;  // Xfeatb [N,256] / Ybufb [M,256] / Xcb [N,128]
    u16* Xfeatb = XfeatR;
    u16* Ybufb  = XfeatR;
    u16* Abuf = (u16*)(ws + off); off += (size_t)N * 128;    // [N,256] bf16: X cast / h
    u16* Ae   = (u16*)(ws + off); off += (size_t)M * 160;    // [M,320] bf16 edge buffer
    u16* WxvT0h = (u16*)(ws + off); off += (size_t)(512 * 128) / 2;
    u16* WxvT0l = (u16*)(ws + off); off += (size_t)(512 * 128) / 2;
    u16* WtT0h  = (u16*)(ws + off); off += (size_t)(256 * 320) / 2;
    u16* WtT0l  = (u16*)(ws + off); off += (size_t)(256 * 320) / 2;
    u16* WxvT1h = (u16*)(ws + off); off += (size_t)(512 * 256) / 2;
    u16* WxvT1l = (u16*)(ws + off); off += (size_t)(512 * 256) / 2;
    u16* WtT1h  = (u16*)(ws + off); off += (size_t)(256 * 320) / 2;
    u16* WtT1l  = (u16*)(ws + off); off += (size_t)(256 * 320) / 2;
    u16* WfTh   = (u16*)(ws + off); off += (size_t)(128 * 256) / 2;
    u16* WfTl   = (u16*)(ws + off); off += (size_t)(128 * 256) / 2;
    float* score = ws + off; off += (size_t)N;
    int* eoff   = (int*)(ws + off); off += (size_t)(M + 1);
    int* ecnt   = (int*)(ws + off); off += (size_t)M;
    int* ecur   = (int*)(ws + off); off += (size_t)M;
    int* psumE  = (int*)(ws + off); off += 64;
    int* edge_v = (int*)(ws + off); off += (size_t)NNZ;
    int* noff   = (int*)(ws + off); off += (size_t)(N + 1);
    int* ncnt   = (int*)(ws + off); off += (size_t)N;
    int* ncur   = (int*)(ws + off); off += (size_t)N;
    int* psumN  = (int*)(ws + off); off += 64;
    int* node_e = (int*)(ws + off); off += (size_t)NNZ;

    // ---- CSR build ----
    hipMemsetAsync(ecnt, 0, (size_t)M * 4, stream);
    hipMemsetAsync(ncnt, 0, (size_t)N * 4, stream);
    count_kernel<<<((NNZ + 3) / 4 + 255) / 256, 256, 0, stream>>>(V, E, ecnt, ncnt, NNZ);
    int nbE = (M + 1023) / 1024, nbN = (N + 1023) / 1024;
    scan_part1<<<nbE, 256, 0, stream>>>(ecnt, eoff, psumE, M);
    scan_part1<<<nbN, 256, 0, stream>>>(ncnt, noff, psumN, N);
    scan_part2<<<nbE, 256, 0, stream>>>(ecnt, eoff, psumE, ecur, M);
    scan_part2<<<nbN, 256, 0, stream>>>(ncnt, noff, psumN, ncur, N);
    fill_kernel<<<((NNZ + 3) / 4 + 255) / 256, 256, 0, stream>>>(V, E, ecur, ncur, edge_v, node_e, NNZ);

    // ---- input casts (one launch) ----
    int n4x = N * 128 / 4, nS = M * 64;
    cast_inputs_kernel<<<(n4x + nS + 255) / 256, 256, 0, stream>>>(X, Abuf, n4x, S, Ae, nS);

    // ---- weight transpose+split (one launch, 7 jobs) ----
    WJobs jobs;
    jobs.j[0] = {Wx0, WxvT0h,                WxvT0l,                128, 8};
    jobs.j[1] = {Wv0, WxvT0h + 256 * 128,    WxvT0l + 256 * 128,    128, 8};
    jobs.j[2] = {Wt0, WtT0h,                 WtT0l,                 320, 8};
    jobs.j[3] = {Wx1, WxvT1h,                WxvT1l,                256, 8};
    jobs.j[4] = {Wv1, WxvT1h + 256 * 256,    WxvT1l + 256 * 256,    256, 8};
    jobs.j[5] = {Wt1, WtT1h,                 WtT1l,                 320, 8};
    jobs.j[6] = {Wf,  WfTh,                  WfTl,                  256, 7};
    dim3 wg((320 * 256 + 255) / 256, 7);
    wsplit_all_kernel<<<wg, 256, 0, stream>>>(jobs);

    // ---- layers (h bf16 lands back in Abuf) ----
    run_layer(Abuf, 128, WxvT0h, WxvT0l, bx0, bv0, a0,
              WtT0h, WtT0l, bt0, Ae, XinitB, Xfeatb, Ybufb, score,
              eoff, edge_v, noff, node_e, N, M, stream);
    run_layer(Abuf, 256, WxvT1h, WxvT1l, bx1, bv1, a1,
              WtT1h, WtT1l, bt1, Ae, XinitB, Xfeatb, Ybufb, score,
              eoff, edge_v, noff, node_e, N, M, stream);

    // ---- hyperconv (all-bf16 intermediates, fp32 final out) ----
    u16* Xcb = XfeatR;   // [N,128] bf16 (Xfeatb/Ybufb dead)
    u16* Yhb = XinitB;   // [M,128] bf16 (Xinit dead)
    gemm(Abuf, 256, WfTh, WfTl, 256, bf, nullptr, Xcb, nullptr, N, 128, 128, 256, stream);
    yh_kernel<<<(M + 15) / 16, 256, 0, stream>>>(Xcb, eoff, edge_v, noff, Yhb, M);
    xo_final_kernel<<<(N + 15) / 16, 256, 0, stream>>>(Yhb, noff, node_e, (float*)d_out, N);
}

// Round 13
// 553.148 us; speedup vs baseline: 1.5104x; 1.0544x over previous
//
#include <hip/hip_runtime.h>
#include <hip/hip_bf16.h>

typedef unsigned short u16;
typedef __attribute__((ext_vector_type(4))) u16 u16x4;
typedef __attribute__((ext_vector_type(8))) u16 u16x8;
typedef __attribute__((ext_vector_type(8))) __bf16 bf16x8;
typedef __attribute__((ext_vector_type(4))) float f32x4;

__device__ __forceinline__ u16 f2bf(float x) {
    unsigned u = __float_as_uint(x);
    unsigned r = u + 0x7FFF + ((u >> 16) & 1);
    return (u16)(r >> 16);
}
__device__ __forceinline__ float bf2f(u16 h) {
    return __uint_as_float(((unsigned)h) << 16);
}

__device__ __forceinline__ void gl_lds16(const void* g, void* l) {
    __builtin_amdgcn_global_load_lds(
        (const __attribute__((address_space(1))) void*)g,
        (__attribute__((address_space(3))) void*)l, 16, 0, 0);
}

// =============== bf16-activation x split-bf16-weight MFMA GEMM ===============
// Out[M,Nc] = A[M,K] @ B^T[Nc,K] + bias.  A: plain bf16.  B: (hi,lo) pair.
// acc = A*Bhi + A*Blo.  Output bf16, split into two regions:
//   cols [0,ncSplit)   -> CbA (stride ncSplit,    bias biasF)
//   cols [ncSplit,Nc)  -> CbB (stride Nc-ncSplit, bias biasB)
// Epilogue: per-wave LDS transpose -> u16x8 (16B) global stores.
__global__ __launch_bounds__(256) void gemm_mfma_kernel(
    const u16* __restrict__ A, int lda,
    const u16* __restrict__ Bhi, const u16* __restrict__ Blo, int ldb,
    const float* __restrict__ biasF, const float* __restrict__ biasB,
    u16* __restrict__ CbA, u16* __restrict__ CbB,
    int M, int Nc, int ncSplit, int K)
{
    __shared__ __align__(16) u16 lds[3 * 4096];
    u16* sA   = lds;
    u16* sBhi = lds + 4096;
    u16* sBlo = lds + 8192;

    int tid = threadIdx.x;
    int wave = tid >> 6, lane = tid & 63;
    int row0 = blockIdx.x * 128, col0 = blockIdx.y * 128;

    long gA[2], gB[2];
    int sOff[2];
#pragma unroll
    for (int r = 0; r < 2; ++r) {
        int trow = r * 64 + wave * 16 + (lane >> 2);
        int chunk = (lane & 3) ^ ((trow >> 2) & 3);
        int arow = min(row0 + trow, M - 1);
        gA[r] = (long)arow * lda + chunk * 8;
        gB[r] = (long)(col0 + trow) * ldb + chunk * 8;
        sOff[r] = (r * 64 + wave * 16) * 32;
    }

    int m16 = lane & 15, quad = lane >> 4;
    int offA[4], offB[4];
#pragma unroll
    for (int i = 0; i < 4; ++i) {
        int ra = (wave & 1) * 64 + i * 16 + m16;
        offA[i] = ra * 32 + ((quad ^ ((ra >> 2) & 3)) * 8);
        int rb = (wave >> 1) * 64 + i * 16 + m16;
        offB[i] = rb * 32 + ((quad ^ ((rb >> 2) & 3)) * 8);
    }

    f32x4 acc[4][4];
#pragma unroll
    for (int i = 0; i < 4; ++i)
#pragma unroll
        for (int j = 0; j < 4; ++j) {
            f32x4 z = {0.f, 0.f, 0.f, 0.f};
            acc[i][j] = z;
        }

    int nkb = K >> 5;
    for (int kb = 0; kb < nkb; ++kb) {
#pragma unroll
        for (int r = 0; r < 2; ++r) {
            gl_lds16(A + gA[r], sA + sOff[r]);
            gl_lds16(Bhi + gB[r], sBhi + sOff[r]);
            gl_lds16(Blo + gB[r], sBlo + sOff[r]);
        }
        __syncthreads();
        bf16x8 av[4], bh[4], bl[4];
#pragma unroll
        for (int i = 0; i < 4; ++i) {
            av[i] = *(const bf16x8*)(sA + offA[i]);
            bh[i] = *(const bf16x8*)(sBhi + offB[i]);
            bl[i] = *(const bf16x8*)(sBlo + offB[i]);
        }
#pragma unroll
        for (int i = 0; i < 4; ++i)
#pragma unroll
            for (int j = 0; j < 4; ++j) {
                acc[i][j] = __builtin_amdgcn_mfma_f32_16x16x32_bf16(av[i], bh[j], acc[i][j], 0, 0, 0);
                acc[i][j] = __builtin_amdgcn_mfma_f32_16x16x32_bf16(av[i], bl[j], acc[i][j], 0, 0, 0);
            }
        __syncthreads();
#pragma unroll
        for (int r = 0; r < 2; ++r) { gA[r] += 32; gB[r] += 32; }
    }

    // ---- epilogue: per-wave LDS transpose, 16B stores ----
    int wm = (wave & 1) * 64, wn = (wave >> 1) * 64;
    float bj[4];
#pragma unroll
    for (int j = 0; j < 4; ++j) {
        int col = col0 + wn + j * 16 + m16;
        bj[j] = (col >= ncSplit) ? biasB[col - ncSplit] : biasF[col];
    }
    u16* wlds = lds + wave * 2560;   // 64 rows x 40 u16 (32 data + 8 pad)
#pragma unroll
    for (int c = 0; c < 2; ++c) {
        __syncthreads();
#pragma unroll
        for (int jj = 0; jj < 2; ++jj) {
            int j = 2 * c + jj;
#pragma unroll
            for (int i = 0; i < 4; ++i)
#pragma unroll
                for (int rr = 0; rr < 4; ++rr) {
                    int lr = i * 16 + quad * 4 + rr;
                    int lc = jj * 16 + m16;
                    int seg = (lc >> 3) ^ ((lr >> 2) & 3);
                    wlds[lr * 40 + seg * 8 + (lc & 7)] = f2bf(acc[i][j][rr] + bj[j]);
                }
        }
        __syncthreads();
        int colbase = col0 + wn + c * 32;
        bool isB = (colbase >= ncSplit);
        u16* Cp = isB ? CbB : CbA;
        int stride = isB ? (Nc - ncSplit) : ncSplit;
        int cc = isB ? (colbase - ncSplit) : colbase;
        int row = row0 + wm + lane;
        if (row < M) {
#pragma unroll
            for (int s = 0; s < 4; ++s) {
                int sseg = s ^ ((lane >> 2) & 3);      // LDS segment holding logical col-block s
                u16x8 vv = *(const u16x8*)(wlds + lane * 40 + sseg * 8);
                *(u16x8*)(Cp + (size_t)row * stride + cc + s * 8) = vv;   // de-swizzled target
            }
        }
    }
}

// =============== prep kernels (merged) ===============
struct WJob { const float* W; u16* Whi; u16* Wlo; int K; int ncShift; };
struct WJobs { WJob j[7]; };

__global__ void wsplit_all_kernel(WJobs jobs)
{
    WJob jb = jobs.j[blockIdx.y];
    int Nc = 1 << jb.ncShift;
    int idx = blockIdx.x * blockDim.x + threadIdx.x;
    if (idx >= jb.K * Nc) return;
    int k = idx >> jb.ncShift, n = idx & (Nc - 1);
    float x = jb.W[idx];
    u16 h = f2bf(x);
    u16 l = f2bf(x - bf2f(h));
    jb.Whi[(size_t)n * jb.K + k] = h;
    jb.Wlo[(size_t)n * jb.K + k] = l;
}

__global__ void cast_inputs_kernel(const float* __restrict__ X, u16* __restrict__ Abuf, int n4x,
                                   const float* __restrict__ S, u16* __restrict__ Ae, int nS)
{
    int id = blockIdx.x * blockDim.x + threadIdx.x;
    if (id < n4x) {
        float4 x = ((const float4*)X)[id];
        u16x4 h;
        h.x = f2bf(x.x); h.y = f2bf(x.y); h.z = f2bf(x.z); h.w = f2bf(x.w);
        *(u16x4*)(Abuf + (size_t)id * 4) = h;
    } else {
        int i = id - n4x;
        if (i < nS) {
            int e = i >> 6, c = i & 63;
            Ae[(size_t)e * 320 + 256 + c] = f2bf(S[i]);
        }
    }
}

// =============== CSR build ===============
__global__ void count_kernel(const int* __restrict__ V, const int* __restrict__ E,
                             int* ecnt, int* ncnt, int nnz)
{
    int k0 = (blockIdx.x * blockDim.x + threadIdx.x) * 4;
    if (k0 >= nnz) return;
    int kmax = min(nnz - k0, 4);
    int vv[4], ee[4];
    if (kmax == 4) {
        int4 v4 = *(const int4*)(V + k0);
        int4 e4 = *(const int4*)(E + k0);
        vv[0] = v4.x; vv[1] = v4.y; vv[2] = v4.z; vv[3] = v4.w;
        ee[0] = e4.x; ee[1] = e4.y; ee[2] = e4.z; ee[3] = e4.w;
    } else {
        for (int q = 0; q < kmax; ++q) { vv[q] = V[k0 + q]; ee[q] = E[k0 + q]; }
    }
    for (int q = 0; q < kmax; ++q) atomicAdd(&ecnt[ee[q]], 1);
    for (int q = 0; q < kmax; ++q) atomicAdd(&ncnt[vv[q]], 1);
}

__global__ __launch_bounds__(256) void scan_part1(const int* __restrict__ cnt,
                                                  int* __restrict__ off,
                                                  int* __restrict__ psum, int n)
{
    __shared__ int tsum[256];
    int base = blockIdx.x * 1024;
    int t = threadIdx.x;
    int idx0 = base + t * 4;
    int4 c = make_int4(0, 0, 0, 0);
    if (idx0 + 3 < n) c = *(const int4*)(cnt + idx0);
    else {
        if (idx0 + 0 < n) c.x = cnt[idx0 + 0];
        if (idx0 + 1 < n) c.y = cnt[idx0 + 1];
        if (idx0 + 2 < n) c.z = cnt[idx0 + 2];
        if (idx0 + 3 < n) c.w = cnt[idx0 + 3];
    }
    int s = c.x + c.y + c.z + c.w;
    tsum[t] = s;
    __syncthreads();
    for (int o = 1; o < 256; o <<= 1) {
        int v = (t >= o) ? tsum[t - o] : 0;
        __syncthreads();
        tsum[t] += v;
        __syncthreads();
    }
    int run = tsum[t] - s;
    run += c.x; if (idx0 + 0 < n) off[idx0 + 1] = run;
    run += c.y; if (idx0 + 1 < n) off[idx0 + 2] = run;
    run += c.z; if (idx0 + 2 < n) off[idx0 + 3] = run;
    run += c.w; if (idx0 + 3 < n) off[idx0 + 4] = run;
    if (t == 255) psum[blockIdx.x] = tsum[255];
}

__global__ __launch_bounds__(256) void scan_part2(const int* __restrict__ cnt,
                                                  int* __restrict__ off,
                                                  const int* __restrict__ psum,
                                                  int* __restrict__ cur, int n)
{
    __shared__ int bpref;
    int t = threadIdx.x;
    int b = blockIdx.x;
    if (t < 64) {
        int s = (t < b) ? psum[t] : 0;
#pragma unroll
        for (int o = 32; o; o >>= 1) s += __shfl_xor(s, o);
        if (t == 0) {
            bpref = s;
            if (b == 0) off[0] = 0;
        }
    }
    __syncthreads();
    int base = b * 1024 + t * 4;
#pragma unroll
    for (int q = 0; q < 4; ++q) {
        int i = base + q;
        if (i < n) {
            int inc = off[i + 1] + bpref;
            off[i + 1] = inc;
            cur[i] = inc - cnt[i];
        }
    }
}

__global__ void fill_kernel(const int* __restrict__ V, const int* __restrict__ E,
                            int* ecur, int* ncur, int* edge_v, int* node_e, int nnz)
{
    int k0 = (blockIdx.x * blockDim.x + threadIdx.x) * 4;
    if (k0 >= nnz) return;
    int kmax = min(nnz - k0, 4);
    int vv[4], ee[4], js[4], is_[4];
    if (kmax == 4) {
        int4 v4 = *(const int4*)(V + k0);
        int4 e4 = *(const int4*)(E + k0);
        vv[0] = v4.x; vv[1] = v4.y; vv[2] = v4.z; vv[3] = v4.w;
        ee[0] = e4.x; ee[1] = e4.y; ee[2] = e4.z; ee[3] = e4.w;
    } else {
        for (int q = 0; q < kmax; ++q) { vv[q] = V[k0 + q]; ee[q] = E[k0 + q]; }
    }
    for (int q = 0; q < kmax; ++q) js[q] = atomicAdd(&ecur[ee[q]], 1);
    for (int q = 0; q < kmax; ++q) is_[q] = atomicAdd(&ncur[vv[q]], 1);
    for (int q = 0; q < kmax; ++q) edge_v[js[q]] = vv[q];
    for (int q = 0; q < kmax; ++q) node_e[is_[q]] = ee[q];
}

// =============== graph kernels ===============
__global__ void score_kernel(const u16* __restrict__ Xf, const float* __restrict__ a,
                             float* __restrict__ score, int N)
{
    int row = blockIdx.x * (blockDim.x >> 6) + (threadIdx.x >> 6);
    int lane = threadIdx.x & 63;
    if (row >= N) return;
    u16x4 x = *(const u16x4*)(Xf + (size_t)row * 256 + lane * 4);
    float4 av = *(const float4*)(a + lane * 4);
    float p = bf2f(x.x) * av.x + bf2f(x.y) * av.y + bf2f(x.z) * av.z + bf2f(x.w) * av.w;
#pragma unroll
    for (int off = 32; off; off >>= 1) p += __shfl_down(p, off);
    if (lane == 0) score[row] = p;
}

__device__ __forceinline__ float lrelu(float s) { return s >= 0.f ? s : 0.2f * s; }

__global__ void v2e_fused_kernel(const u16* __restrict__ Xf,
                                 const float* __restrict__ score,
                                 const int* __restrict__ eoff,
                                 const int* __restrict__ edge_v,
                                 u16* __restrict__ Ae, int M)
{
    int e = blockIdx.x * 8 + (threadIdx.x >> 5);
    if (e >= M) return;
    int sl = threadIdx.x & 31;
    int j0 = eoff[e], j1 = eoff[e + 1];
    float m = -INFINITY;
    for (int j = j0 + sl; j < j1; j += 32) m = fmaxf(m, lrelu(score[edge_v[j]]));
#pragma unroll
    for (int o = 16; o; o >>= 1) m = fmaxf(m, __shfl_xor(m, o));
    float sum = 0.f;
    for (int j = j0 + sl; j < j1; j += 32) sum += expf(lrelu(score[edge_v[j]]) - m);
#pragma unroll
    for (int o = 16; o; o >>= 1) sum += __shfl_xor(sum, o);
    float inv = (j1 > j0) ? 1.0f / sum : 0.f;

    float acc[8] = {0.f, 0.f, 0.f, 0.f, 0.f, 0.f, 0.f, 0.f};
    int col = sl * 8;
    int j = j0;
    for (; j + 3 < j1; j += 4) {
        int v0 = edge_v[j + 0], v1 = edge_v[j + 1], v2 = edge_v[j + 2], v3 = edge_v[j + 3];
        float s0 = score[v0], s1 = score[v1], s2 = score[v2], s3 = score[v3];
        u16x8 r0 = *(const u16x8*)(Xf + (size_t)v0 * 256 + col);
        u16x8 r1 = *(const u16x8*)(Xf + (size_t)v1 * 256 + col);
        u16x8 r2 = *(const u16x8*)(Xf + (size_t)v2 * 256 + col);
        u16x8 r3 = *(const u16x8*)(Xf + (size_t)v3 * 256 + col);
        float w0 = expf(lrelu(s0) - m) * inv;
        float w1 = expf(lrelu(s1) - m) * inv;
        float w2 = expf(lrelu(s2) - m) * inv;
        float w3 = expf(lrelu(s3) - m) * inv;
#pragma unroll
        for (int q = 0; q < 8; ++q) {
            acc[q] += bf2f(r0[q]) * w0;
            acc[q] += bf2f(r1[q]) * w1;
            acc[q] += bf2f(r2[q]) * w2;
            acc[q] += bf2f(r3[q]) * w3;
        }
    }
    for (; j < j1; ++j) {
        int v = edge_v[j];
        float ww = expf(lrelu(score[v]) - m) * inv;
        u16x8 r = *(const u16x8*)(Xf + (size_t)v * 256 + col);
#pragma unroll
        for (int q = 0; q < 8; ++q) acc[q] += bf2f(r[q]) * ww;
    }
    u16x8 hv;
#pragma unroll
    for (int q = 0; q < 8; ++q) {
        float vq = acc[q];
        vq = vq > 0.f ? vq : expm1f(vq);
        hv[q] = f2bf(vq);
    }
    *(u16x8*)(Ae + (size_t)e * 320 + col) = hv;
}

__global__ void e2v_finish_kernel(const u16* __restrict__ Y,
                                  const int* __restrict__ noff,
                                  const int* __restrict__ node_e,
                                  const u16* __restrict__ Xinit,
                                  u16* __restrict__ H, int N)
{
    int v = blockIdx.x * 8 + (threadIdx.x >> 5);
    if (v >= N) return;
    int sl = threadIdx.x & 31;
    int col = sl * 8;
    int i0 = noff[v], i1 = noff[v + 1];
    float acc[8] = {0.f, 0.f, 0.f, 0.f, 0.f, 0.f, 0.f, 0.f};
    int i = i0;
    for (; i + 3 < i1; i += 4) {
        int e0 = node_e[i + 0], e1 = node_e[i + 1], e2 = node_e[i + 2], e3 = node_e[i + 3];
        u16x8 r0 = *(const u16x8*)(Y + (size_t)e0 * 256 + col);
        u16x8 r1 = *(const u16x8*)(Y + (size_t)e1 * 256 + col);
        u16x8 r2 = *(const u16x8*)(Y + (size_t)e2 * 256 + col);
        u16x8 r3 = *(const u16x8*)(Y + (size_t)e3 * 256 + col);
#pragma unroll
        for (int q = 0; q < 8; ++q) {
            acc[q] += bf2f(r0[q]);
            acc[q] += bf2f(r1[q]);
            acc[q] += bf2f(r2[q]);
            acc[q] += bf2f(r3[q]);
        }
    }
    for (; i < i1; ++i) {
        int e = node_e[i];
        u16x8 r = *(const u16x8*)(Y + (size_t)e * 256 + col);
#pragma unroll
        for (int q = 0; q < 8; ++q) acc[q] += bf2f(r[q]);
    }
    float inv = (i1 > i0) ? 1.0f / (float)(i1 - i0) : 0.f;
    size_t base = (size_t)v * 256 + col;
    u16x8 xi = *(const u16x8*)(Xinit + base);
    u16x8 hv;
#pragma unroll
    for (int q = 0; q < 8; ++q) {
        float mm = acc[q] * inv;
        float oq = (mm > 0.f ? mm : expm1f(mm)) + bf2f(xi[q]);
        hv[q] = f2bf(oq);
    }
    *(u16x8*)(H + base) = hv;
}

// =============== hyperconv ===============
__global__ void yh_kernel(const u16* __restrict__ Xc,
                          const int* __restrict__ eoff, const int* __restrict__ edge_v,
                          const int* __restrict__ noff, u16* __restrict__ Yh, int M)
{
    int e = blockIdx.x * 16 + (threadIdx.x >> 4);
    if (e >= M) return;
    int sl = threadIdx.x & 15;
    int col = sl * 8;
    int j0 = eoff[e], j1 = eoff[e + 1];

    float dsum = 0.f;
    for (int j = j0 + sl; j < j1; j += 16) {
        int v = edge_v[j];
        dsum += (float)(noff[v + 1] - noff[v]);
    }
#pragma unroll
    for (int o = 8; o; o >>= 1) dsum += __shfl_xor(dsum, o);
    float De = dsum / ((float)(j1 - j0) + 1.0f);
    float deinv = De > 0.f ? rsqrtf(De) : 1.0f;

    float acc[8] = {0.f, 0.f, 0.f, 0.f, 0.f, 0.f, 0.f, 0.f};
    int j = j0;
    for (; j + 3 < j1; j += 4) {
        int v0 = edge_v[j + 0], v1 = edge_v[j + 1], v2 = edge_v[j + 2], v3 = edge_v[j + 3];
        u16x8 r0 = *(const u16x8*)(Xc + (size_t)v0 * 128 + col);
        u16x8 r1 = *(const u16x8*)(Xc + (size_t)v1 * 128 + col);
        u16x8 r2 = *(const u16x8*)(Xc + (size_t)v2 * 128 + col);
        u16x8 r3 = *(const u16x8*)(Xc + (size_t)v3 * 128 + col);
#pragma unroll
        for (int q = 0; q < 8; ++q) {
            acc[q] += bf2f(r0[q]);
            acc[q] += bf2f(r1[q]);
            acc[q] += bf2f(r2[q]);
            acc[q] += bf2f(r3[q]);
        }
    }
    for (; j < j1; ++j) {
        int v = edge_v[j];
        u16x8 r = *(const u16x8*)(Xc + (size_t)v * 128 + col);
#pragma unroll
        for (int q = 0; q < 8; ++q) acc[q] += bf2f(r[q]);
    }
    float sc = ((j1 > j0) ? 1.0f / (float)(j1 - j0) : 0.f) * deinv;
    u16x8 o8;
#pragma unroll
    for (int q = 0; q < 8; ++q) o8[q] = f2bf(acc[q] * sc);
    *(u16x8*)(Yh + (size_t)e * 128 + col) = o8;
}

__global__ void xo_final_kernel(const u16* __restrict__ Yh,
                                const int* __restrict__ noff, const int* __restrict__ node_e,
                                float* __restrict__ out, int N)
{
    int v = blockIdx.x * 16 + (threadIdx.x >> 4);
    if (v >= N) return;
    int sl = threadIdx.x & 15;
    int col = sl * 8;
    int i0 = noff[v], i1 = noff[v + 1];
    float acc[8] = {0.f, 0.f, 0.f, 0.f, 0.f, 0.f, 0.f, 0.f};
    int i = i0;
    for (; i + 3 < i1; i += 4) {
        int e0 = node_e[i + 0], e1 = node_e[i + 1], e2 = node_e[i + 2], e3 = node_e[i + 3];
        u16x8 r0 = *(const u16x8*)(Yh + (size_t)e0 * 128 + col);
        u16x8 r1 = *(const u16x8*)(Yh + (size_t)e1 * 128 + col);
        u16x8 r2 = *(const u16x8*)(Yh + (size_t)e2 * 128 + col);
        u16x8 r3 = *(const u16x8*)(Yh + (size_t)e3 * 128 + col);
#pragma unroll
        for (int q = 0; q < 8; ++q) {
            acc[q] += bf2f(r0[q]);
            acc[q] += bf2f(r1[q]);
            acc[q] += bf2f(r2[q]);
            acc[q] += bf2f(r3[q]);
        }
    }
    for (; i < i1; ++i) {
        int e = node_e[i];
        u16x8 r = *(const u16x8*)(Yh + (size_t)e * 128 + col);
#pragma unroll
        for (int q = 0; q < 8; ++q) acc[q] += bf2f(r[q]);
    }
    float sc = (i1 > i0) ? rsqrtf((float)(i1 - i0)) : 0.f;
    float4 oA, oB;
    oA.x = acc[0] * sc; oA.y = acc[1] * sc; oA.z = acc[2] * sc; oA.w = acc[3] * sc;
    oB.x = acc[4] * sc; oB.y = acc[5] * sc; oB.z = acc[6] * sc; oB.w = acc[7] * sc;
    float* d = out + (size_t)v * 128 + col;
    *(float4*)d = oA;
    *(float4*)(d + 4) = oB;
}

// =============== host-side ===============
static void gemm(const u16* A, int lda,
                 const u16* Bhi, const u16* Blo, int ldb,
                 const float* biasF, const float* biasB,
                 u16* CbA, u16* CbB, int M, int Nc, int ncSplit, int K,
                 hipStream_t stream)
{
    dim3 g((M + 127) / 128, Nc / 128);
    gemm_mfma_kernel<<<g, 256, 0, stream>>>(A, lda, Bhi, Blo, ldb, biasF, biasB,
                                            CbA, CbB, M, Nc, ncSplit, K);
}

static void run_layer(u16* A, int K,
                      const u16* WxvThi, const u16* WxvTlo,
                      const float* bx, const float* bv, const float* a,
                      const u16* WtThi, const u16* WtTlo, const float* bt,
                      u16* Ae,
                      u16* XinitB, u16* Xfeatb, u16* Ybufb, float* score,
                      const int* eoff, const int* edge_v,
                      const int* noff, const int* node_e,
                      int N, int M, hipStream_t stream)
{
    gemm(A, K, WxvThi, WxvTlo, K, bx, bv, XinitB, Xfeatb, N, 512, 256, K, stream);
    score_kernel<<<(N + 3) / 4, 256, 0, stream>>>(Xfeatb, a, score, N);
    v2e_fused_kernel<<<(M + 7) / 8, 256, 0, stream>>>(Xfeatb, score, eoff, edge_v, Ae, M);
    gemm(Ae, 320, WtThi, WtTlo, 320, nullptr, bt, nullptr, Ybufb, M, 256, 0, 320, stream);
    e2v_finish_kernel<<<(N + 7) / 8, 256, 0, stream>>>(Ybufb, noff, node_e, XinitB, A, N);
}

extern "C" void kernel_launch(void* const* d_in, const int* in_sizes, int n_in,
                              void* d_out, int out_size, void* d_ws, size_t ws_size,
                              hipStream_t stream)
{
    const float* X   = (const float*)d_in[0];
    const int*   V   = (const int*)d_in[1];
    const int*   E   = (const int*)d_in[2];
    const float* S   = (const float*)d_in[3];
    const float* Wx0 = (const float*)d_in[4];  const float* bx0 = (const float*)d_in[5];
    const float* Wv0 = (const float*)d_in[6];  const float* bv0 = (const float*)d_in[7];
    const float* a0  = (const float*)d_in[8];
    const float* Wt0 = (const float*)d_in[9];  const float* bt0 = (const float*)d_in[10];
    const float* Wx1 = (const float*)d_in[11]; const float* bx1 = (const float*)d_in[12];
    const float* Wv1 = (const float*)d_in[13]; const float* bv1 = (const float*)d_in[14];
    const float* a1  = (const float*)d_in[15];
    const float* Wt1 = (const float*)d_in[16]; const float* bt1 = (const float*)d_in[17];
    const float* Wf  = (const float*)d_in[18]; const float* bf  = (const float*)d_in[19];

    int N   = in_sizes[0] / 128;
    int NNZ = in_sizes[1];
    int M   = in_sizes[3] / 64;

    float* ws = (float*)d_ws;
    size_t off = 0;
    u16* XinitB = (u16*)(ws + off); off += (size_t)N * 128;  // [N,256] bf16; also Yh [M,128] bf16
    u16* XfeatR = (u16*)(ws + off); off += (size_t)N * 128;  // Xfeatb/Ybufb/Xcb
    u16* Xfeatb = XfeatR;
    u16* Ybufb  = XfeatR;
    u16* Abuf = (u16*)(ws + off); off += (size_t)N * 128;    // [N,256] bf16: X cast / h
    u16* Ae   = (u16*)(ws + off); off += (size_t)M * 160;    // [M,320] bf16 edge buffer
    u16* WxvT0h = (u16*)(ws + off); off += (size_t)(512 * 128) / 2;
    u16* WxvT0l = (u16*)(ws + off); off += (size_t)(512 * 128) / 2;
    u16* WtT0h  = (u16*)(ws + off); off += (size_t)(256 * 320) / 2;
    u16* WtT0l  = (u16*)(ws + off); off += (size_t)(256 * 320) / 2;
    u16* WxvT1h = (u16*)(ws + off); off += (size_t)(512 * 256) / 2;
    u16* WxvT1l = (u16*)(ws + off); off += (size_t)(512 * 256) / 2;
    u16* WtT1h  = (u16*)(ws + off); off += (size_t)(256 * 320) / 2;
    u16* WtT1l  = (u16*)(ws + off); off += (size_t)(256 * 320) / 2;
    u16* WfTh   = (u16*)(ws + off); off += (size_t)(128 * 256) / 2;
    u16* WfTl   = (u16*)(ws + off); off += (size_t)(128 * 256) / 2;
    float* score = ws + off; off += (size_t)N;
    int* eoff   = (int*)(ws + off); off += (size_t)(M + 1);
    int* ecnt   = (int*)(ws + off); off += (size_t)M;
    int* ecur   = (int*)(ws + off); off += (size_t)M;
    int* psumE  = (int*)(ws + off); off += 64;
    int* edge_v = (int*)(ws + off); off += (size_t)NNZ;
    int* noff   = (int*)(ws + off); off += (size_t)(N + 1);
    int* ncnt   = (int*)(ws + off); off += (size_t)N;
    int* ncur   = (int*)(ws + off); off += (size_t)N;
    int* psumN  = (int*)(ws + off); off += 64;
    int* node_e = (int*)(ws + off); off += (size_t)NNZ;

    // ---- CSR build ----
    hipMemsetAsync(ecnt, 0, (size_t)M * 4, stream);
    hipMemsetAsync(ncnt, 0, (size_t)N * 4, stream);
    count_kernel<<<((NNZ + 3) / 4 + 255) / 256, 256, 0, stream>>>(V, E, ecnt, ncnt, NNZ);
    int nbE = (M + 1023) / 1024, nbN = (N + 1023) / 1024;
    scan_part1<<<nbE, 256, 0, stream>>>(ecnt, eoff, psumE, M);
    scan_part1<<<nbN, 256, 0, stream>>>(ncnt, noff, psumN, N);
    scan_part2<<<nbE, 256, 0, stream>>>(ecnt, eoff, psumE, ecur, M);
    scan_part2<<<nbN, 256, 0, stream>>>(ncnt, noff, psumN, ncur, N);
    fill_kernel<<<((NNZ + 3) / 4 + 255) / 256, 256, 0, stream>>>(V, E, ecur, ncur, edge_v, node_e, NNZ);

    // ---- input casts (one launch) ----
    int n4x = N * 128 / 4, nS = M * 64;
    cast_inputs_kernel<<<(n4x + nS + 255) / 256, 256, 0, stream>>>(X, Abuf, n4x, S, Ae, nS);

    // ---- weight transpose+split (one launch, 7 jobs) ----
    WJobs jobs;
    jobs.j[0] = {Wx0, WxvT0h,                WxvT0l,                128, 8};
    jobs.j[1] = {Wv0, WxvT0h + 256 * 128,    WxvT0l + 256 * 128,    128, 8};
    jobs.j[2] = {Wt0, WtT0h,                 WtT0l,                 320, 8};
    jobs.j[3] = {Wx1, WxvT1h,                WxvT1l,                256, 8};
    jobs.j[4] = {Wv1, WxvT1h + 256 * 256,    WxvT1l + 256 * 256,    256, 8};
    jobs.j[5] = {Wt1, WtT1h,                 WtT1l,                 320, 8};
    jobs.j[6] = {Wf,  WfTh,                  WfTl,                  256, 7};
    dim3 wg((320 * 256 + 255) / 256, 7);
    wsplit_all_kernel<<<wg, 256, 0, stream>>>(jobs);

    // ---- layers (h bf16 lands back in Abuf) ----
    run_layer(Abuf, 128, WxvT0h, WxvT0l, bx0, bv0, a0,
              WtT0h, WtT0l, bt0, Ae, XinitB, Xfeatb, Ybufb, score,
              eoff, edge_v, noff, node_e, N, M, stream);
    run_layer(Abuf, 256, WxvT1h, WxvT1l, bx1, bv1, a1,
              WtT1h, WtT1l, bt1, Ae, XinitB, Xfeatb, Ybufb, score,
              eoff, edge_v, noff, node_e, N, M, stream);

    // ---- hyperconv (all-bf16 intermediates, fp32 final out) ----
    u16* Xcb = XfeatR;   // [N,128] bf16
    u16* Yhb = XinitB;   // [M,128] bf16
    gemm(Abuf, 256, WfTh, WfTl, 256, bf, nullptr, Xcb, nullptr, N, 128, 128, 256, stream);
    yh_kernel<<<(M + 15) / 16, 256, 0, stream>>>(Xcb, eoff, edge_v, noff, Yhb, M);
    xo_final_kernel<<<(N + 15) / 16, 256, 0, stream>>>(Yhb, noff, node_e, (float*)d_out, N);
}

// Round 14
// 546.832 us; speedup vs baseline: 1.5279x; 1.0116x over previous
//
#include <hip/hip_runtime.h>
#include <hip/hip_bf16.h>

typedef unsigned short u16;
typedef __attribute__((ext_vector_type(4))) u16 u16x4;
typedef __attribute__((ext_vector_type(8))) u16 u16x8;
typedef __attribute__((ext_vector_type(8))) __bf16 bf16x8;
typedef __attribute__((ext_vector_type(4))) float f32x4;

__device__ __forceinline__ u16 f2bf(float x) {
    unsigned u = __float_as_uint(x);
    unsigned r = u + 0x7FFF + ((u >> 16) & 1);
    return (u16)(r >> 16);
}
__device__ __forceinline__ float bf2f(u16 h) {
    return __uint_as_float(((unsigned)h) << 16);
}

__device__ __forceinline__ void gl_lds16(const void* g, void* l) {
    __builtin_amdgcn_global_load_lds(
        (const __attribute__((address_space(1))) void*)g,
        (__attribute__((address_space(3))) void*)l, 16, 0, 0);
}

// =============== bf16-activation x split-bf16-weight MFMA GEMM ===============
// Out[M,Nc] = A[M,K] @ B^T[Nc,K] + bias.  A: plain bf16.  B: (hi,lo) pair.
// acc = A*Bhi + A*Blo.  Output bf16, two regions split at ncSplit.
// 1-D grid, XCD-aware decode: all col-blocks of a row-block land on one XCD
// (assuming round-robin blockid%8 dispatch) so the A-tile L2-hits.
__global__ __launch_bounds__(256) void gemm_mfma_kernel(
    const u16* __restrict__ A, int lda,
    const u16* __restrict__ Bhi, const u16* __restrict__ Blo, int ldb,
    const float* __restrict__ biasF, const float* __restrict__ biasB,
    u16* __restrict__ CbA, u16* __restrict__ CbB,
    int M, int Nc, int ncSplit, int K, int nrb, int ncb)
{
    // decode: xcd = g&7, slot = g>>3; rb = xcd + 8*(slot/ncb), cb = slot%ncb
    int g = blockIdx.x;
    int xcd = g & 7;
    int slot = g >> 3;
    int rbi = slot / ncb;
    int cb = slot - rbi * ncb;
    int rb = xcd + 8 * rbi;
    if (rb >= nrb) return;

    __shared__ __align__(16) u16 lds[3 * 4096];
    u16* sA   = lds;
    u16* sBhi = lds + 4096;
    u16* sBlo = lds + 8192;

    int tid = threadIdx.x;
    int wave = tid >> 6, lane = tid & 63;
    int row0 = rb * 128, col0 = cb * 128;

    long gA[2], gB[2];
    int sOff[2];
#pragma unroll
    for (int r = 0; r < 2; ++r) {
        int trow = r * 64 + wave * 16 + (lane >> 2);
        int chunk = (lane & 3) ^ ((trow >> 2) & 3);
        int arow = min(row0 + trow, M - 1);
        gA[r] = (long)arow * lda + chunk * 8;
        gB[r] = (long)(col0 + trow) * ldb + chunk * 8;
        sOff[r] = (r * 64 + wave * 16) * 32;
    }

    int m16 = lane & 15, quad = lane >> 4;
    int offA[4], offB[4];
#pragma unroll
    for (int i = 0; i < 4; ++i) {
        int ra = (wave & 1) * 64 + i * 16 + m16;
        offA[i] = ra * 32 + ((quad ^ ((ra >> 2) & 3)) * 8);
        int rbx = (wave >> 1) * 64 + i * 16 + m16;
        offB[i] = rbx * 32 + ((quad ^ ((rbx >> 2) & 3)) * 8);
    }

    f32x4 acc[4][4];
#pragma unroll
    for (int i = 0; i < 4; ++i)
#pragma unroll
        for (int j = 0; j < 4; ++j) {
            f32x4 z = {0.f, 0.f, 0.f, 0.f};
            acc[i][j] = z;
        }

    int nkb = K >> 5;
    for (int kb = 0; kb < nkb; ++kb) {
#pragma unroll
        for (int r = 0; r < 2; ++r) {
            gl_lds16(A + gA[r], sA + sOff[r]);
            gl_lds16(Bhi + gB[r], sBhi + sOff[r]);
            gl_lds16(Blo + gB[r], sBlo + sOff[r]);
        }
        __syncthreads();
        bf16x8 av[4], bh[4], bl[4];
#pragma unroll
        for (int i = 0; i < 4; ++i) {
            av[i] = *(const bf16x8*)(sA + offA[i]);
            bh[i] = *(const bf16x8*)(sBhi + offB[i]);
            bl[i] = *(const bf16x8*)(sBlo + offB[i]);
        }
#pragma unroll
        for (int i = 0; i < 4; ++i)
#pragma unroll
            for (int j = 0; j < 4; ++j) {
                acc[i][j] = __builtin_amdgcn_mfma_f32_16x16x32_bf16(av[i], bh[j], acc[i][j], 0, 0, 0);
                acc[i][j] = __builtin_amdgcn_mfma_f32_16x16x32_bf16(av[i], bl[j], acc[i][j], 0, 0, 0);
            }
        __syncthreads();
#pragma unroll
        for (int r = 0; r < 2; ++r) { gA[r] += 32; gB[r] += 32; }
    }

    // ---- epilogue: per-wave LDS transpose, 16B stores ----
    int wm = (wave & 1) * 64, wn = (wave >> 1) * 64;
    float bj[4];
#pragma unroll
    for (int j = 0; j < 4; ++j) {
        int col = col0 + wn + j * 16 + m16;
        bj[j] = (col >= ncSplit) ? biasB[col - ncSplit] : biasF[col];
    }
    u16* wlds = lds + wave * 2560;   // 64 rows x 40 u16
#pragma unroll
    for (int c = 0; c < 2; ++c) {
        __syncthreads();
#pragma unroll
        for (int jj = 0; jj < 2; ++jj) {
            int j = 2 * c + jj;
#pragma unroll
            for (int i = 0; i < 4; ++i)
#pragma unroll
                for (int rr = 0; rr < 4; ++rr) {
                    int lr = i * 16 + quad * 4 + rr;
                    int lc = jj * 16 + m16;
                    int seg = (lc >> 3) ^ ((lr >> 2) & 3);
                    wlds[lr * 40 + seg * 8 + (lc & 7)] = f2bf(acc[i][j][rr] + bj[j]);
                }
        }
        __syncthreads();
        int colbase = col0 + wn + c * 32;
        bool isB = (colbase >= ncSplit);
        u16* Cp = isB ? CbB : CbA;
        int stride = isB ? (Nc - ncSplit) : ncSplit;
        int cc = isB ? (colbase - ncSplit) : colbase;
        int row = row0 + wm + lane;
        if (row < M) {
#pragma unroll
            for (int s = 0; s < 4; ++s) {
                int sseg = s ^ ((lane >> 2) & 3);
                u16x8 vv = *(const u16x8*)(wlds + lane * 40 + sseg * 8);
                *(u16x8*)(Cp + (size_t)row * stride + cc + s * 8) = vv;
            }
        }
    }
}

// =============== prep kernels (merged) ===============
struct WJob { const float* W; u16* Whi; u16* Wlo; int K; int ncShift; };
struct WJobs { WJob j[7]; };

__global__ void wsplit_all_kernel(WJobs jobs)
{
    WJob jb = jobs.j[blockIdx.y];
    int Nc = 1 << jb.ncShift;
    int idx = blockIdx.x * blockDim.x + threadIdx.x;
    if (idx >= jb.K * Nc) return;
    int k = idx >> jb.ncShift, n = idx & (Nc - 1);
    float x = jb.W[idx];
    u16 h = f2bf(x);
    u16 l = f2bf(x - bf2f(h));
    jb.Whi[(size_t)n * jb.K + k] = h;
    jb.Wlo[(size_t)n * jb.K + k] = l;
}

__global__ void cast_inputs_kernel(const float* __restrict__ X, u16* __restrict__ Abuf, int n4x,
                                   const float* __restrict__ S, u16* __restrict__ Ae, int nS)
{
    int id = blockIdx.x * blockDim.x + threadIdx.x;
    if (id < n4x) {
        float4 x = ((const float4*)X)[id];
        u16x4 h;
        h.x = f2bf(x.x); h.y = f2bf(x.y); h.z = f2bf(x.z); h.w = f2bf(x.w);
        *(u16x4*)(Abuf + (size_t)id * 4) = h;
    } else {
        int i = id - n4x;
        if (i < nS) {
            int e = i >> 6, c = i & 63;
            Ae[(size_t)e * 320 + 256 + c] = f2bf(S[i]);
        }
    }
}

// =============== CSR build (8-wide: 16 atomics in flight/thread) ===============
__global__ void count_kernel(const int* __restrict__ V, const int* __restrict__ E,
                             int* ecnt, int* ncnt, int nnz)
{
    int k0 = (blockIdx.x * blockDim.x + threadIdx.x) * 8;
    if (k0 >= nnz) return;
    int kmax = min(nnz - k0, 8);
    int vv[8], ee[8];
    if (kmax == 8) {
        int4 a = *(const int4*)(V + k0), b = *(const int4*)(V + k0 + 4);
        int4 c = *(const int4*)(E + k0), d = *(const int4*)(E + k0 + 4);
        vv[0]=a.x; vv[1]=a.y; vv[2]=a.z; vv[3]=a.w; vv[4]=b.x; vv[5]=b.y; vv[6]=b.z; vv[7]=b.w;
        ee[0]=c.x; ee[1]=c.y; ee[2]=c.z; ee[3]=c.w; ee[4]=d.x; ee[5]=d.y; ee[6]=d.z; ee[7]=d.w;
    } else {
        for (int q = 0; q < kmax; ++q) { vv[q] = V[k0 + q]; ee[q] = E[k0 + q]; }
    }
    for (int q = 0; q < kmax; ++q) atomicAdd(&ecnt[ee[q]], 1);
    for (int q = 0; q < kmax; ++q) atomicAdd(&ncnt[vv[q]], 1);
}

__global__ __launch_bounds__(256) void scan_part1(const int* __restrict__ cnt,
                                                  int* __restrict__ off,
                                                  int* __restrict__ psum, int n)
{
    __shared__ int tsum[256];
    int base = blockIdx.x * 1024;
    int t = threadIdx.x;
    int idx0 = base + t * 4;
    int4 c = make_int4(0, 0, 0, 0);
    if (idx0 + 3 < n) c = *(const int4*)(cnt + idx0);
    else {
        if (idx0 + 0 < n) c.x = cnt[idx0 + 0];
        if (idx0 + 1 < n) c.y = cnt[idx0 + 1];
        if (idx0 + 2 < n) c.z = cnt[idx0 + 2];
        if (idx0 + 3 < n) c.w = cnt[idx0 + 3];
    }
    int s = c.x + c.y + c.z + c.w;
    tsum[t] = s;
    __syncthreads();
    for (int o = 1; o < 256; o <<= 1) {
        int v = (t >= o) ? tsum[t - o] : 0;
        __syncthreads();
        tsum[t] += v;
        __syncthreads();
    }
    int run = tsum[t] - s;
    run += c.x; if (idx0 + 0 < n) off[idx0 + 1] = run;
    run += c.y; if (idx0 + 1 < n) off[idx0 + 2] = run;
    run += c.z; if (idx0 + 2 < n) off[idx0 + 3] = run;
    run += c.w; if (idx0 + 3 < n) off[idx0 + 4] = run;
    if (t == 255) psum[blockIdx.x] = tsum[255];
}

__global__ __launch_bounds__(256) void scan_part2(const int* __restrict__ cnt,
                                                  int* __restrict__ off,
                                                  const int* __restrict__ psum,
                                                  int* __restrict__ cur, int n)
{
    __shared__ int bpref;
    int t = threadIdx.x;
    int b = blockIdx.x;
    if (t < 64) {
        int s = (t < b) ? psum[t] : 0;
#pragma unroll
        for (int o = 32; o; o >>= 1) s += __shfl_xor(s, o);
        if (t == 0) {
            bpref = s;
            if (b == 0) off[0] = 0;
        }
    }
    __syncthreads();
    int base = b * 1024 + t * 4;
#pragma unroll
    for (int q = 0; q < 4; ++q) {
        int i = base + q;
        if (i < n) {
            int inc = off[i + 1] + bpref;
            off[i + 1] = inc;
            cur[i] = inc - cnt[i];
        }
    }
}

__global__ void fill_kernel(const int* __restrict__ V, const int* __restrict__ E,
                            int* ecur, int* ncur, int* edge_v, int* node_e, int nnz)
{
    int k0 = (blockIdx.x * blockDim.x + threadIdx.x) * 8;
    if (k0 >= nnz) return;
    int kmax = min(nnz - k0, 8);
    int vv[8], ee[8], js[8], is_[8];
    if (kmax == 8) {
        int4 a = *(const int4*)(V + k0), b = *(const int4*)(V + k0 + 4);
        int4 c = *(const int4*)(E + k0), d = *(const int4*)(E + k0 + 4);
        vv[0]=a.x; vv[1]=a.y; vv[2]=a.z; vv[3]=a.w; vv[4]=b.x; vv[5]=b.y; vv[6]=b.z; vv[7]=b.w;
        ee[0]=c.x; ee[1]=c.y; ee[2]=c.z; ee[3]=c.w; ee[4]=d.x; ee[5]=d.y; ee[6]=d.z; ee[7]=d.w;
    } else {
        for (int q = 0; q < kmax; ++q) { vv[q] = V[k0 + q]; ee[q] = E[k0 + q]; }
    }
    for (int q = 0; q < kmax; ++q) js[q] = atomicAdd(&ecur[ee[q]], 1);
    for (int q = 0; q < kmax; ++q) is_[q] = atomicAdd(&ncur[vv[q]], 1);
    for (int q = 0; q < kmax; ++q) edge_v[js[q]] = vv[q];
    for (int q = 0; q < kmax; ++q) node_e[is_[q]] = ee[q];
}

// =============== graph kernels ===============
__global__ void score_kernel(const u16* __restrict__ Xf, const float* __restrict__ a,
                             float* __restrict__ score, int N)
{
    int row = blockIdx.x * (blockDim.x >> 6) + (threadIdx.x >> 6);
    int lane = threadIdx.x & 63;
    if (row >= N) return;
    u16x4 x = *(const u16x4*)(Xf + (size_t)row * 256 + lane * 4);
    float4 av = *(const float4*)(a + lane * 4);
    float p = bf2f(x.x) * av.x + bf2f(x.y) * av.y + bf2f(x.z) * av.z + bf2f(x.w) * av.w;
#pragma unroll
    for (int off = 32; off; off >>= 1) p += __shfl_down(p, off);
    if (lane == 0) score[row] = p;
}

__device__ __forceinline__ float lrelu(float s) { return s >= 0.f ? s : 0.2f * s; }

__global__ void v2e_fused_kernel(const u16* __restrict__ Xf,
                                 const float* __restrict__ score,
                                 const int* __restrict__ eoff,
                                 const int* __restrict__ edge_v,
                                 u16* __restrict__ Ae, int M)
{
    int e = blockIdx.x * 8 + (threadIdx.x >> 5);
    if (e >= M) return;
    int sl = threadIdx.x & 31;
    int j0 = eoff[e], j1 = eoff[e + 1];
    float m = -INFINITY;
    for (int j = j0 + sl; j < j1; j += 32) m = fmaxf(m, lrelu(score[edge_v[j]]));
#pragma unroll
    for (int o = 16; o; o >>= 1) m = fmaxf(m, __shfl_xor(m, o));
    float sum = 0.f;
    for (int j = j0 + sl; j < j1; j += 32) sum += expf(lrelu(score[edge_v[j]]) - m);
#pragma unroll
    for (int o = 16; o; o >>= 1) sum += __shfl_xor(sum, o);
    float inv = (j1 > j0) ? 1.0f / sum : 0.f;

    float acc[8] = {0.f, 0.f, 0.f, 0.f, 0.f, 0.f, 0.f, 0.f};
    int col = sl * 8;
    int j = j0;
    for (; j + 3 < j1; j += 4) {
        int v0 = edge_v[j + 0], v1 = edge_v[j + 1], v2 = edge_v[j + 2], v3 = edge_v[j + 3];
        float s0 = score[v0], s1 = score[v1], s2 = score[v2], s3 = score[v3];
        u16x8 r0 = *(const u16x8*)(Xf + (size_t)v0 * 256 + col);
        u16x8 r1 = *(const u16x8*)(Xf + (size_t)v1 * 256 + col);
        u16x8 r2 = *(const u16x8*)(Xf + (size_t)v2 * 256 + col);
        u16x8 r3 = *(const u16x8*)(Xf + (size_t)v3 * 256 + col);
        float w0 = expf(lrelu(s0) - m) * inv;
        float w1 = expf(lrelu(s1) - m) * inv;
        float w2 = expf(lrelu(s2) - m) * inv;
        float w3 = expf(lrelu(s3) - m) * inv;
#pragma unroll
        for (int q = 0; q < 8; ++q) {
            acc[q] += bf2f(r0[q]) * w0;
            acc[q] += bf2f(r1[q]) * w1;
            acc[q] += bf2f(r2[q]) * w2;
            acc[q] += bf2f(r3[q]) * w3;
        }
    }
    for (; j < j1; ++j) {
        int v = edge_v[j];
        float ww = expf(lrelu(score[v]) - m) * inv;
        u16x8 r = *(const u16x8*)(Xf + (size_t)v * 256 + col);
#pragma unroll
        for (int q = 0; q < 8; ++q) acc[q] += bf2f(r[q]) * ww;
    }
    u16x8 hv;
#pragma unroll
    for (int q = 0; q < 8; ++q) {
        float vq = acc[q];
        vq = vq > 0.f ? vq : expm1f(vq);
        hv[q] = f2bf(vq);
    }
    *(u16x8*)(Ae + (size_t)e * 320 + col) = hv;
}

__global__ void e2v_finish_kernel(const u16* __restrict__ Y,
                                  const int* __restrict__ noff,
                                  const int* __restrict__ node_e,
                                  const u16* __restrict__ Xinit,
                                  u16* __restrict__ H, int N)
{
    int v = blockIdx.x * 8 + (threadIdx.x >> 5);
    if (v >= N) return;
    int sl = threadIdx.x & 31;
    int col = sl * 8;
    int i0 = noff[v], i1 = noff[v + 1];
    float acc[8] = {0.f, 0.f, 0.f, 0.f, 0.f, 0.f, 0.f, 0.f};
    int i = i0;
    for (; i + 3 < i1; i += 4) {
        int e0 = node_e[i + 0], e1 = node_e[i + 1], e2 = node_e[i + 2], e3 = node_e[i + 3];
        u16x8 r0 = *(const u16x8*)(Y + (size_t)e0 * 256 + col);
        u16x8 r1 = *(const u16x8*)(Y + (size_t)e1 * 256 + col);
        u16x8 r2 = *(const u16x8*)(Y + (size_t)e2 * 256 + col);
        u16x8 r3 = *(const u16x8*)(Y + (size_t)e3 * 256 + col);
#pragma unroll
        for (int q = 0; q < 8; ++q) {
            acc[q] += bf2f(r0[q]);
            acc[q] += bf2f(r1[q]);
            acc[q] += bf2f(r2[q]);
            acc[q] += bf2f(r3[q]);
        }
    }
    for (; i < i1; ++i) {
        int e = node_e[i];
        u16x8 r = *(const u16x8*)(Y + (size_t)e * 256 + col);
#pragma unroll
        for (int q = 0; q < 8; ++q) acc[q] += bf2f(r[q]);
    }
    float inv = (i1 > i0) ? 1.0f / (float)(i1 - i0) : 0.f;
    size_t base = (size_t)v * 256 + col;
    u16x8 xi = *(const u16x8*)(Xinit + base);
    u16x8 hv;
#pragma unroll
    for (int q = 0; q < 8; ++q) {
        float mm = acc[q] * inv;
        float oq = (mm > 0.f ? mm : expm1f(mm)) + bf2f(xi[q]);
        hv[q] = f2bf(oq);
    }
    *(u16x8*)(H + base) = hv;
}

// =============== hyperconv ===============
__global__ void yh_kernel(const u16* __restrict__ Xc,
                          const int* __restrict__ eoff, const int* __restrict__ edge_v,
                          const int* __restrict__ noff, u16* __restrict__ Yh, int M)
{
    int e = blockIdx.x * 16 + (threadIdx.x >> 4);
    if (e >= M) return;
    int sl = threadIdx.x & 15;
    int col = sl * 8;
    int j0 = eoff[e], j1 = eoff[e + 1];

    float dsum = 0.f;
    for (int j = j0 + sl; j < j1; j += 16) {
        int v = edge_v[j];
        dsum += (float)(noff[v + 1] - noff[v]);
    }
#pragma unroll
    for (int o = 8; o; o >>= 1) dsum += __shfl_xor(dsum, o);
    float De = dsum / ((float)(j1 - j0) + 1.0f);
    float deinv = De > 0.f ? rsqrtf(De) : 1.0f;

    float acc[8] = {0.f, 0.f, 0.f, 0.f, 0.f, 0.f, 0.f, 0.f};
    int j = j0;
    for (; j + 3 < j1; j += 4) {
        int v0 = edge_v[j + 0], v1 = edge_v[j + 1], v2 = edge_v[j + 2], v3 = edge_v[j + 3];
        u16x8 r0 = *(const u16x8*)(Xc + (size_t)v0 * 128 + col);
        u16x8 r1 = *(const u16x8*)(Xc + (size_t)v1 * 128 + col);
        u16x8 r2 = *(const u16x8*)(Xc + (size_t)v2 * 128 + col);
        u16x8 r3 = *(const u16x8*)(Xc + (size_t)v3 * 128 + col);
#pragma unroll
        for (int q = 0; q < 8; ++q) {
            acc[q] += bf2f(r0[q]);
            acc[q] += bf2f(r1[q]);
            acc[q] += bf2f(r2[q]);
            acc[q] += bf2f(r3[q]);
        }
    }
    for (; j < j1; ++j) {
        int v = edge_v[j];
        u16x8 r = *(const u16x8*)(Xc + (size_t)v * 128 + col);
#pragma unroll
        for (int q = 0; q < 8; ++q) acc[q] += bf2f(r[q]);
    }
    float sc = ((j1 > j0) ? 1.0f / (float)(j1 - j0) : 0.f) * deinv;
    u16x8 o8;
#pragma unroll
    for (int q = 0; q < 8; ++q) o8[q] = f2bf(acc[q] * sc);
    *(u16x8*)(Yh + (size_t)e * 128 + col) = o8;
}

__global__ void xo_final_kernel(const u16* __restrict__ Yh,
                                const int* __restrict__ noff, const int* __restrict__ node_e,
                                float* __restrict__ out, int N)
{
    int v = blockIdx.x * 16 + (threadIdx.x >> 4);
    if (v >= N) return;
    int sl = threadIdx.x & 15;
    int col = sl * 8;
    int i0 = noff[v], i1 = noff[v + 1];
    float acc[8] = {0.f, 0.f, 0.f, 0.f, 0.f, 0.f, 0.f, 0.f};
    int i = i0;
    for (; i + 3 < i1; i += 4) {
        int e0 = node_e[i + 0], e1 = node_e[i + 1], e2 = node_e[i + 2], e3 = node_e[i + 3];
        u16x8 r0 = *(const u16x8*)(Yh + (size_t)e0 * 128 + col);
        u16x8 r1 = *(const u16x8*)(Yh + (size_t)e1 * 128 + col);
        u16x8 r2 = *(const u16x8*)(Yh + (size_t)e2 * 128 + col);
        u16x8 r3 = *(const u16x8*)(Yh + (size_t)e3 * 128 + col);
#pragma unroll
        for (int q = 0; q < 8; ++q) {
            acc[q] += bf2f(r0[q]);
            acc[q] += bf2f(r1[q]);
            acc[q] += bf2f(r2[q]);
            acc[q] += bf2f(r3[q]);
        }
    }
    for (; i < i1; ++i) {
        int e = node_e[i];
        u16x8 r = *(const u16x8*)(Yh + (size_t)e * 128 + col);
#pragma unroll
        for (int q = 0; q < 8; ++q) acc[q] += bf2f(r[q]);
    }
    float sc = (i1 > i0) ? rsqrtf((float)(i1 - i0)) : 0.f;
    float4 oA, oB;
    oA.x = acc[0] * sc; oA.y = acc[1] * sc; oA.z = acc[2] * sc; oA.w = acc[3] * sc;
    oB.x = acc[4] * sc; oB.y = acc[5] * sc; oB.z = acc[6] * sc; oB.w = acc[7] * sc;
    float* d = out + (size_t)v * 128 + col;
    *(float4*)d = oA;
    *(float4*)(d + 4) = oB;
}

// =============== host-side ===============
static void gemm(const u16* A, int lda,
                 const u16* Bhi, const u16* Blo, int ldb,
                 const float* biasF, const float* biasB,
                 u16* CbA, u16* CbB, int M, int Nc, int ncSplit, int K,
                 hipStream_t stream)
{
    int nrb = (M + 127) / 128, ncb = Nc / 128;
    int nrb8 = ((nrb + 7) / 8) * 8;
    gemm_mfma_kernel<<<nrb8 * ncb, 256, 0, stream>>>(
        A, lda, Bhi, Blo, ldb, biasF, biasB, CbA, CbB, M, Nc, ncSplit, K, nrb, ncb);
}

static void run_layer(u16* A, int K,
                      const u16* WxvThi, const u16* WxvTlo,
                      const float* bx, const float* bv, const float* a,
                      const u16* WtThi, const u16* WtTlo, const float* bt,
                      u16* Ae,
                      u16* XinitB, u16* Xfeatb, u16* Ybufb, float* score,
                      const int* eoff, const int* edge_v,
                      const int* noff, const int* node_e,
                      int N, int M, hipStream_t stream)
{
    gemm(A, K, WxvThi, WxvTlo, K, bx, bv, XinitB, Xfeatb, N, 512, 256, K, stream);
    score_kernel<<<(N + 3) / 4, 256, 0, stream>>>(Xfeatb, a, score, N);
    v2e_fused_kernel<<<(M + 7) / 8, 256, 0, stream>>>(Xfeatb, score, eoff, edge_v, Ae, M);
    gemm(Ae, 320, WtThi, WtTlo, 320, nullptr, bt, nullptr, Ybufb, M, 256, 0, 320, stream);
    e2v_finish_kernel<<<(N + 7) / 8, 256, 0, stream>>>(Ybufb, noff, node_e, XinitB, A, N);
}

extern "C" void kernel_launch(void* const* d_in, const int* in_sizes, int n_in,
                              void* d_out, int out_size, void* d_ws, size_t ws_size,
                              hipStream_t stream)
{
    const float* X   = (const float*)d_in[0];
    const int*   V   = (const int*)d_in[1];
    const int*   E   = (const int*)d_in[2];
    const float* S   = (const float*)d_in[3];
    const float* Wx0 = (const float*)d_in[4];  const float* bx0 = (const float*)d_in[5];
    const float* Wv0 = (const float*)d_in[6];  const float* bv0 = (const float*)d_in[7];
    const float* a0  = (const float*)d_in[8];
    const float* Wt0 = (const float*)d_in[9];  const float* bt0 = (const float*)d_in[10];
    const float* Wx1 = (const float*)d_in[11]; const float* bx1 = (const float*)d_in[12];
    const float* Wv1 = (const float*)d_in[13]; const float* bv1 = (const float*)d_in[14];
    const float* a1  = (const float*)d_in[15];
    const float* Wt1 = (const float*)d_in[16]; const float* bt1 = (const float*)d_in[17];
    const float* Wf  = (const float*)d_in[18]; const float* bf  = (const float*)d_in[19];

    int N   = in_sizes[0] / 128;
    int NNZ = in_sizes[1];
    int M   = in_sizes[3] / 64;

    float* ws = (float*)d_ws;
    size_t off = 0;
    u16* XinitB = (u16*)(ws + off); off += (size_t)N * 128;  // [N,256] bf16; also Yh [M,128] bf16
    u16* XfeatR = (u16*)(ws + off); off += (size_t)N * 128;  // Xfeatb/Ybufb/Xcb
    u16* Xfeatb = XfeatR;
    u16* Ybufb  = XfeatR;
    u16* Abuf = (u16*)(ws + off); off += (size_t)N * 128;    // [N,256] bf16: X cast / h
    u16* Ae   = (u16*)(ws + off); off += (size_t)M * 160;    // [M,320] bf16 edge buffer
    u16* WxvT0h = (u16*)(ws + off); off += (size_t)(512 * 128) / 2;
    u16* WxvT0l = (u16*)(ws + off); off += (size_t)(512 * 128) / 2;
    u16* WtT0h  = (u16*)(ws + off); off += (size_t)(256 * 320) / 2;
    u16* WtT0l  = (u16*)(ws + off); off += (size_t)(256 * 320) / 2;
    u16* WxvT1h = (u16*)(ws + off); off += (size_t)(512 * 256) / 2;
    u16* WxvT1l = (u16*)(ws + off); off += (size_t)(512 * 256) / 2;
    u16* WtT1h  = (u16*)(ws + off); off += (size_t)(256 * 320) / 2;
    u16* WtT1l  = (u16*)(ws + off); off += (size_t)(256 * 320) / 2;
    u16* WfTh   = (u16*)(ws + off); off += (size_t)(128 * 256) / 2;
    u16* WfTl   = (u16*)(ws + off); off += (size_t)(128 * 256) / 2;
    float* score = ws + off; off += (size_t)N;
    int* eoff   = (int*)(ws + off); off += (size_t)(M + 1);
    int* ecnt   = (int*)(ws + off); off += (size_t)M;
    int* ecur   = (int*)(ws + off); off += (size_t)M;
    int* psumE  = (int*)(ws + off); off += 64;
    int* edge_v = (int*)(ws + off); off += (size_t)NNZ;
    int* noff   = (int*)(ws + off); off += (size_t)(N + 1);
    int* ncnt   = (int*)(ws + off); off += (size_t)N;
    int* ncur   = (int*)(ws + off); off += (size_t)N;
    int* psumN  = (int*)(ws + off); off += 64;
    int* node_e = (int*)(ws + off); off += (size_t)NNZ;

    // ---- CSR build ----
    hipMemsetAsync(ecnt, 0, (size_t)M * 4, stream);
    hipMemsetAsync(ncnt, 0, (size_t)N * 4, stream);
    count_kernel<<<((NNZ + 7) / 8 + 255) / 256, 256, 0, stream>>>(V, E, ecnt, ncnt, NNZ);
    int nbE = (M + 1023) / 1024, nbN = (N + 1023) / 1024;
    scan_part1<<<nbE, 256, 0, stream>>>(ecnt, eoff, psumE, M);
    scan_part1<<<nbN, 256, 0, stream>>>(ncnt, noff, psumN, N);
    scan_part2<<<nbE, 256, 0, stream>>>(ecnt, eoff, psumE, ecur, M);
    scan_part2<<<nbN, 256, 0, stream>>>(ncnt, noff, psumN, ncur, N);
    fill_kernel<<<((NNZ + 7) / 8 + 255) / 256, 256, 0, stream>>>(V, E, ecur, ncur, edge_v, node_e, NNZ);

    // ---- input casts (one launch) ----
    int n4x = N * 128 / 4, nS = M * 64;
    cast_inputs_kernel<<<(n4x + nS + 255) / 256, 256, 0, stream>>>(X, Abuf, n4x, S, Ae, nS);

    // ---- weight transpose+split (one launch, 7 jobs) ----
    WJobs jobs;
    jobs.j[0] = {Wx0, WxvT0h,                WxvT0l,                128, 8};
    jobs.j[1] = {Wv0, WxvT0h + 256 * 128,    WxvT0l + 256 * 128,    128, 8};
    jobs.j[2] = {Wt0, WtT0h,                 WtT0l,                 320, 8};
    jobs.j[3] = {Wx1, WxvT1h,                WxvT1l,                256, 8};
    jobs.j[4] = {Wv1, WxvT1h + 256 * 256,    WxvT1l + 256 * 256,    256, 8};
    jobs.j[5] = {Wt1, WtT1h,                 WtT1l,                 320, 8};
    jobs.j[6] = {Wf,  WfTh,                  WfTl,                  256, 7};
    dim3 wg((320 * 256 + 255) / 256, 7);
    wsplit_all_kernel<<<wg, 256, 0, stream>>>(jobs);

    // ---- layers (h bf16 lands back in Abuf) ----
    run_layer(Abuf, 128, WxvT0h, WxvT0l, bx0, bv0, a0,
              WtT0h, WtT0l, bt0, Ae, XinitB, Xfeatb, Ybufb, score,
              eoff, edge_v, noff, node_e, N, M, stream);
    run_layer(Abuf, 256, WxvT1h, WxvT1l, bx1, bv1, a1,
              WtT1h, WtT1l, bt1, Ae, XinitB, Xfeatb, Ybufb, score,
              eoff, edge_v, noff, node_e, N, M, stream);

    // ---- hyperconv (all-bf16 intermediates, fp32 final out) ----
    u16* Xcb = XfeatR;   // [N,128] bf16
    u16* Yhb = XinitB;   // [M,128] bf16
    gemm(Abuf, 256, WfTh, WfTl, 256, bf, nullptr, Xcb, nullptr, N, 128, 128, 256, stream);
    yh_kernel<<<(M + 15) / 16, 256, 0, stream>>>(Xcb, eoff, edge_v, noff, Yhb, M);
    xo_final_kernel<<<(N + 15) / 16, 256, 0, stream>>>(Yhb, noff, node_e, (float*)d_out, N);
}

// Round 15
// 536.993 us; speedup vs baseline: 1.5559x; 1.0183x over previous
//
#include <hip/hip_runtime.h>
#include <hip/hip_bf16.h>

typedef unsigned short u16;
typedef __attribute__((ext_vector_type(4))) u16 u16x4;
typedef __attribute__((ext_vector_type(8))) u16 u16x8;
typedef __attribute__((ext_vector_type(8))) __bf16 bf16x8;
typedef __attribute__((ext_vector_type(4))) float f32x4;

__device__ __forceinline__ u16 f2bf(float x) {
    unsigned u = __float_as_uint(x);
    unsigned r = u + 0x7FFF + ((u >> 16) & 1);
    return (u16)(r >> 16);
}
__device__ __forceinline__ float bf2f(u16 h) {
    return __uint_as_float(((unsigned)h) << 16);
}

__device__ __forceinline__ void gl_lds16(const void* g, void* l) {
    __builtin_amdgcn_global_load_lds(
        (const __attribute__((address_space(1))) void*)g,
        (__attribute__((address_space(3))) void*)l, 16, 0, 0);
}

// =============== bf16-activation x split-bf16-weight MFMA GEMM ===============
// Out[M,Nc] = A[M,K] @ B^T[Nc,K] + bias.  A: plain bf16.  B: (hi,lo) pair.
// acc = A*Bhi + A*Blo.  Output bf16, two regions split at ncSplit.
// Block tile 128x64 (per-wave 64x32, acc[4][2] -> 32 acc VGPRs for occupancy).
// 1-D grid, XCD-aware decode: col-blocks of a row-block share an XCD.
__global__ __launch_bounds__(256) void gemm_mfma_kernel(
    const u16* __restrict__ A, int lda,
    const u16* __restrict__ Bhi, const u16* __restrict__ Blo, int ldb,
    const float* __restrict__ biasF, const float* __restrict__ biasB,
    u16* __restrict__ CbA, u16* __restrict__ CbB,
    int M, int Nc, int ncSplit, int K, int nrb, int ncb)
{
    int g = blockIdx.x;
    int xcd = g & 7;
    int slot = g >> 3;
    int rbi = slot / ncb;
    int cb = slot - rbi * ncb;
    int rb = xcd + 8 * rbi;
    if (rb >= nrb) return;

    __shared__ __align__(16) u16 lds[10240];   // 16KB staging / 20KB epilogue
    u16* sA   = lds;          // 128 rows x 32k = 4096 u16
    u16* sBhi = lds + 4096;   // 64 rows x 32k = 2048 u16
    u16* sBlo = lds + 6144;

    int tid = threadIdx.x;
    int wave = tid >> 6, lane = tid & 63;
    int row0 = rb * 128, col0 = cb * 64;

    // A staging: 2 rounds of 64 rows; B staging: 1 round of 64 rows
    long gA[2];
    int sOffA[2];
#pragma unroll
    for (int r = 0; r < 2; ++r) {
        int trow = r * 64 + wave * 16 + (lane >> 2);
        int chunk = (lane & 3) ^ ((trow >> 2) & 3);
        int arow = min(row0 + trow, M - 1);
        gA[r] = (long)arow * lda + chunk * 8;
        sOffA[r] = (r * 64 + wave * 16) * 32;
    }
    int trowB = wave * 16 + (lane >> 2);
    int chunkB = (lane & 3) ^ ((trowB >> 2) & 3);
    long gB = (long)(col0 + trowB) * ldb + chunkB * 8;
    int sOffB = (wave * 16) * 32;

    int m16 = lane & 15, quad = lane >> 4;
    int offA[4], offB[2];
#pragma unroll
    for (int i = 0; i < 4; ++i) {
        int ra = (wave & 1) * 64 + i * 16 + m16;
        offA[i] = ra * 32 + ((quad ^ ((ra >> 2) & 3)) * 8);
    }
#pragma unroll
    for (int j = 0; j < 2; ++j) {
        int rbx = (wave >> 1) * 32 + j * 16 + m16;
        offB[j] = rbx * 32 + ((quad ^ ((rbx >> 2) & 3)) * 8);
    }

    f32x4 acc[4][2];
#pragma unroll
    for (int i = 0; i < 4; ++i)
#pragma unroll
        for (int j = 0; j < 2; ++j) {
            f32x4 z = {0.f, 0.f, 0.f, 0.f};
            acc[i][j] = z;
        }

    int nkb = K >> 5;
    for (int kb = 0; kb < nkb; ++kb) {
#pragma unroll
        for (int r = 0; r < 2; ++r) gl_lds16(A + gA[r], sA + sOffA[r]);
        gl_lds16(Bhi + gB, sBhi + sOffB);
        gl_lds16(Blo + gB, sBlo + sOffB);
        __syncthreads();
        bf16x8 av[4], bh[2], bl[2];
#pragma unroll
        for (int i = 0; i < 4; ++i) av[i] = *(const bf16x8*)(sA + offA[i]);
#pragma unroll
        for (int j = 0; j < 2; ++j) {
            bh[j] = *(const bf16x8*)(sBhi + offB[j]);
            bl[j] = *(const bf16x8*)(sBlo + offB[j]);
        }
#pragma unroll
        for (int i = 0; i < 4; ++i)
#pragma unroll
            for (int j = 0; j < 2; ++j) {
                acc[i][j] = __builtin_amdgcn_mfma_f32_16x16x32_bf16(av[i], bh[j], acc[i][j], 0, 0, 0);
                acc[i][j] = __builtin_amdgcn_mfma_f32_16x16x32_bf16(av[i], bl[j], acc[i][j], 0, 0, 0);
            }
        __syncthreads();
#pragma unroll
        for (int r = 0; r < 2; ++r) gA[r] += 32;
        gB += 32;
    }

    // ---- epilogue: per-wave LDS transpose (64 rows x 32 cols), 16B stores ----
    int rbase = (wave & 1) * 64, cbase = (wave >> 1) * 32;
    float bj[2];
#pragma unroll
    for (int j = 0; j < 2; ++j) {
        int col = col0 + cbase + j * 16 + m16;
        bj[j] = (col >= ncSplit) ? biasB[col - ncSplit] : biasF[col];
    }
    u16* wlds = lds + wave * 2560;   // 64 rows x 40 u16
    __syncthreads();
#pragma unroll
    for (int j = 0; j < 2; ++j)
#pragma unroll
        for (int i = 0; i < 4; ++i)
#pragma unroll
            for (int rr = 0; rr < 4; ++rr) {
                int lr = i * 16 + quad * 4 + rr;
                int lc = j * 16 + m16;
                int seg = (lc >> 3) ^ ((lr >> 2) & 3);
                wlds[lr * 40 + seg * 8 + (lc & 7)] = f2bf(acc[i][j][rr] + bj[j]);
            }
    __syncthreads();
    {
        int colbase = col0 + cbase;
        bool isB = (colbase >= ncSplit);
        u16* Cp = isB ? CbB : CbA;
        int stride = isB ? (Nc - ncSplit) : ncSplit;
        int cc = isB ? (colbase - ncSplit) : colbase;
        int row = row0 + rbase + lane;
        // note: rbase+lane spans 64 rows (lane 0..63)
        if (row < M) {
#pragma unroll
            for (int s = 0; s < 4; ++s) {
                int sseg = s ^ ((lane >> 2) & 3);
                u16x8 vv = *(const u16x8*)(wlds + lane * 40 + sseg * 8);
                *(u16x8*)(Cp + (size_t)row * stride + cc + s * 8) = vv;
            }
        }
    }
}

// =============== prep kernels (merged) ===============
struct WJob { const float* W; u16* Whi; u16* Wlo; int K; int ncShift; };
struct WJobs { WJob j[7]; };

__global__ void wsplit_all_kernel(WJobs jobs)
{
    WJob jb = jobs.j[blockIdx.y];
    int Nc = 1 << jb.ncShift;
    int idx = blockIdx.x * blockDim.x + threadIdx.x;
    if (idx >= jb.K * Nc) return;
    int k = idx >> jb.ncShift, n = idx & (Nc - 1);
    float x = jb.W[idx];
    u16 h = f2bf(x);
    u16 l = f2bf(x - bf2f(h));
    jb.Whi[(size_t)n * jb.K + k] = h;
    jb.Wlo[(size_t)n * jb.K + k] = l;
}

__global__ void cast_inputs_kernel(const float* __restrict__ X, u16* __restrict__ Abuf, int n4x,
                                   const float* __restrict__ S, u16* __restrict__ Ae, int nS)
{
    int id = blockIdx.x * blockDim.x + threadIdx.x;
    if (id < n4x) {
        float4 x = ((const float4*)X)[id];
        u16x4 h;
        h.x = f2bf(x.x); h.y = f2bf(x.y); h.z = f2bf(x.z); h.w = f2bf(x.w);
        *(u16x4*)(Abuf + (size_t)id * 4) = h;
    } else {
        int i = id - n4x;
        if (i < nS) {
            int e = i >> 6, c = i & 63;
            Ae[(size_t)e * 320 + 256 + c] = f2bf(S[i]);
        }
    }
}

// =============== CSR build (8-wide) ===============
__global__ void count_kernel(const int* __restrict__ V, const int* __restrict__ E,
                             int* ecnt, int* ncnt, int nnz)
{
    int k0 = (blockIdx.x * blockDim.x + threadIdx.x) * 8;
    if (k0 >= nnz) return;
    int kmax = min(nnz - k0, 8);
    int vv[8], ee[8];
    if (kmax == 8) {
        int4 a = *(const int4*)(V + k0), b = *(const int4*)(V + k0 + 4);
        int4 c = *(const int4*)(E + k0), d = *(const int4*)(E + k0 + 4);
        vv[0]=a.x; vv[1]=a.y; vv[2]=a.z; vv[3]=a.w; vv[4]=b.x; vv[5]=b.y; vv[6]=b.z; vv[7]=b.w;
        ee[0]=c.x; ee[1]=c.y; ee[2]=c.z; ee[3]=c.w; ee[4]=d.x; ee[5]=d.y; ee[6]=d.z; ee[7]=d.w;
    } else {
        for (int q = 0; q < kmax; ++q) { vv[q] = V[k0 + q]; ee[q] = E[k0 + q]; }
    }
    for (int q = 0; q < kmax; ++q) atomicAdd(&ecnt[ee[q]], 1);
    for (int q = 0; q < kmax; ++q) atomicAdd(&ncnt[vv[q]], 1);
}

__global__ __launch_bounds__(256) void scan_part1(const int* __restrict__ cnt,
                                                  int* __restrict__ off,
                                                  int* __restrict__ psum, int n)
{
    __shared__ int tsum[256];
    int base = blockIdx.x * 1024;
    int t = threadIdx.x;
    int idx0 = base + t * 4;
    int4 c = make_int4(0, 0, 0, 0);
    if (idx0 + 3 < n) c = *(const int4*)(cnt + idx0);
    else {
        if (idx0 + 0 < n) c.x = cnt[idx0 + 0];
        if (idx0 + 1 < n) c.y = cnt[idx0 + 1];
        if (idx0 + 2 < n) c.z = cnt[idx0 + 2];
        if (idx0 + 3 < n) c.w = cnt[idx0 + 3];
    }
    int s = c.x + c.y + c.z + c.w;
    tsum[t] = s;
    __syncthreads();
    for (int o = 1; o < 256; o <<= 1) {
        int v = (t >= o) ? tsum[t - o] : 0;
        __syncthreads();
        tsum[t] += v;
        __syncthreads();
    }
    int run = tsum[t] - s;
    run += c.x; if (idx0 + 0 < n) off[idx0 + 1] = run;
    run += c.y; if (idx0 + 1 < n) off[idx0 + 2] = run;
    run += c.z; if (idx0 + 2 < n) off[idx0 + 3] = run;
    run += c.w; if (idx0 + 3 < n) off[idx0 + 4] = run;
    if (t == 255) psum[blockIdx.x] = tsum[255];
}

__global__ __launch_bounds__(256) void scan_part2(const int* __restrict__ cnt,
                                                  int* __restrict__ off,
                                                  const int* __restrict__ psum,
                                                  int* __restrict__ cur, int n)
{
    __shared__ int bpref;
    int t = threadIdx.x;
    int b = blockIdx.x;
    if (t < 64) {
        int s = (t < b) ? psum[t] : 0;
#pragma unroll
        for (int o = 32; o; o >>= 1) s += __shfl_xor(s, o);
        if (t == 0) {
            bpref = s;
            if (b == 0) off[0] = 0;
        }
    }
    __syncthreads();
    int base = b * 1024 + t * 4;
#pragma unroll
    for (int q = 0; q < 4; ++q) {
        int i = base + q;
        if (i < n) {
            int inc = off[i + 1] + bpref;
            off[i + 1] = inc;
            cur[i] = inc - cnt[i];
        }
    }
}

__global__ void fill_kernel(const int* __restrict__ V, const int* __restrict__ E,
                            int* ecur, int* ncur, int* edge_v, int* node_e, int nnz)
{
    int k0 = (blockIdx.x * blockDim.x + threadIdx.x) * 8;
    if (k0 >= nnz) return;
    int kmax = min(nnz - k0, 8);
    int vv[8], ee[8], js[8], is_[8];
    if (kmax == 8) {
        int4 a = *(const int4*)(V + k0), b = *(const int4*)(V + k0 + 4);
        int4 c = *(const int4*)(E + k0), d = *(const int4*)(E + k0 + 4);
        vv[0]=a.x; vv[1]=a.y; vv[2]=a.z; vv[3]=a.w; vv[4]=b.x; vv[5]=b.y; vv[6]=b.z; vv[7]=b.w;
        ee[0]=c.x; ee[1]=c.y; ee[2]=c.z; ee[3]=c.w; ee[4]=d.x; ee[5]=d.y; ee[6]=d.z; ee[7]=d.w;
    } else {
        for (int q = 0; q < kmax; ++q) { vv[q] = V[k0 + q]; ee[q] = E[k0 + q]; }
    }
    for (int q = 0; q < kmax; ++q) js[q] = atomicAdd(&ecur[ee[q]], 1);
    for (int q = 0; q < kmax; ++q) is_[q] = atomicAdd(&ncur[vv[q]], 1);
    for (int q = 0; q < kmax; ++q) edge_v[js[q]] = vv[q];
    for (int q = 0; q < kmax; ++q) node_e[is_[q]] = ee[q];
}

// =============== graph kernels ===============
__global__ void score_kernel(const u16* __restrict__ Xf, const float* __restrict__ a,
                             float* __restrict__ score, int N)
{
    int row = blockIdx.x * (blockDim.x >> 6) + (threadIdx.x >> 6);
    int lane = threadIdx.x & 63;
    if (row >= N) return;
    u16x4 x = *(const u16x4*)(Xf + (size_t)row * 256 + lane * 4);
    float4 av = *(const float4*)(a + lane * 4);
    float p = bf2f(x.x) * av.x + bf2f(x.y) * av.y + bf2f(x.z) * av.z + bf2f(x.w) * av.w;
#pragma unroll
    for (int off = 32; off; off >>= 1) p += __shfl_down(p, off);
    if (lane == 0) score[row] = p;
}

__device__ __forceinline__ float lrelu(float s) { return s >= 0.f ? s : 0.2f * s; }

__global__ void v2e_fused_kernel(const u16* __restrict__ Xf,
                                 const float* __restrict__ score,
                                 const int* __restrict__ eoff,
                                 const int* __restrict__ edge_v,
                                 u16* __restrict__ Ae, int M)
{
    int e = blockIdx.x * 8 + (threadIdx.x >> 5);
    if (e >= M) return;
    int sl = threadIdx.x & 31;
    int j0 = eoff[e], j1 = eoff[e + 1];
    float m = -INFINITY;
    for (int j = j0 + sl; j < j1; j += 32) m = fmaxf(m, lrelu(score[edge_v[j]]));
#pragma unroll
    for (int o = 16; o; o >>= 1) m = fmaxf(m, __shfl_xor(m, o));
    float sum = 0.f;
    for (int j = j0 + sl; j < j1; j += 32) sum += expf(lrelu(score[edge_v[j]]) - m);
#pragma unroll
    for (int o = 16; o; o >>= 1) sum += __shfl_xor(sum, o);
    float inv = (j1 > j0) ? 1.0f / sum : 0.f;

    float acc[8] = {0.f, 0.f, 0.f, 0.f, 0.f, 0.f, 0.f, 0.f};
    int col = sl * 8;
    int j = j0;
    for (; j + 3 < j1; j += 4) {
        int v0 = edge_v[j + 0], v1 = edge_v[j + 1], v2 = edge_v[j + 2], v3 = edge_v[j + 3];
        float s0 = score[v0], s1 = score[v1], s2 = score[v2], s3 = score[v3];
        u16x8 r0 = *(const u16x8*)(Xf + (size_t)v0 * 256 + col);
        u16x8 r1 = *(const u16x8*)(Xf + (size_t)v1 * 256 + col);
        u16x8 r2 = *(const u16x8*)(Xf + (size_t)v2 * 256 + col);
        u16x8 r3 = *(const u16x8*)(Xf + (size_t)v3 * 256 + col);
        float w0 = expf(lrelu(s0) - m) * inv;
        float w1 = expf(lrelu(s1) - m) * inv;
        float w2 = expf(lrelu(s2) - m) * inv;
        float w3 = expf(lrelu(s3) - m) * inv;
#pragma unroll
        for (int q = 0; q < 8; ++q) {
            acc[q] += bf2f(r0[q]) * w0;
            acc[q] += bf2f(r1[q]) * w1;
            acc[q] += bf2f(r2[q]) * w2;
            acc[q] += bf2f(r3[q]) * w3;
        }
    }
    for (; j < j1; ++j) {
        int v = edge_v[j];
        float ww = expf(lrelu(score[v]) - m) * inv;
        u16x8 r = *(const u16x8*)(Xf + (size_t)v * 256 + col);
#pragma unroll
        for (int q = 0; q < 8; ++q) acc[q] += bf2f(r[q]) * ww;
    }
    u16x8 hv;
#pragma unroll
    for (int q = 0; q < 8; ++q) {
        float vq = acc[q];
        vq = vq > 0.f ? vq : expm1f(vq);
        hv[q] = f2bf(vq);
    }
    *(u16x8*)(Ae + (size_t)e * 320 + col) = hv;
}

__global__ void e2v_finish_kernel(const u16* __restrict__ Y,
                                  const int* __restrict__ noff,
                                  const int* __restrict__ node_e,
                                  const u16* __restrict__ Xinit,
                                  u16* __restrict__ H, int N)
{
    int v = blockIdx.x * 8 + (threadIdx.x >> 5);
    if (v >= N) return;
    int sl = threadIdx.x & 31;
    int col = sl * 8;
    int i0 = noff[v], i1 = noff[v + 1];
    float acc[8] = {0.f, 0.f, 0.f, 0.f, 0.f, 0.f, 0.f, 0.f};
    int i = i0;
    for (; i + 3 < i1; i += 4) {
        int e0 = node_e[i + 0], e1 = node_e[i + 1], e2 = node_e[i + 2], e3 = node_e[i + 3];
        u16x8 r0 = *(const u16x8*)(Y + (size_t)e0 * 256 + col);
        u16x8 r1 = *(const u16x8*)(Y + (size_t)e1 * 256 + col);
        u16x8 r2 = *(const u16x8*)(Y + (size_t)e2 * 256 + col);
        u16x8 r3 = *(const u16x8*)(Y + (size_t)e3 * 256 + col);
#pragma unroll
        for (int q = 0; q < 8; ++q) {
            acc[q] += bf2f(r0[q]);
            acc[q] += bf2f(r1[q]);
            acc[q] += bf2f(r2[q]);
            acc[q] += bf2f(r3[q]);
        }
    }
    for (; i < i1; ++i) {
        int e = node_e[i];
        u16x8 r = *(const u16x8*)(Y + (size_t)e * 256 + col);
#pragma unroll
        for (int q = 0; q < 8; ++q) acc[q] += bf2f(r[q]);
    }
    float inv = (i1 > i0) ? 1.0f / (float)(i1 - i0) : 0.f;
    size_t base = (size_t)v * 256 + col;
    u16x8 xi = *(const u16x8*)(Xinit + base);
    u16x8 hv;
#pragma unroll
    for (int q = 0; q < 8; ++q) {
        float mm = acc[q] * inv;
        float oq = (mm > 0.f ? mm : expm1f(mm)) + bf2f(xi[q]);
        hv[q] = f2bf(oq);
    }
    *(u16x8*)(H + base) = hv;
}

// =============== hyperconv ===============
__global__ void yh_kernel(const u16* __restrict__ Xc,
                          const int* __restrict__ eoff, const int* __restrict__ edge_v,
                          const int* __restrict__ noff, u16* __restrict__ Yh, int M)
{
    int e = blockIdx.x * 16 + (threadIdx.x >> 4);
    if (e >= M) return;
    int sl = threadIdx.x & 15;
    int col = sl * 8;
    int j0 = eoff[e], j1 = eoff[e + 1];

    float dsum = 0.f;
    for (int j = j0 + sl; j < j1; j += 16) {
        int v = edge_v[j];
        dsum += (float)(noff[v + 1] - noff[v]);
    }
#pragma unroll
    for (int o = 8; o; o >>= 1) dsum += __shfl_xor(dsum, o);
    float De = dsum / ((float)(j1 - j0) + 1.0f);
    float deinv = De > 0.f ? rsqrtf(De) : 1.0f;

    float acc[8] = {0.f, 0.f, 0.f, 0.f, 0.f, 0.f, 0.f, 0.f};
    int j = j0;
    for (; j + 3 < j1; j += 4) {
        int v0 = edge_v[j + 0], v1 = edge_v[j + 1], v2 = edge_v[j + 2], v3 = edge_v[j + 3];
        u16x8 r0 = *(const u16x8*)(Xc + (size_t)v0 * 128 + col);
        u16x8 r1 = *(const u16x8*)(Xc + (size_t)v1 * 128 + col);
        u16x8 r2 = *(const u16x8*)(Xc + (size_t)v2 * 128 + col);
        u16x8 r3 = *(const u16x8*)(Xc + (size_t)v3 * 128 + col);
#pragma unroll
        for (int q = 0; q < 8; ++q) {
            acc[q] += bf2f(r0[q]);
            acc[q] += bf2f(r1[q]);
            acc[q] += bf2f(r2[q]);
            acc[q] += bf2f(r3[q]);
        }
    }
    for (; j < j1; ++j) {
        int v = edge_v[j];
        u16x8 r = *(const u16x8*)(Xc + (size_t)v * 128 + col);
#pragma unroll
        for (int q = 0; q < 8; ++q) acc[q] += bf2f(r[q]);
    }
    float sc = ((j1 > j0) ? 1.0f / (float)(j1 - j0) : 0.f) * deinv;
    u16x8 o8;
#pragma unroll
    for (int q = 0; q < 8; ++q) o8[q] = f2bf(acc[q] * sc);
    *(u16x8*)(Yh + (size_t)e * 128 + col) = o8;
}

__global__ void xo_final_kernel(const u16* __restrict__ Yh,
                                const int* __restrict__ noff, const int* __restrict__ node_e,
                                float* __restrict__ out, int N)
{
    int v = blockIdx.x * 16 + (threadIdx.x >> 4);
    if (v >= N) return;
    int sl = threadIdx.x & 15;
    int col = sl * 8;
    int i0 = noff[v], i1 = noff[v + 1];
    float acc[8] = {0.f, 0.f, 0.f, 0.f, 0.f, 0.f, 0.f, 0.f};
    int i = i0;
    for (; i + 3 < i1; i += 4) {
        int e0 = node_e[i + 0], e1 = node_e[i + 1], e2 = node_e[i + 2], e3 = node_e[i + 3];
        u16x8 r0 = *(const u16x8*)(Yh + (size_t)e0 * 128 + col);
        u16x8 r1 = *(const u16x8*)(Yh + (size_t)e1 * 128 + col);
        u16x8 r2 = *(const u16x8*)(Yh + (size_t)e2 * 128 + col);
        u16x8 r3 = *(const u16x8*)(Yh + (size_t)e3 * 128 + col);
#pragma unroll
        for (int q = 0; q < 8; ++q) {
            acc[q] += bf2f(r0[q]);
            acc[q] += bf2f(r1[q]);
            acc[q] += bf2f(r2[q]);
            acc[q] += bf2f(r3[q]);
        }
    }
    for (; i < i1; ++i) {
        int e = node_e[i];
        u16x8 r = *(const u16x8*)(Yh + (size_t)e * 128 + col);
#pragma unroll
        for (int q = 0; q < 8; ++q) acc[q] += bf2f(r[q]);
    }
    float sc = (i1 > i0) ? rsqrtf((float)(i1 - i0)) : 0.f;
    float4 oA, oB;
    oA.x = acc[0] * sc; oA.y = acc[1] * sc; oA.z = acc[2] * sc; oA.w = acc[3] * sc;
    oB.x = acc[4] * sc; oB.y = acc[5] * sc; oB.z = acc[6] * sc; oB.w = acc[7] * sc;
    float* d = out + (size_t)v * 128 + col;
    *(float4*)d = oA;
    *(float4*)(d + 4) = oB;
}

// =============== host-side ===============
static void gemm(const u16* A, int lda,
                 const u16* Bhi, const u16* Blo, int ldb,
                 const float* biasF, const float* biasB,
                 u16* CbA, u16* CbB, int M, int Nc, int ncSplit, int K,
                 hipStream_t stream)
{
    int nrb = (M + 127) / 128, ncb = Nc / 64;
    int nrb8 = ((nrb + 7) / 8) * 8;
    gemm_mfma_kernel<<<nrb8 * ncb, 256, 0, stream>>>(
        A, lda, Bhi, Blo, ldb, biasF, biasB, CbA, CbB, M, Nc, ncSplit, K, nrb, ncb);
}

static void run_layer(u16* A, int K,
                      const u16* WxvThi, const u16* WxvTlo,
                      const float* bx, const float* bv, const float* a,
                      const u16* WtThi, const u16* WtTlo, const float* bt,
                      u16* Ae,
                      u16* XinitB, u16* Xfeatb, u16* Ybufb, float* score,
                      const int* eoff, const int* edge_v,
                      const int* noff, const int* node_e,
                      int N, int M, hipStream_t stream)
{
    gemm(A, K, WxvThi, WxvTlo, K, bx, bv, XinitB, Xfeatb, N, 512, 256, K, stream);
    score_kernel<<<(N + 3) / 4, 256, 0, stream>>>(Xfeatb, a, score, N);
    v2e_fused_kernel<<<(M + 7) / 8, 256, 0, stream>>>(Xfeatb, score, eoff, edge_v, Ae, M);
    gemm(Ae, 320, WtThi, WtTlo, 320, nullptr, bt, nullptr, Ybufb, M, 256, 0, 320, stream);
    e2v_finish_kernel<<<(N + 7) / 8, 256, 0, stream>>>(Ybufb, noff, node_e, XinitB, A, N);
}

extern "C" void kernel_launch(void* const* d_in, const int* in_sizes, int n_in,
                              void* d_out, int out_size, void* d_ws, size_t ws_size,
                              hipStream_t stream)
{
    const float* X   = (const float*)d_in[0];
    const int*   V   = (const int*)d_in[1];
    const int*   E   = (const int*)d_in[2];
    const float* S   = (const float*)d_in[3];
    const float* Wx0 = (const float*)d_in[4];  const float* bx0 = (const float*)d_in[5];
    const float* Wv0 = (const float*)d_in[6];  const float* bv0 = (const float*)d_in[7];
    const float* a0  = (const float*)d_in[8];
    const float* Wt0 = (const float*)d_in[9];  const float* bt0 = (const float*)d_in[10];
    const float* Wx1 = (const float*)d_in[11]; const float* bx1 = (const float*)d_in[12];
    const float* Wv1 = (const float*)d_in[13]; const float* bv1 = (const float*)d_in[14];
    const float* a1  = (const float*)d_in[15];
    const float* Wt1 = (const float*)d_in[16]; const float* bt1 = (const float*)d_in[17];
    const float* Wf  = (const float*)d_in[18]; const float* bf  = (const float*)d_in[19];

    int N   = in_sizes[0] / 128;
    int NNZ = in_sizes[1];
    int M   = in_sizes[3] / 64;

    float* ws = (float*)d_ws;
    size_t off = 0;
    u16* XinitB = (u16*)(ws + off); off += (size_t)N * 128;  // [N,256] bf16; also Yh [M,128] bf16
    u16* XfeatR = (u16*)(ws + off); off += (size_t)N * 128;  // Xfeatb/Ybufb/Xcb
    u16* Xfeatb = XfeatR;
    u16* Ybufb  = XfeatR;
    u16* Abuf = (u16*)(ws + off); off += (size_t)N * 128;    // [N,256] bf16: X cast / h
    u16* Ae   = (u16*)(ws + off); off += (size_t)M * 160;    // [M,320] bf16 edge buffer
    u16* WxvT0h = (u16*)(ws + off); off += (size_t)(512 * 128) / 2;
    u16* WxvT0l = (u16*)(ws + off); off += (size_t)(512 * 128) / 2;
    u16* WtT0h  = (u16*)(ws + off); off += (size_t)(256 * 320) / 2;
    u16* WtT0l  = (u16*)(ws + off); off += (size_t)(256 * 320) / 2;
    u16* WxvT1h = (u16*)(ws + off); off += (size_t)(512 * 256) / 2;
    u16* WxvT1l = (u16*)(ws + off); off += (size_t)(512 * 256) / 2;
    u16* WtT1h  = (u16*)(ws + off); off += (size_t)(256 * 320) / 2;
    u16* WtT1l  = (u16*)(ws + off); off += (size_t)(256 * 320) / 2;
    u16* WfTh   = (u16*)(ws + off); off += (size_t)(128 * 256) / 2;
    u16* WfTl   = (u16*)(ws + off); off += (size_t)(128 * 256) / 2;
    float* score = ws + off; off += (size_t)N;
    int* eoff   = (int*)(ws + off); off += (size_t)(M + 1);
    int* ecnt   = (int*)(ws + off); off += (size_t)M;
    int* ecur   = (int*)(ws + off); off += (size_t)M;
    int* psumE  = (int*)(ws + off); off += 64;
    int* edge_v = (int*)(ws + off); off += (size_t)NNZ;
    int* noff   = (int*)(ws + off); off += (size_t)(N + 1);
    int* ncnt   = (int*)(ws + off); off += (size_t)N;
    int* ncur   = (int*)(ws + off); off += (size_t)N;
    int* psumN  = (int*)(ws + off); off += 64;
    int* node_e = (int*)(ws + off); off += (size_t)NNZ;

    // ---- CSR build ----
    hipMemsetAsync(ecnt, 0, (size_t)M * 4, stream);
    hipMemsetAsync(ncnt, 0, (size_t)N * 4, stream);
    count_kernel<<<((NNZ + 7) / 8 + 255) / 256, 256, 0, stream>>>(V, E, ecnt, ncnt, NNZ);
    int nbE = (M + 1023) / 1024, nbN = (N + 1023) / 1024;
    scan_part1<<<nbE, 256, 0, stream>>>(ecnt, eoff, psumE, M);
    scan_part1<<<nbN, 256, 0, stream>>>(ncnt, noff, psumN, N);
    scan_part2<<<nbE, 256, 0, stream>>>(ecnt, eoff, psumE, ecur, M);
    scan_part2<<<nbN, 256, 0, stream>>>(ncnt, noff, psumN, ncur, N);
    fill_kernel<<<((NNZ + 7) / 8 + 255) / 256, 256, 0, stream>>>(V, E, ecur, ncur, edge_v, node_e, NNZ);

    // ---- input casts (one launch) ----
    int n4x = N * 128 / 4, nS = M * 64;
    cast_inputs_kernel<<<(n4x + nS + 255) / 256, 256, 0, stream>>>(X, Abuf, n4x, S, Ae, nS);

    // ---- weight transpose+split (one launch, 7 jobs) ----
    WJobs jobs;
    jobs.j[0] = {Wx0, WxvT0h,                WxvT0l,                128, 8};
    jobs.j[1] = {Wv0, WxvT0h + 256 * 128,    WxvT0l + 256 * 128,    128, 8};
    jobs.j[2] = {Wt0, WtT0h,                 WtT0l,                 320, 8};
    jobs.j[3] = {Wx1, WxvT1h,                WxvT1l,                256, 8};
    jobs.j[4] = {Wv1, WxvT1h + 256 * 256,    WxvT1l + 256 * 256,    256, 8};
    jobs.j[5] = {Wt1, WtT1h,                 WtT1l,                 320, 8};
    jobs.j[6] = {Wf,  WfTh,                  WfTl,                  256, 7};
    dim3 wg((320 * 256 + 255) / 256, 7);
    wsplit_all_kernel<<<wg, 256, 0, stream>>>(jobs);

    // ---- layers (h bf16 lands back in Abuf) ----
    run_layer(Abuf, 128, WxvT0h, WxvT0l, bx0, bv0, a0,
              WtT0h, WtT0l, bt0, Ae, XinitB, Xfeatb, Ybufb, score,
              eoff, edge_v, noff, node_e, N, M, stream);
    run_layer(Abuf, 256, WxvT1h, WxvT1l, bx1, bv1, a1,
              WtT1h, WtT1l, bt1, Ae, XinitB, Xfeatb, Ybufb, score,
              eoff, edge_v, noff, node_e, N, M, stream);

    // ---- hyperconv (all-bf16 intermediates, fp32 final out) ----
    u16* Xcb = XfeatR;   // [N,128] bf16
    u16* Yhb = XinitB;   // [M,128] bf16
    gemm(Abuf, 256, WfTh, WfTl, 256, bf, nullptr, Xcb, nullptr, N, 128, 128, 256, stream);
    yh_kernel<<<(M + 15) / 16, 256, 0, stream>>>(Xcb, eoff, edge_v, noff, Yhb, M);
    xo_final_kernel<<<(N + 15) / 16, 256, 0, stream>>>(Yhb, noff, node_e, (float*)d_out, N);
}

// Round 16
// 524.044 us; speedup vs baseline: 1.5943x; 1.0247x over previous
//
#include <hip/hip_runtime.h>
#include <hip/hip_bf16.h>

typedef unsigned short u16;
typedef __attribute__((ext_vector_type(4))) u16 u16x4;
typedef __attribute__((ext_vector_type(8))) u16 u16x8;
typedef __attribute__((ext_vector_type(8))) __bf16 bf16x8;
typedef __attribute__((ext_vector_type(4))) float f32x4;

__device__ __forceinline__ u16 f2bf(float x) {
    unsigned u = __float_as_uint(x);
    unsigned r = u + 0x7FFF + ((u >> 16) & 1);
    return (u16)(r >> 16);
}
__device__ __forceinline__ float bf2f(u16 h) {
    return __uint_as_float(((unsigned)h) << 16);
}

__device__ __forceinline__ void gl_lds16(const void* g, void* l) {
    __builtin_amdgcn_global_load_lds(
        (const __attribute__((address_space(1))) void*)g,
        (__attribute__((address_space(3))) void*)l, 16, 0, 0);
}

// =============== bf16-activation x split-bf16-weight MFMA GEMM ===============
// Out[M,Nc] = A[M,K] @ B^T[Nc,K] + bias.  A: plain bf16.  B: (hi,lo) pair.
// Block tile 128x64; BK=64 (two 32-K chunks per barrier pair).
// 1-D grid, XCD-aware decode. Epilogue: per-wave LDS transpose, 16B stores.
__global__ __launch_bounds__(256) void gemm_mfma_kernel(
    const u16* __restrict__ A, int lda,
    const u16* __restrict__ Bhi, const u16* __restrict__ Blo, int ldb,
    const float* __restrict__ biasF, const float* __restrict__ biasB,
    u16* __restrict__ CbA, u16* __restrict__ CbB,
    int M, int Nc, int ncSplit, int K, int nrb, int ncb)
{
    int g = blockIdx.x;
    int xcd = g & 7;
    int slot = g >> 3;
    int rbi = slot / ncb;
    int cb = slot - rbi * ncb;
    int rb = xcd + 8 * rbi;
    if (rb >= nrb) return;

    __shared__ __align__(16) u16 lds[16384];   // 32 KB: A 2x4096, Bhi 2x2048, Blo 2x2048
    u16* sA0   = lds;
    u16* sA1   = lds + 4096;
    u16* sBhi0 = lds + 8192;
    u16* sBhi1 = lds + 10240;
    u16* sBlo0 = lds + 12288;
    u16* sBlo1 = lds + 14336;

    int tid = threadIdx.x;
    int wave = tid >> 6, lane = tid & 63;
    int row0 = rb * 128, col0 = cb * 64;

    long gA[2];
    int sOffA[2];
#pragma unroll
    for (int r = 0; r < 2; ++r) {
        int trow = r * 64 + wave * 16 + (lane >> 2);
        int chunk = (lane & 3) ^ ((trow >> 2) & 3);
        int arow = min(row0 + trow, M - 1);
        gA[r] = (long)arow * lda + chunk * 8;
        sOffA[r] = (r * 64 + wave * 16) * 32;
    }
    int trowB = wave * 16 + (lane >> 2);
    int chunkB = (lane & 3) ^ ((trowB >> 2) & 3);
    long gB = (long)(col0 + trowB) * ldb + chunkB * 8;
    int sOffB = (wave * 16) * 32;

    int m16 = lane & 15, quad = lane >> 4;
    int offA[4], offB[2];
#pragma unroll
    for (int i = 0; i < 4; ++i) {
        int ra = (wave & 1) * 64 + i * 16 + m16;
        offA[i] = ra * 32 + ((quad ^ ((ra >> 2) & 3)) * 8);
    }
#pragma unroll
    for (int j = 0; j < 2; ++j) {
        int rbx = (wave >> 1) * 32 + j * 16 + m16;
        offB[j] = rbx * 32 + ((quad ^ ((rbx >> 2) & 3)) * 8);
    }

    f32x4 acc[4][2];
#pragma unroll
    for (int i = 0; i < 4; ++i)
#pragma unroll
        for (int j = 0; j < 2; ++j) {
            f32x4 z = {0.f, 0.f, 0.f, 0.f};
            acc[i][j] = z;
        }

    int nkb = K >> 6;   // BK = 64
    for (int kb = 0; kb < nkb; ++kb) {
        // stage both 32-K chunks
#pragma unroll
        for (int r = 0; r < 2; ++r) {
            gl_lds16(A + gA[r], sA0 + sOffA[r]);
            gl_lds16(A + gA[r] + 32, sA1 + sOffA[r]);
        }
        gl_lds16(Bhi + gB, sBhi0 + sOffB);
        gl_lds16(Bhi + gB + 32, sBhi1 + sOffB);
        gl_lds16(Blo + gB, sBlo0 + sOffB);
        gl_lds16(Blo + gB + 32, sBlo1 + sOffB);
        __syncthreads();
        // chunk 0
        {
            bf16x8 av[4], bh[2], bl[2];
#pragma unroll
            for (int i = 0; i < 4; ++i) av[i] = *(const bf16x8*)(sA0 + offA[i]);
#pragma unroll
            for (int j = 0; j < 2; ++j) {
                bh[j] = *(const bf16x8*)(sBhi0 + offB[j]);
                bl[j] = *(const bf16x8*)(sBlo0 + offB[j]);
            }
#pragma unroll
            for (int i = 0; i < 4; ++i)
#pragma unroll
                for (int j = 0; j < 2; ++j) {
                    acc[i][j] = __builtin_amdgcn_mfma_f32_16x16x32_bf16(av[i], bh[j], acc[i][j], 0, 0, 0);
                    acc[i][j] = __builtin_amdgcn_mfma_f32_16x16x32_bf16(av[i], bl[j], acc[i][j], 0, 0, 0);
                }
        }
        // chunk 1
        {
            bf16x8 av[4], bh[2], bl[2];
#pragma unroll
            for (int i = 0; i < 4; ++i) av[i] = *(const bf16x8*)(sA1 + offA[i]);
#pragma unroll
            for (int j = 0; j < 2; ++j) {
                bh[j] = *(const bf16x8*)(sBhi1 + offB[j]);
                bl[j] = *(const bf16x8*)(sBlo1 + offB[j]);
            }
#pragma unroll
            for (int i = 0; i < 4; ++i)
#pragma unroll
                for (int j = 0; j < 2; ++j) {
                    acc[i][j] = __builtin_amdgcn_mfma_f32_16x16x32_bf16(av[i], bh[j], acc[i][j], 0, 0, 0);
                    acc[i][j] = __builtin_amdgcn_mfma_f32_16x16x32_bf16(av[i], bl[j], acc[i][j], 0, 0, 0);
                }
        }
        __syncthreads();
#pragma unroll
        for (int r = 0; r < 2; ++r) gA[r] += 64;
        gB += 64;
    }

    // ---- epilogue: per-wave LDS transpose (64 rows x 32 cols), 16B stores ----
    int rbase = (wave & 1) * 64, cbase = (wave >> 1) * 32;
    float bj[2];
#pragma unroll
    for (int j = 0; j < 2; ++j) {
        int col = col0 + cbase + j * 16 + m16;
        bj[j] = (col >= ncSplit) ? biasB[col - ncSplit] : biasF[col];
    }
    u16* wlds = lds + wave * 2560;   // 64 rows x 40 u16
    __syncthreads();
#pragma unroll
    for (int j = 0; j < 2; ++j)
#pragma unroll
        for (int i = 0; i < 4; ++i)
#pragma unroll
            for (int rr = 0; rr < 4; ++rr) {
                int lr = i * 16 + quad * 4 + rr;
                int lc = j * 16 + m16;
                int seg = (lc >> 3) ^ ((lr >> 2) & 3);
                wlds[lr * 40 + seg * 8 + (lc & 7)] = f2bf(acc[i][j][rr] + bj[j]);
            }
    __syncthreads();
    {
        int colbase = col0 + cbase;
        bool isB = (colbase >= ncSplit);
        u16* Cp = isB ? CbB : CbA;
        int stride = isB ? (Nc - ncSplit) : ncSplit;
        int cc = isB ? (colbase - ncSplit) : colbase;
        int row = row0 + rbase + lane;
        if (row < M) {
#pragma unroll
            for (int s = 0; s < 4; ++s) {
                int sseg = s ^ ((lane >> 2) & 3);
                u16x8 vv = *(const u16x8*)(wlds + lane * 40 + sseg * 8);
                *(u16x8*)(Cp + (size_t)row * stride + cc + s * 8) = vv;
            }
        }
    }
}

// =============== prep kernels (merged) ===============
struct WJob { const float* W; u16* Whi; u16* Wlo; int K; int ncShift; };
struct WJobs { WJob j[7]; };

__global__ void wsplit_all_kernel(WJobs jobs)
{
    WJob jb = jobs.j[blockIdx.y];
    int Nc = 1 << jb.ncShift;
    int idx = blockIdx.x * blockDim.x + threadIdx.x;
    if (idx >= jb.K * Nc) return;
    int k = idx >> jb.ncShift, n = idx & (Nc - 1);
    float x = jb.W[idx];
    u16 h = f2bf(x);
    u16 l = f2bf(x - bf2f(h));
    jb.Whi[(size_t)n * jb.K + k] = h;
    jb.Wlo[(size_t)n * jb.K + k] = l;
}

__global__ void cast_inputs_kernel(const float* __restrict__ X, u16* __restrict__ Abuf, int n4x,
                                   const float* __restrict__ S, u16* __restrict__ Ae, int nS)
{
    int id = blockIdx.x * blockDim.x + threadIdx.x;
    if (id < n4x) {
        float4 x = ((const float4*)X)[id];
        u16x4 h;
        h.x = f2bf(x.x); h.y = f2bf(x.y); h.z = f2bf(x.z); h.w = f2bf(x.w);
        *(u16x4*)(Abuf + (size_t)id * 4) = h;
    } else {
        int i = id - n4x;
        if (i < nS) {
            int e = i >> 6, c = i & 63;
            Ae[(size_t)e * 320 + 256 + c] = f2bf(S[i]);
        }
    }
}

// =============== CSR build (8-wide) ===============
__global__ void count_kernel(const int* __restrict__ V, const int* __restrict__ E,
                             int* ecnt, int* ncnt, int nnz)
{
    int k0 = (blockIdx.x * blockDim.x + threadIdx.x) * 8;
    if (k0 >= nnz) return;
    int kmax = min(nnz - k0, 8);
    int vv[8], ee[8];
    if (kmax == 8) {
        int4 a = *(const int4*)(V + k0), b = *(const int4*)(V + k0 + 4);
        int4 c = *(const int4*)(E + k0), d = *(const int4*)(E + k0 + 4);
        vv[0]=a.x; vv[1]=a.y; vv[2]=a.z; vv[3]=a.w; vv[4]=b.x; vv[5]=b.y; vv[6]=b.z; vv[7]=b.w;
        ee[0]=c.x; ee[1]=c.y; ee[2]=c.z; ee[3]=c.w; ee[4]=d.x; ee[5]=d.y; ee[6]=d.z; ee[7]=d.w;
    } else {
        for (int q = 0; q < kmax; ++q) { vv[q] = V[k0 + q]; ee[q] = E[k0 + q]; }
    }
    for (int q = 0; q < kmax; ++q) atomicAdd(&ecnt[ee[q]], 1);
    for (int q = 0; q < kmax; ++q) atomicAdd(&ncnt[vv[q]], 1);
}

__global__ __launch_bounds__(256) void scan_part1(const int* __restrict__ cnt,
                                                  int* __restrict__ off,
                                                  int* __restrict__ psum, int n)
{
    __shared__ int tsum[256];
    int base = blockIdx.x * 1024;
    int t = threadIdx.x;
    int idx0 = base + t * 4;
    int4 c = make_int4(0, 0, 0, 0);
    if (idx0 + 3 < n) c = *(const int4*)(cnt + idx0);
    else {
        if (idx0 + 0 < n) c.x = cnt[idx0 + 0];
        if (idx0 + 1 < n) c.y = cnt[idx0 + 1];
        if (idx0 + 2 < n) c.z = cnt[idx0 + 2];
        if (idx0 + 3 < n) c.w = cnt[idx0 + 3];
    }
    int s = c.x + c.y + c.z + c.w;
    tsum[t] = s;
    __syncthreads();
    for (int o = 1; o < 256; o <<= 1) {
        int v = (t >= o) ? tsum[t - o] : 0;
        __syncthreads();
        tsum[t] += v;
        __syncthreads();
    }
    int run = tsum[t] - s;
    run += c.x; if (idx0 + 0 < n) off[idx0 + 1] = run;
    run += c.y; if (idx0 + 1 < n) off[idx0 + 2] = run;
    run += c.z; if (idx0 + 2 < n) off[idx0 + 3] = run;
    run += c.w; if (idx0 + 3 < n) off[idx0 + 4] = run;
    if (t == 255) psum[blockIdx.x] = tsum[255];
}

__global__ __launch_bounds__(256) void scan_part2(const int* __restrict__ cnt,
                                                  int* __restrict__ off,
                                                  const int* __restrict__ psum,
                                                  int* __restrict__ cur, int n)
{
    __shared__ int bpref;
    int t = threadIdx.x;
    int b = blockIdx.x;
    if (t < 64) {
        int s = (t < b) ? psum[t] : 0;
#pragma unroll
        for (int o = 32; o; o >>= 1) s += __shfl_xor(s, o);
        if (t == 0) {
            bpref = s;
            if (b == 0) off[0] = 0;
        }
    }
    __syncthreads();
    int base = b * 1024 + t * 4;
#pragma unroll
    for (int q = 0; q < 4; ++q) {
        int i = base + q;
        if (i < n) {
            int inc = off[i + 1] + bpref;
            off[i + 1] = inc;
            cur[i] = inc - cnt[i];
        }
    }
}

__global__ void fill_kernel(const int* __restrict__ V, const int* __restrict__ E,
                            int* ecur, int* ncur, int* edge_v, int* node_e, int nnz)
{
    int k0 = (blockIdx.x * blockDim.x + threadIdx.x) * 8;
    if (k0 >= nnz) return;
    int kmax = min(nnz - k0, 8);
    int vv[8], ee[8], js[8], is_[8];
    if (kmax == 8) {
        int4 a = *(const int4*)(V + k0), b = *(const int4*)(V + k0 + 4);
        int4 c = *(const int4*)(E + k0), d = *(const int4*)(E + k0 + 4);
        vv[0]=a.x; vv[1]=a.y; vv[2]=a.z; vv[3]=a.w; vv[4]=b.x; vv[5]=b.y; vv[6]=b.z; vv[7]=b.w;
        ee[0]=c.x; ee[1]=c.y; ee[2]=c.z; ee[3]=c.w; ee[4]=d.x; ee[5]=d.y; ee[6]=d.z; ee[7]=d.w;
    } else {
        for (int q = 0; q < kmax; ++q) { vv[q] = V[k0 + q]; ee[q] = E[k0 + q]; }
    }
    for (int q = 0; q < kmax; ++q) js[q] = atomicAdd(&ecur[ee[q]], 1);
    for (int q = 0; q < kmax; ++q) is_[q] = atomicAdd(&ncur[vv[q]], 1);
    for (int q = 0; q < kmax; ++q) edge_v[js[q]] = vv[q];
    for (int q = 0; q < kmax; ++q) node_e[is_[q]] = ee[q];
}

// =============== graph kernels ===============
__global__ void score_kernel(const u16* __restrict__ Xf, const float* __restrict__ a,
                             float* __restrict__ score, int N)
{
    int row = blockIdx.x * (blockDim.x >> 6) + (threadIdx.x >> 6);
    int lane = threadIdx.x & 63;
    if (row >= N) return;
    u16x4 x = *(const u16x4*)(Xf + (size_t)row * 256 + lane * 4);
    float4 av = *(const float4*)(a + lane * 4);
    float p = bf2f(x.x) * av.x + bf2f(x.y) * av.y + bf2f(x.z) * av.z + bf2f(x.w) * av.w;
#pragma unroll
    for (int off = 32; off; off >>= 1) p += __shfl_down(p, off);
    if (lane == 0) score[row] = p;
}

__device__ __forceinline__ float lrelu(float s) { return s >= 0.f ? s : 0.2f * s; }

__global__ void v2e_fused_kernel(const u16* __restrict__ Xf,
                                 const float* __restrict__ score,
                                 const int* __restrict__ eoff,
                                 const int* __restrict__ edge_v,
                                 u16* __restrict__ Ae, int M)
{
    int e = blockIdx.x * 8 + (threadIdx.x >> 5);
    if (e >= M) return;
    int sl = threadIdx.x & 31;
    int j0 = eoff[e], j1 = eoff[e + 1];
    float m = -INFINITY;
    for (int j = j0 + sl; j < j1; j += 32) m = fmaxf(m, lrelu(score[edge_v[j]]));
#pragma unroll
    for (int o = 16; o; o >>= 1) m = fmaxf(m, __shfl_xor(m, o));
    float sum = 0.f;
    for (int j = j0 + sl; j < j1; j += 32) sum += expf(lrelu(score[edge_v[j]]) - m);
#pragma unroll
    for (int o = 16; o; o >>= 1) sum += __shfl_xor(sum, o);
    float inv = (j1 > j0) ? 1.0f / sum : 0.f;

    float acc[8] = {0.f, 0.f, 0.f, 0.f, 0.f, 0.f, 0.f, 0.f};
    int col = sl * 8;
    int j = j0;
    for (; j + 3 < j1; j += 4) {
        int v0 = edge_v[j + 0], v1 = edge_v[j + 1], v2 = edge_v[j + 2], v3 = edge_v[j + 3];
        float s0 = score[v0], s1 = score[v1], s2 = score[v2], s3 = score[v3];
        u16x8 r0 = *(const u16x8*)(Xf + (size_t)v0 * 256 + col);
        u16x8 r1 = *(const u16x8*)(Xf + (size_t)v1 * 256 + col);
        u16x8 r2 = *(const u16x8*)(Xf + (size_t)v2 * 256 + col);
        u16x8 r3 = *(const u16x8*)(Xf + (size_t)v3 * 256 + col);
        float w0 = expf(lrelu(s0) - m) * inv;
        float w1 = expf(lrelu(s1) - m) * inv;
        float w2 = expf(lrelu(s2) - m) * inv;
        float w3 = expf(lrelu(s3) - m) * inv;
#pragma unroll
        for (int q = 0; q < 8; ++q) {
            acc[q] += bf2f(r0[q]) * w0;
            acc[q] += bf2f(r1[q]) * w1;
            acc[q] += bf2f(r2[q]) * w2;
            acc[q] += bf2f(r3[q]) * w3;
        }
    }
    for (; j < j1; ++j) {
        int v = edge_v[j];
        float ww = expf(lrelu(score[v]) - m) * inv;
        u16x8 r = *(const u16x8*)(Xf + (size_t)v * 256 + col);
#pragma unroll
        for (int q = 0; q < 8; ++q) acc[q] += bf2f(r[q]) * ww;
    }
    u16x8 hv;
#pragma unroll
    for (int q = 0; q < 8; ++q) {
        float vq = acc[q];
        vq = vq > 0.f ? vq : expm1f(vq);
        hv[q] = f2bf(vq);
    }
    *(u16x8*)(Ae + (size_t)e * 320 + col) = hv;
}

__global__ void e2v_finish_kernel(const u16* __restrict__ Y,
                                  const int* __restrict__ noff,
                                  const int* __restrict__ node_e,
                                  const u16* __restrict__ Xinit,
                                  u16* __restrict__ H, int N)
{
    int v = blockIdx.x * 8 + (threadIdx.x >> 5);
    if (v >= N) return;
    int sl = threadIdx.x & 31;
    int col = sl * 8;
    int i0 = noff[v], i1 = noff[v + 1];
    float acc[8] = {0.f, 0.f, 0.f, 0.f, 0.f, 0.f, 0.f, 0.f};
    int i = i0;
    for (; i + 3 < i1; i += 4) {
        int e0 = node_e[i + 0], e1 = node_e[i + 1], e2 = node_e[i + 2], e3 = node_e[i + 3];
        u16x8 r0 = *(const u16x8*)(Y + (size_t)e0 * 256 + col);
        u16x8 r1 = *(const u16x8*)(Y + (size_t)e1 * 256 + col);
        u16x8 r2 = *(const u16x8*)(Y + (size_t)e2 * 256 + col);
        u16x8 r3 = *(const u16x8*)(Y + (size_t)e3 * 256 + col);
#pragma unroll
        for (int q = 0; q < 8; ++q) {
            acc[q] += bf2f(r0[q]);
            acc[q] += bf2f(r1[q]);
            acc[q] += bf2f(r2[q]);
            acc[q] += bf2f(r3[q]);
        }
    }
    for (; i < i1; ++i) {
        int e = node_e[i];
        u16x8 r = *(const u16x8*)(Y + (size_t)e * 256 + col);
#pragma unroll
        for (int q = 0; q < 8; ++q) acc[q] += bf2f(r[q]);
    }
    float inv = (i1 > i0) ? 1.0f / (float)(i1 - i0) : 0.f;
    size_t base = (size_t)v * 256 + col;
    u16x8 xi = *(const u16x8*)(Xinit + base);
    u16x8 hv;
#pragma unroll
    for (int q = 0; q < 8; ++q) {
        float mm = acc[q] * inv;
        float oq = (mm > 0.f ? mm : expm1f(mm)) + bf2f(xi[q]);
        hv[q] = f2bf(oq);
    }
    *(u16x8*)(H + base) = hv;
}

// =============== hyperconv ===============
__global__ void yh_kernel(const u16* __restrict__ Xc,
                          const int* __restrict__ eoff, const int* __restrict__ edge_v,
                          const int* __restrict__ noff, u16* __restrict__ Yh, int M)
{
    int e = blockIdx.x * 16 + (threadIdx.x >> 4);
    if (e >= M) return;
    int sl = threadIdx.x & 15;
    int col = sl * 8;
    int j0 = eoff[e], j1 = eoff[e + 1];

    float dsum = 0.f;
    for (int j = j0 + sl; j < j1; j += 16) {
        int v = edge_v[j];
        dsum += (float)(noff[v + 1] - noff[v]);
    }
#pragma unroll
    for (int o = 8; o; o >>= 1) dsum += __shfl_xor(dsum, o);
    float De = dsum / ((float)(j1 - j0) + 1.0f);
    float deinv = De > 0.f ? rsqrtf(De) : 1.0f;

    float acc[8] = {0.f, 0.f, 0.f, 0.f, 0.f, 0.f, 0.f, 0.f};
    int j = j0;
    for (; j + 3 < j1; j += 4) {
        int v0 = edge_v[j + 0], v1 = edge_v[j + 1], v2 = edge_v[j + 2], v3 = edge_v[j + 3];
        u16x8 r0 = *(const u16x8*)(Xc + (size_t)v0 * 128 + col);
        u16x8 r1 = *(const u16x8*)(Xc + (size_t)v1 * 128 + col);
        u16x8 r2 = *(const u16x8*)(Xc + (size_t)v2 * 128 + col);
        u16x8 r3 = *(const u16x8*)(Xc + (size_t)v3 * 128 + col);
#pragma unroll
        for (int q = 0; q < 8; ++q) {
            acc[q] += bf2f(r0[q]);
            acc[q] += bf2f(r1[q]);
            acc[q] += bf2f(r2[q]);
            acc[q] += bf2f(r3[q]);
        }
    }
    for (; j < j1; ++j) {
        int v = edge_v[j];
        u16x8 r = *(const u16x8*)(Xc + (size_t)v * 128 + col);
#pragma unroll
        for (int q = 0; q < 8; ++q) acc[q] += bf2f(r[q]);
    }
    float sc = ((j1 > j0) ? 1.0f / (float)(j1 - j0) : 0.f) * deinv;
    u16x8 o8;
#pragma unroll
    for (int q = 0; q < 8; ++q) o8[q] = f2bf(acc[q] * sc);
    *(u16x8*)(Yh + (size_t)e * 128 + col) = o8;
}

__global__ void xo_final_kernel(const u16* __restrict__ Yh,
                                const int* __restrict__ noff, const int* __restrict__ node_e,
                                float* __restrict__ out, int N)
{
    int v = blockIdx.x * 16 + (threadIdx.x >> 4);
    if (v >= N) return;
    int sl = threadIdx.x & 15;
    int col = sl * 8;
    int i0 = noff[v], i1 = noff[v + 1];
    float acc[8] = {0.f, 0.f, 0.f, 0.f, 0.f, 0.f, 0.f, 0.f};
    int i = i0;
    for (; i + 3 < i1; i += 4) {
        int e0 = node_e[i + 0], e1 = node_e[i + 1], e2 = node_e[i + 2], e3 = node_e[i + 3];
        u16x8 r0 = *(const u16x8*)(Yh + (size_t)e0 * 128 + col);
        u16x8 r1 = *(const u16x8*)(Yh + (size_t)e1 * 128 + col);
        u16x8 r2 = *(const u16x8*)(Yh + (size_t)e2 * 128 + col);
        u16x8 r3 = *(const u16x8*)(Yh + (size_t)e3 * 128 + col);
#pragma unroll
        for (int q = 0; q < 8; ++q) {
            acc[q] += bf2f(r0[q]);
            acc[q] += bf2f(r1[q]);
            acc[q] += bf2f(r2[q]);
            acc[q] += bf2f(r3[q]);
        }
    }
    for (; i < i1; ++i) {
        int e = node_e[i];
        u16x8 r = *(const u16x8*)(Yh + (size_t)e * 128 + col);
#pragma unroll
        for (int q = 0; q < 8; ++q) acc[q] += bf2f(r[q]);
    }
    float sc = (i1 > i0) ? rsqrtf((float)(i1 - i0)) : 0.f;
    float4 oA, oB;
    oA.x = acc[0] * sc; oA.y = acc[1] * sc; oA.z = acc[2] * sc; oA.w = acc[3] * sc;
    oB.x = acc[4] * sc; oB.y = acc[5] * sc; oB.z = acc[6] * sc; oB.w = acc[7] * sc;
    float* d = out + (size_t)v * 128 + col;
    *(float4*)d = oA;
    *(float4*)(d + 4) = oB;
}

// =============== host-side ===============
static void gemm(const u16* A, int lda,
                 const u16* Bhi, const u16* Blo, int ldb,
                 const float* biasF, const float* biasB,
                 u16* CbA, u16* CbB, int M, int Nc, int ncSplit, int K,
                 hipStream_t stream)
{
    int nrb = (M + 127) / 128, ncb = Nc / 64;
    int nrb8 = ((nrb + 7) / 8) * 8;
    gemm_mfma_kernel<<<nrb8 * ncb, 256, 0, stream>>>(
        A, lda, Bhi, Blo, ldb, biasF, biasB, CbA, CbB, M, Nc, ncSplit, K, nrb, ncb);
}

static void run_layer(u16* A, int K,
                      const u16* WxvThi, const u16* WxvTlo,
                      const float* bx, const float* bv, const float* a,
                      const u16* WtThi, const u16* WtTlo, const float* bt,
                      u16* Ae,
                      u16* XinitB, u16* Xfeatb, u16* Ybufb, float* score,
                      const int* eoff, const int* edge_v,
                      const int* noff, const int* node_e,
                      int N, int M, hipStream_t stream)
{
    gemm(A, K, WxvThi, WxvTlo, K, bx, bv, XinitB, Xfeatb, N, 512, 256, K, stream);
    score_kernel<<<(N + 3) / 4, 256, 0, stream>>>(Xfeatb, a, score, N);
    v2e_fused_kernel<<<(M + 7) / 8, 256, 0, stream>>>(Xfeatb, score, eoff, edge_v, Ae, M);
    gemm(Ae, 320, WtThi, WtTlo, 320, nullptr, bt, nullptr, Ybufb, M, 256, 0, 320, stream);
    e2v_finish_kernel<<<(N + 7) / 8, 256, 0, stream>>>(Ybufb, noff, node_e, XinitB, A, N);
}

extern "C" void kernel_launch(void* const* d_in, const int* in_sizes, int n_in,
                              void* d_out, int out_size, void* d_ws, size_t ws_size,
                              hipStream_t stream)
{
    const float* X   = (const float*)d_in[0];
    const int*   V   = (const int*)d_in[1];
    const int*   E   = (const int*)d_in[2];
    const float* S   = (const float*)d_in[3];
    const float* Wx0 = (const float*)d_in[4];  const float* bx0 = (const float*)d_in[5];
    const float* Wv0 = (const float*)d_in[6];  const float* bv0 = (const float*)d_in[7];
    const float* a0  = (const float*)d_in[8];
    const float* Wt0 = (const float*)d_in[9];  const float* bt0 = (const float*)d_in[10];
    const float* Wx1 = (const float*)d_in[11]; const float* bx1 = (const float*)d_in[12];
    const float* Wv1 = (const float*)d_in[13]; const float* bv1 = (const float*)d_in[14];
    const float* a1  = (const float*)d_in[15];
    const float* Wt1 = (const float*)d_in[16]; const float* bt1 = (const float*)d_in[17];
    const float* Wf  = (const float*)d_in[18]; const float* bf  = (const float*)d_in[19];

    int N   = in_sizes[0] / 128;
    int NNZ = in_sizes[1];
    int M   = in_sizes[3] / 64;

    float* ws = (float*)d_ws;
    size_t off = 0;
    u16* XinitB = (u16*)(ws + off); off += (size_t)N * 128;  // [N,256] bf16; also Yh [M,128] bf16
    u16* XfeatR = (u16*)(ws + off); off += (size_t)N * 128;  // Xfeatb/Ybufb/Xcb
    u16* Xfeatb = XfeatR;
    u16* Ybufb  = XfeatR;
    u16* Abuf = (u16*)(ws + off); off += (size_t)N * 128;    // [N,256] bf16: X cast / h
    u16* Ae   = (u16*)(ws + off); off += (size_t)M * 160;    // [M,320] bf16 edge buffer
    u16* WxvT0h = (u16*)(ws + off); off += (size_t)(512 * 128) / 2;
    u16* WxvT0l = (u16*)(ws + off); off += (size_t)(512 * 128) / 2;
    u16* WtT0h  = (u16*)(ws + off); off += (size_t)(256 * 320) / 2;
    u16* WtT0l  = (u16*)(ws + off); off += (size_t)(256 * 320) / 2;
    u16* WxvT1h = (u16*)(ws + off); off += (size_t)(512 * 256) / 2;
    u16* WxvT1l = (u16*)(ws + off); off += (size_t)(512 * 256) / 2;
    u16* WtT1h  = (u16*)(ws + off); off += (size_t)(256 * 320) / 2;
    u16* WtT1l  = (u16*)(ws + off); off += (size_t)(256 * 320) / 2;
    u16* WfTh   = (u16*)(ws + off); off += (size_t)(128 * 256) / 2;
    u16* WfTl   = (u16*)(ws + off); off += (size_t)(128 * 256) / 2;
    float* score = ws + off; off += (size_t)N;
    int* eoff   = (int*)(ws + off); off += (size_t)(M + 1);
    int* ecnt   = (int*)(ws + off); off += (size_t)M;
    int* ecur   = (int*)(ws + off); off += (size_t)M;
    int* psumE  = (int*)(ws + off); off += 64;
    int* edge_v = (int*)(ws + off); off += (size_t)NNZ;
    int* noff   = (int*)(ws + off); off += (size_t)(N + 1);
    int* ncnt   = (int*)(ws + off); off += (size_t)N;
    int* ncur   = (int*)(ws + off); off += (size_t)N;
    int* psumN  = (int*)(ws + off); off += 64;
    int* node_e = (int*)(ws + off); off += (size_t)NNZ;

    // ---- CSR build ----
    hipMemsetAsync(ecnt, 0, (size_t)M * 4, stream);
    hipMemsetAsync(ncnt, 0, (size_t)N * 4, stream);
    count_kernel<<<((NNZ + 7) / 8 + 255) / 256, 256, 0, stream>>>(V, E, ecnt, ncnt, NNZ);
    int nbE = (M + 1023) / 1024, nbN = (N + 1023) / 1024;
    scan_part1<<<nbE, 256, 0, stream>>>(ecnt, eoff, psumE, M);
    scan_part1<<<nbN, 256, 0, stream>>>(ncnt, noff, psumN, N);
    scan_part2<<<nbE, 256, 0, stream>>>(ecnt, eoff, psumE, ecur, M);
    scan_part2<<<nbN, 256, 0, stream>>>(ncnt, noff, psumN, ncur, N);
    fill_kernel<<<((NNZ + 7) / 8 + 255) / 256, 256, 0, stream>>>(V, E, ecur, ncur, edge_v, node_e, NNZ);

    // ---- input casts (one launch) ----
    int n4x = N * 128 / 4, nS = M * 64;
    cast_inputs_kernel<<<(n4x + nS + 255) / 256, 256, 0, stream>>>(X, Abuf, n4x, S, Ae, nS);

    // ---- weight transpose+split (one launch, 7 jobs) ----
    WJobs jobs;
    jobs.j[0] = {Wx0, WxvT0h,                WxvT0l,                128, 8};
    jobs.j[1] = {Wv0, WxvT0h + 256 * 128,    WxvT0l + 256 * 128,    128, 8};
    jobs.j[2] = {Wt0, WtT0h,                 WtT0l,                 320, 8};
    jobs.j[3] = {Wx1, WxvT1h,                WxvT1l,                256, 8};
    jobs.j[4] = {Wv1, WxvT1h + 256 * 256,    WxvT1l + 256 * 256,    256, 8};
    jobs.j[5] = {Wt1, WtT1h,                 WtT1l,                 320, 8};
    jobs.j[6] = {Wf,  WfTh,                  WfTl,                  256, 7};
    dim3 wg((320 * 256 + 255) / 256, 7);
    wsplit_all_kernel<<<wg, 256, 0, stream>>>(jobs);

    // ---- layers (h bf16 lands back in Abuf) ----
    run_layer(Abuf, 128, WxvT0h, WxvT0l, bx0, bv0, a0,
              WtT0h, WtT0l, bt0, Ae, XinitB, Xfeatb, Ybufb, score,
              eoff, edge_v, noff, node_e, N, M, stream);
    run_layer(Abuf, 256, WxvT1h, WxvT1l, bx1, bv1, a1,
              WtT1h, WtT1l, bt1, Ae, XinitB, Xfeatb, Ybufb, score,
              eoff, edge_v, noff, node_e, N, M, stream);

    // ---- hyperconv (all-bf16 intermediates, fp32 final out) ----
    u16* Xcb = XfeatR;   // [N,128] bf16
    u16* Yhb = XinitB;   // [M,128] bf16
    gemm(Abuf, 256, WfTh, WfTl, 256, bf, nullptr, Xcb, nullptr, N, 128, 128, 256, stream);
    yh_kernel<<<(M + 15) / 16, 256, 0, stream>>>(Xcb, eoff, edge_v, noff, Yhb, M);
    xo_final_kernel<<<(N + 15) / 16, 256, 0, stream>>>(Yhb, noff, node_e, (float*)d_out, N);
}